// Round 3
// baseline (572.070 us; speedup 1.0000x reference)
//
#include <hip/hip_runtime.h>

// ---------------------------------------------------------------------------
// TabularDiffFlow sparse-attention pipeline, MI355X (gfx950)
// B=64, N=256, D=512, H=8, HD=64, top-k = 128 of 256 per score row.
//
// Precision: q,k projections and QK^T in split-bf16 (hi+lo, 3 MFMAs); v/P/
// out-proj plain bf16 (passed R1 at absmax 3.9e-3 vs 4.65e-3 threshold).
//
// R3: all GEMMs use global_load_lds(16B) into fragment-major LDS (conflict-
// free ds_read, no VGPR roundtrip). attn: K hi/lo staged once per (b,h) via
// global_load_lds with a row permutation rho so that the QK^T output layout
// IS the PV A-fragment layout -> PV fully in-register, no P LDS at all.
// ---------------------------------------------------------------------------

typedef __attribute__((ext_vector_type(8))) short short8;
typedef __attribute__((ext_vector_type(4))) float float4v;

#define MFMA16(A,B,C) __builtin_amdgcn_mfma_f32_16x16x32_bf16((A),(B),(C),0,0,0)

__device__ __forceinline__ ushort f2bf(float f){
  unsigned u = __float_as_uint(f);
  unsigned r = u + 0x7FFFu + ((u >> 16) & 1u);   // round-to-nearest-even
  return (ushort)(r >> 16);
}
__device__ __forceinline__ float bf2f(ushort h){
  return __uint_as_float(((unsigned)h) << 16);
}
// inverse of the "sortable uint" map (monotone uint <-> float bits)
__device__ __forceinline__ float unsort_u(unsigned u){
  unsigned b = (u & 0x80000000u) ? (u ^ 0x80000000u) : ~u;
  return __uint_as_float(b);
}
// async global -> LDS, 16 bytes per lane; LDS dest = wave-uniform base + lane*16
__device__ __forceinline__ void gl_lds16(const void* g, void* l){
  __builtin_amdgcn_global_load_lds(
      (const __attribute__((address_space(1))) unsigned int*)g,
      (__attribute__((address_space(3))) unsigned int*)l, 16, 0, 0);
}

// ---------------------------------------------------------------- cvt_x ----
__global__ __launch_bounds__(256) void cvt_x_k(const float* __restrict__ x,
                                               ushort* __restrict__ xhi,
                                               ushort* __restrict__ xlo){
  size_t i = ((size_t)blockIdx.x * 256 + threadIdx.x) * 8;
  float4v a = *(const float4v*)(x + i);
  float4v b = *(const float4v*)(x + i + 4);
  float v0=a[0],v1=a[1],v2=a[2],v3=a[3],v4=b[0],v5=b[1],v6=b[2],v7=b[3];
  ushort h0=f2bf(v0),h1=f2bf(v1),h2=f2bf(v2),h3=f2bf(v3);
  ushort h4=f2bf(v4),h5=f2bf(v5),h6=f2bf(v6),h7=f2bf(v7);
  ushort l0=f2bf(v0-bf2f(h0)),l1=f2bf(v1-bf2f(h1)),l2=f2bf(v2-bf2f(h2)),l3=f2bf(v3-bf2f(h3));
  ushort l4=f2bf(v4-bf2f(h4)),l5=f2bf(v5-bf2f(h5)),l6=f2bf(v6-bf2f(h6)),l7=f2bf(v7-bf2f(h7));
  uint4 ph, pl;
  ph.x = h0 | ((unsigned)h1<<16); ph.y = h2 | ((unsigned)h3<<16);
  ph.z = h4 | ((unsigned)h5<<16); ph.w = h6 | ((unsigned)h7<<16);
  pl.x = l0 | ((unsigned)l1<<16); pl.y = l2 | ((unsigned)l3<<16);
  pl.z = l4 | ((unsigned)l5<<16); pl.w = l6 | ((unsigned)l7<<16);
  *(uint4*)(xhi + i) = ph;
  *(uint4*)(xlo + i) = pl;
}

// ---------------------------------------------------------------- cvt_w ----
__global__ __launch_bounds__(256) void cvt_w_k(
    const float* __restrict__ Wq, const float* __restrict__ Wk,
    const float* __restrict__ Wv, const float* __restrict__ Wo,
    const float* __restrict__ bq, const float* __restrict__ bk, const float* __restrict__ bv,
    ushort* __restrict__ Wthi, ushort* __restrict__ Wtlo, ushort* __restrict__ Wot,
    float* __restrict__ fb){
  int r = blockIdx.x, t = threadIdx.x;
  if (r < 1536) {
    const float* W = (r < 512) ? Wq : ((r < 1024) ? Wk : Wv);
    int o = r & 511;
    bool dolo = (r < 1024);
    for (int i = t; i < 512; i += 256) {
      float f = W[(size_t)i*512 + o];
      ushort hi = f2bf(f);
      Wthi[(size_t)r*512 + i] = hi;
      if (dolo) Wtlo[(size_t)r*512 + i] = f2bf(f - bf2f(hi));
    }
  } else if (r < 2048) {
    int o = r - 1536;
    for (int i = t; i < 512; i += 256)
      Wot[(size_t)o*512 + i] = f2bf(Wo[(size_t)i*512 + o]);
  } else {
    for (int i = t; i < 1536; i += 256)
      fb[i] = (i < 512) ? bq[i] : ((i < 1024) ? bk[i-512] : bv[i-1024]);
  }
}

// ------------------------------------------------------------ prior_eff ----
__global__ __launch_bounds__(256) void prior_k(const float* __restrict__ prior,
    const float* __restrict__ fimp, float* __restrict__ pe){
  int i = blockIdx.x, j = threadIdx.x;
  pe[(size_t)i*256 + j] = prior[(size_t)i*256 + j] * fimp[i] * fimp[j];
}

// -------------------------------------------------------------- pv path ----
__global__ __launch_bounds__(256) void pv_mean_k(const float* __restrict__ x,
                                                 float* __restrict__ comb){
  int b = blockIdx.x, t = threadIdx.x;
  const float* xb = x + (size_t)b * 131072;
  float p0=0.f,p1=0.f,q0=0.f,q1=0.f;
  for (int n = 0; n < 128; n++){ p0 += xb[n*512 + t]; p1 += xb[n*512 + t + 256]; }
  for (int n = 128; n < 256; n++){ q0 += xb[n*512 + t]; q1 += xb[n*512 + t + 256]; }
  const float s = 1.0f/128.0f;
  comb[(size_t)b*1024 + t]         = p0*s;
  comb[(size_t)b*1024 + t + 256]   = p1*s;
  comb[(size_t)b*1024 + 512 + t]       = q0*s;
  comb[(size_t)b*1024 + 512 + t + 256] = q1*s;
}

__global__ __launch_bounds__(256) void pv_mlp_k(const float* __restrict__ comb,
    const float* __restrict__ W1, const float* __restrict__ b1,
    const float* __restrict__ W2, const float* __restrict__ b2,
    float* __restrict__ pvc){
  __shared__ float cs[1024];
  __shared__ float red[256];
  int b = blockIdx.x, t = threadIdx.x;
  for (int i = t; i < 1024; i += 256) cs[i] = comb[(size_t)b*1024 + i];
  __syncthreads();
  float a0 = b1[t], a1 = b1[t + 256];
  for (int i = 0; i < 1024; i++){
    float c = cs[i];
    a0 = fmaf(c, W1[(size_t)i*512 + t],       a0);
    a1 = fmaf(c, W1[(size_t)i*512 + t + 256], a1);
  }
  float h0 = a0 / (1.0f + __expf(-a0));
  float h1 = a1 / (1.0f + __expf(-a1));
  red[t] = fmaf(h0, W2[t], h1 * W2[t + 256]);
  __syncthreads();
  for (int s = 128; s > 0; s >>= 1){
    if (t < s) red[t] += red[t + s];
    __syncthreads();
  }
  if (t == 0) pvc[b] = 1.0f / (1.0f + __expf(-(red[0] + b2[0])));
}

// ------------------------------------------------ split GEMM for q and k ---
// M=16384, N=1024 (q|k), K=512. global_load_lds staging into fragment-major
// LDS: unit(r4, lane) holds A[r4*16 + (lane&15)][k0 + (lane>>4)*8 ..+8).
__global__ __launch_bounds__(256) void gemm_qk(
    const ushort* __restrict__ Ahi, const ushort* __restrict__ Alo,
    const ushort* __restrict__ Bhi, const ushort* __restrict__ Blo,
    const float* __restrict__ bias,
    ushort* __restrict__ qhi, ushort* __restrict__ qlo,
    ushort* __restrict__ khi, ushort* __restrict__ klo)
{
  __shared__ __align__(16) char sm[32768];   // [4 mats][8 spans][1024B]
  int flat = (int)blockIdx.x;
  int sw = ((flat & 7) << 7) + (flat >> 3);  // XCD swizzle, 1024 blocks
  int n0 = (sw & 7) * 128, m0 = (sw >> 3) * 128;
  int tid = threadIdx.x, lane = tid & 63, w = tid >> 6, wm = w >> 1, wn = w & 1;
  int q15 = lane & 15, g = lane >> 4;
  float4v acc[4][4] = {};
  for (int k0 = 0; k0 < 512; k0 += 32){
    // stage: 32 spans of 1KB; wave w -> spans w*8..w*8+7
    #pragma unroll
    for (int t = 0; t < 8; t++){
      int sp = w*8 + t;
      int mat = sp >> 3, r4 = sp & 7;
      const ushort* gp;
      if      (mat == 0) gp = Ahi + (size_t)(m0 + r4*16 + q15)*512 + k0 + g*8;
      else if (mat == 1) gp = Alo + (size_t)(m0 + r4*16 + q15)*512 + k0 + g*8;
      else if (mat == 2) gp = Bhi + (size_t)(n0 + r4*16 + q15)*512 + k0 + g*8;
      else               gp = Blo + (size_t)(n0 + r4*16 + q15)*512 + k0 + g*8;
      gl_lds16(gp, sm + sp*1024);
    }
    __syncthreads();
    short8 ah[4], al[4], bh[4], bl[4];
    #pragma unroll
    for (int i = 0; i < 4; i++){
      ah[i] = *(const short8*)(sm +         (wm*4 + i)*1024 + lane*16);
      al[i] = *(const short8*)(sm + 8192  + (wm*4 + i)*1024 + lane*16);
      bh[i] = *(const short8*)(sm + 16384 + (wn*4 + i)*1024 + lane*16);
      bl[i] = *(const short8*)(sm + 24576 + (wn*4 + i)*1024 + lane*16);
    }
    #pragma unroll
    for (int mi = 0; mi < 4; mi++){
      #pragma unroll
      for (int ni = 0; ni < 4; ni++){
        acc[mi][ni] = MFMA16(ah[mi], bh[ni], acc[mi][ni]);
        acc[mi][ni] = MFMA16(ah[mi], bl[ni], acc[mi][ni]);
        acc[mi][ni] = MFMA16(al[mi], bh[ni], acc[mi][ni]);
      }
    }
    __syncthreads();
  }
  #pragma unroll
  for (int mi = 0; mi < 4; mi++){
    #pragma unroll
    for (int ni = 0; ni < 4; ni++){
      #pragma unroll
      for (int r = 0; r < 4; r++){
        int rg = m0 + wm*64 + mi*16 + (g<<2) + r;
        int cg = n0 + wn*64 + ni*16 + q15;
        float val = acc[mi][ni][r] + bias[cg];
        int which = cg >> 9, within = cg & 511;
        int bb = rg >> 8, seq = rg & 255, hh = within >> 6, hd = within & 63;
        size_t idx = ((size_t)((bb*8 + hh)*256 + seq))*64 + hd;
        ushort hi_ = f2bf(val);
        ushort lo_ = f2bf(val - bf2f(hi_));
        if (which == 0) { qhi[idx] = hi_; qlo[idx] = lo_; }
        else            { khi[idx] = hi_; klo[idx] = lo_; }
      }
    }
  }
}

// ------------------------------------------- plain bf16 GEMM (v, out-proj) -
// EPI=0: out = bf16 V in MFMA-fragment layout: (k,hd) of head (b,h) at
//        ((b*8+h)<<14) + ((k>>5)*64 + hd)*32 + (k&31).
// EPI=1: out = fp32 [M][512].
template<int EPI>
__global__ __launch_bounds__(256) void gemm_pl(
    const ushort* __restrict__ A, const ushort* __restrict__ Bt,
    const float* __restrict__ bias, void* __restrict__ outp)
{
  __shared__ __align__(16) char sm[16384];   // A: 0..8K, B: 8K..16K
  int flat = (int)blockIdx.x;
  int sw = ((flat & 7) << 6) + (flat >> 3);  // XCD swizzle, 512 blocks
  int n0 = (sw & 3) * 128, m0 = (sw >> 2) * 128;
  int tid = threadIdx.x, lane = tid & 63, w = tid >> 6, wm = w >> 1, wn = w & 1;
  int q15 = lane & 15, g = lane >> 4;
  float4v acc[4][4] = {};
  for (int k0 = 0; k0 < 512; k0 += 32){
    #pragma unroll
    for (int t = 0; t < 2; t++){
      int r4 = w*2 + t;
      gl_lds16(A  + (size_t)(m0 + r4*16 + q15)*512 + k0 + g*8, sm +        r4*1024);
      gl_lds16(Bt + (size_t)(n0 + r4*16 + q15)*512 + k0 + g*8, sm + 8192 + r4*1024);
    }
    __syncthreads();
    short8 af[4], bg4[4];
    #pragma unroll
    for (int i = 0; i < 4; i++){
      af[i]  = *(const short8*)(sm +        (wm*4 + i)*1024 + lane*16);
      bg4[i] = *(const short8*)(sm + 8192 + (wn*4 + i)*1024 + lane*16);
    }
    #pragma unroll
    for (int mi = 0; mi < 4; mi++){
      #pragma unroll
      for (int ni = 0; ni < 4; ni++)
        acc[mi][ni] = MFMA16(af[mi], bg4[ni], acc[mi][ni]);
    }
    __syncthreads();
  }
  #pragma unroll
  for (int mi = 0; mi < 4; mi++){
    #pragma unroll
    for (int ni = 0; ni < 4; ni++){
      int rg0 = m0 + wm*64 + mi*16 + (g<<2);
      int cg  = n0 + wn*64 + ni*16 + q15;
      if (EPI == 0){
        int bb = rg0 >> 8, seq0 = rg0 & 255;
        int hh = cg >> 6, hd = cg & 63;
        int kb = seq0 >> 5, wi = seq0 & 31;
        float b_ = bias[cg];
        uint2 pk;
        pk.x = (unsigned)f2bf(acc[mi][ni][0] + b_) | ((unsigned)f2bf(acc[mi][ni][1] + b_) << 16);
        pk.y = (unsigned)f2bf(acc[mi][ni][2] + b_) | ((unsigned)f2bf(acc[mi][ni][3] + b_) << 16);
        size_t off = ((size_t)(bb*8 + hh) << 14) + (size_t)(((kb<<6) + hd) << 5) + wi;
        *(uint2*)((ushort*)outp + off) = pk;
      } else {
        float b_ = bias[cg];
        #pragma unroll
        for (int r = 0; r < 4; r++)
          ((float*)outp)[(size_t)(rg0 + r)*512 + cg] = acc[mi][ni][r] + b_;
      }
    }
  }
}

// ------------------------------------------------------ fused attention ----
// 512 blocks (one per (b,h)), 8 waves. K hi/lo staged ONCE via global_load_lds
// into fragment-major LDS with row permutation rho(s) = (s&~31)|(((s>>2)&3)<<3)
// |(((s>>4)&1)<<2)|(s&3), chosen so acc[kt][r] (slot kt*16+g*4+r) holds score
// of original row (kt>>1)*32 + g*8 + (kt&1)*4 + r  => PV A-fragments are just
// {acc[2m][0..3], acc[2m+1][0..3]} -- no P LDS, no cross-lane movement.
__global__ __launch_bounds__(512, 4) void attn_k(
    const ushort* __restrict__ qhi_, const ushort* __restrict__ qlo_,
    const ushort* __restrict__ khi_, const ushort* __restrict__ klo_,
    const ushort* __restrict__ vt, const float* __restrict__ pe,
    const float* __restrict__ pvc, ushort* __restrict__ ao)
{
  extern __shared__ char Ksm[];   // 64KB: Khi frag-major 32KB | Klo 32KB

  int bid = (int)blockIdx.x;
  int bh = ((bid & 7) << 6) + (bid >> 3);    // XCD swizzle (512 = 8*64)
  int b = bh >> 3, h = bh & 7;
  int tid = threadIdx.x, lane = tid & 63, w = tid >> 6;
  int g = lane >> 4, q15 = lane & 15;
  size_t base = (size_t)bh << 14;            // *16384 elements per (b,h)
  float pvb = pvc[b] * 0.5f;

  // ---- stage K hi/lo, permuted, fragment-major: span sp (1KB) = (mat, kt, half)
  #pragma unroll
  for (int t = 0; t < 8; t++){
    int sp = w*8 + t;                        // 0..63
    int mat = sp >> 5, s5 = sp & 31;
    int kt = s5 >> 1, half = s5 & 1;
    int R = ((kt>>1)<<5) + ((q15>>2)<<3) + ((kt&1)<<2) + (q15&3);  // rho(kt*16+q15)
    const ushort* gp = (mat ? klo_ : khi_) + base + (size_t)R*64 + half*32 + g*8;
    gl_lds16(gp, Ksm + sp*1024);
  }
  __syncthreads();

  for (int qt = 0; qt < 2; qt++){
    int qbase = ((qt<<3) + w) << 4;          // (qt*8 + w)*16
    int qg = qbase + q15;

    const ushort* qp1 = qhi_ + base + (size_t)qg*64 + (g<<3);
    const ushort* qp2 = qlo_ + base + (size_t)qg*64 + (g<<3);
    short8 qh0 = *(const short8*)(qp1);
    short8 qh1 = *(const short8*)(qp1 + 32);
    short8 ql0 = *(const short8*)(qp2);
    short8 ql1 = *(const short8*)(qp2 + 32);

    // QK^T (split 3-mfma x 2 halves)
    float4v acc[16];
    #pragma unroll
    for (int kt = 0; kt < 16; kt++){
      short8 kh0 = *(const short8*)(Ksm +         kt*2048 +        lane*16);
      short8 kh1 = *(const short8*)(Ksm +         kt*2048 + 1024 + lane*16);
      short8 kl0 = *(const short8*)(Ksm + 32768 + kt*2048 +        lane*16);
      short8 kl1 = *(const short8*)(Ksm + 32768 + kt*2048 + 1024 + lane*16);
      float4v a = {0.f,0.f,0.f,0.f};
      a = MFMA16(kh0, qh0, a);
      a = MFMA16(kh1, qh1, a);
      a = MFMA16(kh0, ql0, a);
      a = MFMA16(kh1, ql1, a);
      a = MFMA16(kl0, qh0, a);
      a = MFMA16(kl1, qh1, a);
      acc[kt] = a;
    }

    // scale + prior (permuted column) + price/vol cross-block bias
    bool qlow = (qg < 128);
    #pragma unroll
    for (int kt = 0; kt < 16; kt++){
      float4v p4 = *(const float4v*)(pe + qg*256 + ((kt>>1)<<5) + (g<<3) + ((kt&1)<<2));
      float cb = (qlow != (kt < 8)) ? pvb : 0.0f;
      #pragma unroll
      for (int r = 0; r < 4; r++)
        acc[kt][r] = acc[kt][r]*0.125f + p4[r] + cb;
    }

    // exact 128th-largest per row (MSB radix-select, sortable-uint space)
    unsigned thr = 0u; int done = 0;
    for (int bit = 31; bit >= 0; --bit){
      if (__all(done)) break;
      unsigned cand = thr | (1u << bit);
      float tf = unsort_u(cand);
      int cnt = 0;
      #pragma unroll
      for (int kt = 0; kt < 16; kt++){
        #pragma unroll
        for (int r = 0; r < 4; r++)
          cnt += (acc[kt][r] >= tf) ? 1 : 0;
      }
      cnt += __shfl_xor(cnt, 16);
      cnt += __shfl_xor(cnt, 32);
      if (!done && cnt >= 128) thr = cand;
      if (!done && cnt == 128) done = 1;
    }
    float thrf = unsort_u(thr);

    // softmax over kept
    float m = -1e30f;
    #pragma unroll
    for (int kt = 0; kt < 16; kt++)
      m = fmaxf(m, fmaxf(fmaxf(acc[kt][0], acc[kt][1]), fmaxf(acc[kt][2], acc[kt][3])));
    m = fmaxf(m, __shfl_xor(m, 16));
    m = fmaxf(m, __shfl_xor(m, 32));
    float sum = 0.0f;
    #pragma unroll
    for (int kt = 0; kt < 16; kt++){
      #pragma unroll
      for (int r = 0; r < 4; r++){
        float e = (acc[kt][r] >= thrf) ? __expf(acc[kt][r] - m) : 0.0f;
        acc[kt][r] = e;
        sum += e;
      }
    }
    sum += __shfl_xor(sum, 16);
    sum += __shfl_xor(sum, 32);
    float inv = 1.0f / sum;

    // PV fully in-register: A-frag m = bf16{acc[2m][0..3]*inv, acc[2m+1][0..3]*inv}
    float4v oa[4] = {};
    #pragma unroll
    for (int mM = 0; mM < 8; mM++){
      short8 pf;
      ushort* pp = (ushort*)&pf;
      #pragma unroll
      for (int r = 0; r < 4; r++){
        pp[r]   = f2bf(acc[2*mM][r]   * inv);
        pp[r+4] = f2bf(acc[2*mM+1][r] * inv);
      }
      #pragma unroll
      for (int ht = 0; ht < 4; ht++){
        short8 vf = *(const short8*)(vt + base + (size_t)(((mM<<6) + (ht<<4) + q15) << 5) + (g<<3));
        oa[ht] = MFMA16(pf, vf, oa[ht]);
      }
    }
    #pragma unroll
    for (int ht = 0; ht < 4; ht++){
      #pragma unroll
      for (int r = 0; r < 4; r++){
        int qo = qbase + (g<<2) + r;
        ao[((size_t)(b*256 + qo) << 9) + (h<<6) + (ht<<4) + q15] = f2bf(oa[ht][r]);
      }
    }
  }
}

// ---------------------------------------------------------------------------
extern "C" void kernel_launch(void* const* d_in, const int* in_sizes, int n_in,
                              void* d_out, int out_size, void* d_ws, size_t ws_size,
                              hipStream_t stream)
{
  const float* x     = (const float*)d_in[0];
  const float* Wq    = (const float*)d_in[1];
  const float* bq    = (const float*)d_in[2];
  const float* Wk    = (const float*)d_in[3];
  const float* bk    = (const float*)d_in[4];
  const float* Wv    = (const float*)d_in[5];
  const float* bv    = (const float*)d_in[6];
  const float* Wo    = (const float*)d_in[7];
  const float* bo    = (const float*)d_in[8];
  const float* prior = (const float*)d_in[9];
  const float* fimp  = (const float*)d_in[10];
  const float* W1    = (const float*)d_in[11];
  const float* b1    = (const float*)d_in[12];
  const float* W2    = (const float*)d_in[13];
  const float* b2    = (const float*)d_in[14];

  char* ws = (char*)d_ws;
  ushort* xhi  = (ushort*)(ws + 0);
  ushort* xlo  = (ushort*)(ws + 16777216);
  ushort* qhi  = (ushort*)(ws + 33554432);
  ushort* qlo  = (ushort*)(ws + 50331648);
  ushort* khi  = (ushort*)(ws + 67108864);
  ushort* klo  = (ushort*)(ws + 83886080);
  ushort* vt   = (ushort*)(ws + 100663296);    // V in MFMA fragment layout
  ushort* Wthi = (ushort*)(ws + 117440512);
  ushort* Wtlo = (ushort*)(ws + 119013376);
  ushort* Wot  = (ushort*)(ws + 120061952);
  float*  fb   = (float*) (ws + 120586240);
  float*  comb = (float*) (ws + 120592384);
  float*  pvc  = (float*) (ws + 120854528);
  float*  pe   = (float*) (ws + 120854784);
  ushort* ao   = xhi;   // alias: xhi dead after the projection GEMMs

  (void)hipFuncSetAttribute((const void*)attn_k,
      hipFuncAttributeMaxDynamicSharedMemorySize, 65536);

  cvt_x_k <<<4096, 256, 0, stream>>>(x, xhi, xlo);
  cvt_w_k <<<2049, 256, 0, stream>>>(Wq, Wk, Wv, Wo, bq, bk, bv, Wthi, Wtlo, Wot, fb);
  prior_k <<<256, 256, 0, stream>>>(prior, fimp, pe);
  pv_mean_k<<<64, 256, 0, stream>>>(x, comb);
  pv_mlp_k <<<64, 256, 0, stream>>>(comb, W1, b1, W2, b2, pvc);
  gemm_qk <<<1024, 256, 0, stream>>>(xhi, xlo, Wthi, Wtlo, fb, qhi, qlo, khi, klo);
  gemm_pl<0><<<512, 256, 0, stream>>>(xhi, Wthi + (size_t)1024*512, fb + 1024, vt);
  attn_k  <<<512, 512, 65536, stream>>>(qhi, qlo, khi, klo, vt, pe, pvc, ao);
  gemm_pl<1><<<512, 256, 0, stream>>>(ao, Wot, bo, d_out);

  (void)in_sizes; (void)n_in; (void)out_size; (void)ws_size;
}

// Round 4
// 517.105 us; speedup vs baseline: 1.1063x; 1.1063x over previous
//
#include <hip/hip_runtime.h>

// ---------------------------------------------------------------------------
// TabularDiffFlow sparse-attention pipeline, MI355X (gfx950)
// B=64, N=256, D=512, H=8, HD=64, top-k = 128 of 256 per score row.
//
// Precision: q,k projections and QK^T in split-bf16 (hi+lo, 3 MFMAs); v/P/
// out-proj plain bf16 (absmax 3.9e-3 vs 4.65e-3 threshold, R1-R3).
//
// R4: attn stages K(hi+lo) AND V in LDS (96 KB, read-once per block; R3's
// mistake was leaving V in global -> 256 MB re-fetch). Frag-major LDS via
// global_load_lds, rho-permuted K so QK^T output = PV A-fragment layout
// (in-register PV, no P LDS). GEMMs reverted to R2's measured-good form.
// pv_mlp: 8 blocks x 8 batches (W1 read 16 MB instead of 134 MB).
// ---------------------------------------------------------------------------

typedef __attribute__((ext_vector_type(8))) short short8;
typedef __attribute__((ext_vector_type(4))) float float4v;

#define MFMA16(A,B,C) __builtin_amdgcn_mfma_f32_16x16x32_bf16((A),(B),(C),0,0,0)

__device__ __forceinline__ ushort f2bf(float f){
  unsigned u = __float_as_uint(f);
  unsigned r = u + 0x7FFFu + ((u >> 16) & 1u);   // round-to-nearest-even
  return (ushort)(r >> 16);
}
__device__ __forceinline__ float bf2f(ushort h){
  return __uint_as_float(((unsigned)h) << 16);
}
// inverse of the "sortable uint" map (monotone uint <-> float bits)
__device__ __forceinline__ float unsort_u(unsigned u){
  unsigned b = (u & 0x80000000u) ? (u ^ 0x80000000u) : ~u;
  return __uint_as_float(b);
}
// async global -> LDS, 16 bytes per lane; LDS dest = wave-uniform base + lane*16
__device__ __forceinline__ void gl_lds16(const void* g, void* l){
  __builtin_amdgcn_global_load_lds(
      (const __attribute__((address_space(1))) unsigned int*)g,
      (__attribute__((address_space(3))) unsigned int*)l, 16, 0, 0);
}

// ---------------------------------------------------------------- cvt_x ----
__global__ __launch_bounds__(256) void cvt_x_k(const float* __restrict__ x,
                                               ushort* __restrict__ xhi,
                                               ushort* __restrict__ xlo){
  size_t i = ((size_t)blockIdx.x * 256 + threadIdx.x) * 8;
  float4v a = *(const float4v*)(x + i);
  float4v b = *(const float4v*)(x + i + 4);
  float v0=a[0],v1=a[1],v2=a[2],v3=a[3],v4=b[0],v5=b[1],v6=b[2],v7=b[3];
  ushort h0=f2bf(v0),h1=f2bf(v1),h2=f2bf(v2),h3=f2bf(v3);
  ushort h4=f2bf(v4),h5=f2bf(v5),h6=f2bf(v6),h7=f2bf(v7);
  ushort l0=f2bf(v0-bf2f(h0)),l1=f2bf(v1-bf2f(h1)),l2=f2bf(v2-bf2f(h2)),l3=f2bf(v3-bf2f(h3));
  ushort l4=f2bf(v4-bf2f(h4)),l5=f2bf(v5-bf2f(h5)),l6=f2bf(v6-bf2f(h6)),l7=f2bf(v7-bf2f(h7));
  uint4 ph, pl;
  ph.x = h0 | ((unsigned)h1<<16); ph.y = h2 | ((unsigned)h3<<16);
  ph.z = h4 | ((unsigned)h5<<16); ph.w = h6 | ((unsigned)h7<<16);
  pl.x = l0 | ((unsigned)l1<<16); pl.y = l2 | ((unsigned)l3<<16);
  pl.z = l4 | ((unsigned)l5<<16); pl.w = l6 | ((unsigned)l7<<16);
  *(uint4*)(xhi + i) = ph;
  *(uint4*)(xlo + i) = pl;
}

// ---------------------------------------------------------------- cvt_w ----
__global__ __launch_bounds__(256) void cvt_w_k(
    const float* __restrict__ Wq, const float* __restrict__ Wk,
    const float* __restrict__ Wv, const float* __restrict__ Wo,
    const float* __restrict__ bq, const float* __restrict__ bk, const float* __restrict__ bv,
    ushort* __restrict__ Wthi, ushort* __restrict__ Wtlo, ushort* __restrict__ Wot,
    float* __restrict__ fb){
  int r = blockIdx.x, t = threadIdx.x;
  if (r < 1536) {
    const float* W = (r < 512) ? Wq : ((r < 1024) ? Wk : Wv);
    int o = r & 511;
    bool dolo = (r < 1024);
    for (int i = t; i < 512; i += 256) {
      float f = W[(size_t)i*512 + o];
      ushort hi = f2bf(f);
      Wthi[(size_t)r*512 + i] = hi;
      if (dolo) Wtlo[(size_t)r*512 + i] = f2bf(f - bf2f(hi));
    }
  } else if (r < 2048) {
    int o = r - 1536;
    for (int i = t; i < 512; i += 256)
      Wot[(size_t)o*512 + i] = f2bf(Wo[(size_t)i*512 + o]);
  } else {
    for (int i = t; i < 1536; i += 256)
      fb[i] = (i < 512) ? bq[i] : ((i < 1024) ? bk[i-512] : bv[i-1024]);
  }
}

// ------------------------------------------------------------ prior_eff ----
__global__ __launch_bounds__(256) void prior_k(const float* __restrict__ prior,
    const float* __restrict__ fimp, float* __restrict__ pe){
  int i = blockIdx.x, j = threadIdx.x;
  pe[(size_t)i*256 + j] = prior[(size_t)i*256 + j] * fimp[i] * fimp[j];
}

// -------------------------------------------------------------- pv path ----
__global__ __launch_bounds__(256) void pv_mean_k(const float* __restrict__ x,
                                                 float* __restrict__ comb){
  int b = blockIdx.x, t = threadIdx.x;
  const float* xb = x + (size_t)b * 131072;
  float p0=0.f,p1=0.f,q0=0.f,q1=0.f;
  for (int n = 0; n < 128; n++){ p0 += xb[n*512 + t]; p1 += xb[n*512 + t + 256]; }
  for (int n = 128; n < 256; n++){ q0 += xb[n*512 + t]; q1 += xb[n*512 + t + 256]; }
  const float s = 1.0f/128.0f;
  comb[(size_t)b*1024 + t]         = p0*s;
  comb[(size_t)b*1024 + t + 256]   = p1*s;
  comb[(size_t)b*1024 + 512 + t]       = q0*s;
  comb[(size_t)b*1024 + 512 + t + 256] = q1*s;
}

// 8 blocks x 8 batches: W1 read once per block (16 MB total, was 134 MB).
__global__ __launch_bounds__(256) void pv_mlp_k(const float* __restrict__ comb,
    const float* __restrict__ W1, const float* __restrict__ b1,
    const float* __restrict__ W2, const float* __restrict__ b2,
    float* __restrict__ pvc){
  __shared__ float cs[8][1024];
  __shared__ float red[8][4];
  int b0 = blockIdx.x * 8, t = threadIdx.x;
  int lane = t & 63, w = t >> 6;
  for (int i = t; i < 8192; i += 256)
    cs[i >> 10][i & 1023] = comb[(size_t)b0*1024 + i];
  __syncthreads();
  float bb0 = b1[t], bb1 = b1[t + 256];
  float a0[8], a1[8];
  #pragma unroll
  for (int j = 0; j < 8; j++){ a0[j] = bb0; a1[j] = bb1; }
  for (int i = 0; i < 1024; i++){
    float w0 = W1[(size_t)i*512 + t];
    float w1 = W1[(size_t)i*512 + t + 256];
    #pragma unroll
    for (int j = 0; j < 8; j++){
      float c = cs[j][i];
      a0[j] = fmaf(c, w0, a0[j]);
      a1[j] = fmaf(c, w1, a1[j]);
    }
  }
  float w2a = W2[t], w2b = W2[t + 256];
  #pragma unroll
  for (int j = 0; j < 8; j++){
    float h0 = a0[j] / (1.0f + __expf(-a0[j]));
    float h1 = a1[j] / (1.0f + __expf(-a1[j]));
    float p = fmaf(h0, w2a, h1 * w2b);
    p += __shfl_down(p, 32); p += __shfl_down(p, 16);
    p += __shfl_down(p, 8);  p += __shfl_down(p, 4);
    p += __shfl_down(p, 2);  p += __shfl_down(p, 1);
    if (lane == 0) red[j][w] = p;
  }
  __syncthreads();
  if (t < 8){
    float s = red[t][0] + red[t][1] + red[t][2] + red[t][3];
    pvc[b0 + t] = 1.0f / (1.0f + __expf(-(s + b2[0])));
  }
}

// ------------------------------------------------ split GEMM for q and k ---
__global__ __launch_bounds__(256) void gemm_qk(
    const ushort* __restrict__ Ahi, const ushort* __restrict__ Alo,
    const ushort* __restrict__ Bhi, const ushort* __restrict__ Blo,
    const float* __restrict__ bias,
    ushort* __restrict__ qhi, ushort* __restrict__ qlo,
    ushort* __restrict__ khi, ushort* __restrict__ klo)
{
  __shared__ __align__(16) ushort As[2][128][40];
  __shared__ __align__(16) ushort Bs[2][128][40];
  int n0 = blockIdx.x * 128, m0 = blockIdx.y * 128;
  int tid = threadIdx.x, lane = tid & 63, w = tid >> 6, wm = w >> 1, wn = w & 1;
  float4v acc[4][4] = {};
  for (int k0 = 0; k0 < 512; k0 += 32){
    for (int c = tid; c < 512; c += 256){
      int row = c >> 2, ch = c & 3;
      *(uint4*)(&As[0][row][ch*8]) = *(const uint4*)(Ahi + (size_t)(m0+row)*512 + k0 + ch*8);
      *(uint4*)(&As[1][row][ch*8]) = *(const uint4*)(Alo + (size_t)(m0+row)*512 + k0 + ch*8);
      *(uint4*)(&Bs[0][row][ch*8]) = *(const uint4*)(Bhi + (size_t)(n0+row)*512 + k0 + ch*8);
      *(uint4*)(&Bs[1][row][ch*8]) = *(const uint4*)(Blo + (size_t)(n0+row)*512 + k0 + ch*8);
    }
    __syncthreads();
    short8 ah[4], al[4], bh[4], bl[4];
    #pragma unroll
    for (int i = 0; i < 4; i++){
      ah[i] = *(const short8*)(&As[0][wm*64 + i*16 + (lane&15)][(lane>>4)*8]);
      al[i] = *(const short8*)(&As[1][wm*64 + i*16 + (lane&15)][(lane>>4)*8]);
      bh[i] = *(const short8*)(&Bs[0][wn*64 + i*16 + (lane&15)][(lane>>4)*8]);
      bl[i] = *(const short8*)(&Bs[1][wn*64 + i*16 + (lane&15)][(lane>>4)*8]);
    }
    #pragma unroll
    for (int mi = 0; mi < 4; mi++){
      #pragma unroll
      for (int ni = 0; ni < 4; ni++){
        acc[mi][ni] = MFMA16(ah[mi], bh[ni], acc[mi][ni]);
        acc[mi][ni] = MFMA16(ah[mi], bl[ni], acc[mi][ni]);
        acc[mi][ni] = MFMA16(al[mi], bh[ni], acc[mi][ni]);
      }
    }
    __syncthreads();
  }
  #pragma unroll
  for (int mi = 0; mi < 4; mi++){
    #pragma unroll
    for (int ni = 0; ni < 4; ni++){
      #pragma unroll
      for (int r = 0; r < 4; r++){
        int rg = m0 + wm*64 + mi*16 + ((lane>>4)<<2) + r;
        int cg = n0 + wn*64 + ni*16 + (lane&15);
        float val = acc[mi][ni][r] + bias[cg];
        int which = cg >> 9, within = cg & 511;
        int bb = rg >> 8, seq = rg & 255, hh = within >> 6, hd = within & 63;
        size_t idx = ((size_t)((bb*8 + hh)*256 + seq))*64 + hd;
        ushort hi_ = f2bf(val);
        ushort lo_ = f2bf(val - bf2f(hi_));
        if (which == 0) { qhi[idx] = hi_; qlo[idx] = lo_; }
        else            { khi[idx] = hi_; klo[idx] = lo_; }
      }
    }
  }
}

// ------------------------------------------- plain bf16 GEMM (v, out-proj) -
// EPI=0: out = bf16 V in MFMA-fragment layout: (k,hd) of head (b,h) at
//        ((b*8+h)<<14) + ((k>>5)*64 + hd)*32 + (k&31).
// EPI=1: out = fp32 [M][512].
template<int EPI>
__global__ __launch_bounds__(256) void gemm_pl(
    const ushort* __restrict__ A, const ushort* __restrict__ Bt,
    const float* __restrict__ bias, void* __restrict__ outp)
{
  __shared__ __align__(16) ushort As[128][40];
  __shared__ __align__(16) ushort Bs[128][40];
  int n0 = blockIdx.x * 128, m0 = blockIdx.y * 128;
  int tid = threadIdx.x, lane = tid & 63, w = tid >> 6, wm = w >> 1, wn = w & 1;
  float4v acc[4][4] = {};
  for (int k0 = 0; k0 < 512; k0 += 32){
    for (int c = tid; c < 512; c += 256){
      int row = c >> 2, ch = c & 3;
      *(uint4*)(&As[row][ch*8]) = *(const uint4*)(A  + (size_t)(m0+row)*512 + k0 + ch*8);
      *(uint4*)(&Bs[row][ch*8]) = *(const uint4*)(Bt + (size_t)(n0+row)*512 + k0 + ch*8);
    }
    __syncthreads();
    short8 af[4], bg4[4];
    #pragma unroll
    for (int i = 0; i < 4; i++){
      af[i]  = *(const short8*)(&As[wm*64 + i*16 + (lane&15)][(lane>>4)*8]);
      bg4[i] = *(const short8*)(&Bs[wn*64 + i*16 + (lane&15)][(lane>>4)*8]);
    }
    #pragma unroll
    for (int mi = 0; mi < 4; mi++){
      #pragma unroll
      for (int ni = 0; ni < 4; ni++)
        acc[mi][ni] = MFMA16(af[mi], bg4[ni], acc[mi][ni]);
    }
    __syncthreads();
  }
  #pragma unroll
  for (int mi = 0; mi < 4; mi++){
    #pragma unroll
    for (int ni = 0; ni < 4; ni++){
      int rg0 = m0 + wm*64 + mi*16 + ((lane>>4)<<2);
      int cg  = n0 + wn*64 + ni*16 + (lane&15);
      if (EPI == 0){
        int bb = rg0 >> 8, seq0 = rg0 & 255;
        int hh = cg >> 6, hd = cg & 63;
        int kb = seq0 >> 5, wi = seq0 & 31;
        float b_ = bias[cg];
        uint2 pk;
        pk.x = (unsigned)f2bf(acc[mi][ni][0] + b_) | ((unsigned)f2bf(acc[mi][ni][1] + b_) << 16);
        pk.y = (unsigned)f2bf(acc[mi][ni][2] + b_) | ((unsigned)f2bf(acc[mi][ni][3] + b_) << 16);
        size_t off = ((size_t)(bb*8 + hh) << 14) + (size_t)(((kb<<6) + hd) << 5) + wi;
        *(uint2*)((ushort*)outp + off) = pk;
      } else {
        float b_ = bias[cg];
        #pragma unroll
        for (int r = 0; r < 4; r++)
          ((float*)outp)[(size_t)(rg0 + r)*512 + cg] = acc[mi][ni][r] + b_;
      }
    }
  }
}

// ------------------------------------------------------ fused attention ----
// 512 blocks (one per (b,h)), 8 waves, 96 KB LDS: Khi|Klo|V all staged ONCE
// via global_load_lds, frag-major. K rows permuted by rho(s) =
// (s&~31)|(((s>>2)&3)<<3)|(((s>>4)&1)<<2)|(s&3) so acc[kt][r] holds score of
// original row (kt>>1)*32 + g*8 + (kt&1)*4 + r => PV A-fragments are
// {acc[2m],acc[2m+1]} directly: no P LDS, no cross-lane movement.
__global__ __launch_bounds__(512, 2) void attn_k(
    const ushort* __restrict__ qhi_, const ushort* __restrict__ qlo_,
    const ushort* __restrict__ khi_, const ushort* __restrict__ klo_,
    const ushort* __restrict__ vt, const float* __restrict__ pe,
    const float* __restrict__ pvc, ushort* __restrict__ ao)
{
  extern __shared__ char sm[];   // Khi 0..32K | Klo 32K..64K | V 64K..96K

  int bid = (int)blockIdx.x;
  int bh = ((bid & 7) << 6) + (bid >> 3);    // XCD swizzle (512 = 8*64)
  int b = bh >> 3, h = bh & 7;
  int tid = threadIdx.x, lane = tid & 63, w = tid >> 6;
  int g = lane >> 4, q15 = lane & 15;
  size_t base = (size_t)bh << 14;            // *16384 elements per (b,h)
  float pvb = pvc[b] * 0.5f;

  // ---- stage K hi/lo + V: 96 spans of 1KB, 12 per wave
  #pragma unroll
  for (int t = 0; t < 12; t++){
    int sp = w*12 + t;                       // 0..95
    const ushort* gp;
    if (sp < 64){
      int mat = sp >> 5, s5 = sp & 31, kt = s5 >> 1, half = s5 & 1;
      int R = ((kt>>1)<<5) + ((q15>>2)<<3) + ((kt&1)<<2) + (q15&3);
      gp = (mat ? klo_ : khi_) + base + (size_t)R*64 + half*32 + g*8;
    } else {
      int vsp = sp - 64, mM = vsp >> 2, ht = vsp & 3;
      gp = vt + base + mM*2048 + (ht*16 + q15)*32 + g*8;
    }
    gl_lds16(gp, sm + sp*1024);
  }
  __syncthreads();

  for (int qt = 0; qt < 2; qt++){
    int qbase = ((qt<<3) + w) << 4;          // (qt*8 + w)*16
    int qg = qbase + q15;

    const ushort* qp1 = qhi_ + base + (size_t)qg*64 + (g<<3);
    const ushort* qp2 = qlo_ + base + (size_t)qg*64 + (g<<3);
    short8 qh0 = *(const short8*)(qp1);
    short8 qh1 = *(const short8*)(qp1 + 32);
    short8 ql0 = *(const short8*)(qp2);
    short8 ql1 = *(const short8*)(qp2 + 32);

    // QK^T (split 3-mfma x 2 halves)
    float4v acc[16];
    #pragma unroll
    for (int kt = 0; kt < 16; kt++){
      short8 kh0 = *(const short8*)(sm +         kt*2048 +        lane*16);
      short8 kh1 = *(const short8*)(sm +         kt*2048 + 1024 + lane*16);
      short8 kl0 = *(const short8*)(sm + 32768 + kt*2048 +        lane*16);
      short8 kl1 = *(const short8*)(sm + 32768 + kt*2048 + 1024 + lane*16);
      float4v a = {0.f,0.f,0.f,0.f};
      a = MFMA16(kh0, qh0, a);
      a = MFMA16(kh1, qh1, a);
      a = MFMA16(kh0, ql0, a);
      a = MFMA16(kh1, ql1, a);
      a = MFMA16(kl0, qh0, a);
      a = MFMA16(kl1, qh1, a);
      acc[kt] = a;
    }

    // scale + prior (permuted column) + price/vol cross-block bias
    bool qlow = (qg < 128);
    #pragma unroll
    for (int kt = 0; kt < 16; kt++){
      float4v p4 = *(const float4v*)(pe + qg*256 + ((kt>>1)<<5) + (g<<3) + ((kt&1)<<2));
      float cb = (qlow != (kt < 8)) ? pvb : 0.0f;
      #pragma unroll
      for (int r = 0; r < 4; r++)
        acc[kt][r] = acc[kt][r]*0.125f + p4[r] + cb;
    }

    // exact 128th-largest per row (MSB radix-select, sortable-uint space)
    unsigned thr = 0u; int done = 0;
    for (int bit = 31; bit >= 0; --bit){
      if (__all(done)) break;
      unsigned cand = thr | (1u << bit);
      float tf = unsort_u(cand);
      int cnt = 0;
      #pragma unroll
      for (int kt = 0; kt < 16; kt++){
        #pragma unroll
        for (int r = 0; r < 4; r++)
          cnt += (acc[kt][r] >= tf) ? 1 : 0;
      }
      cnt += __shfl_xor(cnt, 16);
      cnt += __shfl_xor(cnt, 32);
      if (!done && cnt >= 128) thr = cand;
      if (!done && cnt == 128) done = 1;
    }
    float thrf = unsort_u(thr);

    // softmax over kept (row max always kept)
    float m = -1e30f;
    #pragma unroll
    for (int kt = 0; kt < 16; kt++)
      m = fmaxf(m, fmaxf(fmaxf(acc[kt][0], acc[kt][1]), fmaxf(acc[kt][2], acc[kt][3])));
    m = fmaxf(m, __shfl_xor(m, 16));
    m = fmaxf(m, __shfl_xor(m, 32));
    float sum = 0.0f;
    #pragma unroll
    for (int kt = 0; kt < 16; kt++){
      #pragma unroll
      for (int r = 0; r < 4; r++){
        float e = (acc[kt][r] >= thrf) ? __expf(acc[kt][r] - m) : 0.0f;
        acc[kt][r] = e;
        sum += e;
      }
    }
    sum += __shfl_xor(sum, 16);
    sum += __shfl_xor(sum, 32);
    float inv = 1.0f / sum;

    // PV fully in-register; V fragments from LDS
    float4v oa[4] = {};
    #pragma unroll
    for (int mM = 0; mM < 8; mM++){
      short8 pf;
      ushort* pp = (ushort*)&pf;
      #pragma unroll
      for (int r = 0; r < 4; r++){
        pp[r]   = f2bf(acc[2*mM][r]   * inv);
        pp[r+4] = f2bf(acc[2*mM+1][r] * inv);
      }
      #pragma unroll
      for (int ht = 0; ht < 4; ht++){
        short8 vf = *(const short8*)(sm + 65536 + (mM*4 + ht)*1024 + lane*16);
        oa[ht] = MFMA16(pf, vf, oa[ht]);
      }
    }
    #pragma unroll
    for (int ht = 0; ht < 4; ht++){
      #pragma unroll
      for (int r = 0; r < 4; r++){
        int qo = qbase + (g<<2) + r;
        ao[((size_t)(b*256 + qo) << 9) + (h<<6) + (ht<<4) + q15] = f2bf(oa[ht][r]);
      }
    }
  }
}

// ---------------------------------------------------------------------------
extern "C" void kernel_launch(void* const* d_in, const int* in_sizes, int n_in,
                              void* d_out, int out_size, void* d_ws, size_t ws_size,
                              hipStream_t stream)
{
  const float* x     = (const float*)d_in[0];
  const float* Wq    = (const float*)d_in[1];
  const float* bq    = (const float*)d_in[2];
  const float* Wk    = (const float*)d_in[3];
  const float* bk    = (const float*)d_in[4];
  const float* Wv    = (const float*)d_in[5];
  const float* bv    = (const float*)d_in[6];
  const float* Wo    = (const float*)d_in[7];
  const float* bo    = (const float*)d_in[8];
  const float* prior = (const float*)d_in[9];
  const float* fimp  = (const float*)d_in[10];
  const float* W1    = (const float*)d_in[11];
  const float* b1    = (const float*)d_in[12];
  const float* W2    = (const float*)d_in[13];
  const float* b2    = (const float*)d_in[14];

  char* ws = (char*)d_ws;
  ushort* xhi  = (ushort*)(ws + 0);
  ushort* xlo  = (ushort*)(ws + 16777216);
  ushort* qhi  = (ushort*)(ws + 33554432);
  ushort* qlo  = (ushort*)(ws + 50331648);
  ushort* khi  = (ushort*)(ws + 67108864);
  ushort* klo  = (ushort*)(ws + 83886080);
  ushort* vt   = (ushort*)(ws + 100663296);    // V in MFMA fragment layout
  ushort* Wthi = (ushort*)(ws + 117440512);
  ushort* Wtlo = (ushort*)(ws + 119013376);
  ushort* Wot  = (ushort*)(ws + 120061952);
  float*  fb   = (float*) (ws + 120586240);
  float*  comb = (float*) (ws + 120592384);
  float*  pvc  = (float*) (ws + 120854528);
  float*  pe   = (float*) (ws + 120854784);
  ushort* ao   = xhi;   // alias: xhi dead after the projection GEMMs

  (void)hipFuncSetAttribute((const void*)attn_k,
      hipFuncAttributeMaxDynamicSharedMemorySize, 98304);

  cvt_x_k <<<4096, 256, 0, stream>>>(x, xhi, xlo);
  cvt_w_k <<<2049, 256, 0, stream>>>(Wq, Wk, Wv, Wo, bq, bk, bv, Wthi, Wtlo, Wot, fb);
  prior_k <<<256, 256, 0, stream>>>(prior, fimp, pe);
  pv_mean_k<<<64, 256, 0, stream>>>(x, comb);
  pv_mlp_k <<<8, 256, 0, stream>>>(comb, W1, b1, W2, b2, pvc);
  gemm_qk <<<dim3(8,128), 256, 0, stream>>>(xhi, xlo, Wthi, Wtlo, fb, qhi, qlo, khi, klo);
  gemm_pl<0><<<dim3(4,128), 256, 0, stream>>>(xhi, Wthi + (size_t)1024*512, fb + 1024, vt);
  attn_k  <<<512, 512, 98304, stream>>>(qhi, qlo, khi, klo, vt, pe, pvc, ao);
  gemm_pl<1><<<dim3(4,128), 256, 0, stream>>>(ao, Wot, bo, d_out);

  (void)in_sizes; (void)n_in; (void)out_size; (void)ws_size;
}

// Round 5
// 300.097 us; speedup vs baseline: 1.9063x; 1.7231x over previous
//
#include <hip/hip_runtime.h>

// ---------------------------------------------------------------------------
// TabularDiffFlow sparse-attention pipeline, MI355X (gfx950)
// B=64, N=256, D=512, H=8, HD=64, top-k = 128 of 256 per score row.
//
// Precision: q,k projections and QK^T in split-bf16 (hi+lo, 3 MFMAs); v/P/
// out-proj plain bf16 (absmax 3.9e-3 vs 4.65e-3 threshold, R1-R4).
//
// R5: attn = 1024 half-blocks (b,h,half): K hi/lo in 64 KB LDS (2 blocks/CU,
// 50% occ target), V overwrites K's LDS after QK^T (staged under topk VALU),
// half-major block order keeps the 128 KB pe half L2-resident. pe stored
// pre-permuted in fragment order. pv_mlp split into a 32-block hidden GEMM +
// 64-block reduce (W1 read once). PV bf16 pack via v_cvt_pk_bf16_f32.
// ---------------------------------------------------------------------------

typedef __attribute__((ext_vector_type(8))) short short8;
typedef __attribute__((ext_vector_type(4))) float float4v;

#define MFMA16(A,B,C) __builtin_amdgcn_mfma_f32_16x16x32_bf16((A),(B),(C),0,0,0)

__device__ __forceinline__ ushort f2bf(float f){
  unsigned u = __float_as_uint(f);
  unsigned r = u + 0x7FFFu + ((u >> 16) & 1u);   // round-to-nearest-even
  return (ushort)(r >> 16);
}
__device__ __forceinline__ float bf2f(ushort h){
  return __uint_as_float(((unsigned)h) << 16);
}
// inverse of the "sortable uint" map (monotone uint <-> float bits)
__device__ __forceinline__ float unsort_u(unsigned u){
  unsigned b = (u & 0x80000000u) ? (u ^ 0x80000000u) : ~u;
  return __uint_as_float(b);
}
// async global -> LDS, 16 bytes per lane; LDS dest = wave-uniform base + lane*16
__device__ __forceinline__ void gl_lds16(const void* g, void* l){
  __builtin_amdgcn_global_load_lds(
      (const __attribute__((address_space(1))) unsigned int*)g,
      (__attribute__((address_space(3))) unsigned int*)l, 16, 0, 0);
}
// pack two f32 -> one u32 of two bf16 (RNE), low16 = a, high16 = b
__device__ __forceinline__ unsigned cvt_pk_bf16(float a, float b){
  unsigned r;
  asm("v_cvt_pk_bf16_f32 %0, %1, %2" : "=v"(r) : "v"(a), "v"(b));
  return r;
}

// ---------------------------------------------------------------- cvt_x ----
__global__ __launch_bounds__(256) void cvt_x_k(const float* __restrict__ x,
                                               ushort* __restrict__ xhi,
                                               ushort* __restrict__ xlo){
  size_t i = ((size_t)blockIdx.x * 256 + threadIdx.x) * 8;
  float4v a = *(const float4v*)(x + i);
  float4v b = *(const float4v*)(x + i + 4);
  float v0=a[0],v1=a[1],v2=a[2],v3=a[3],v4=b[0],v5=b[1],v6=b[2],v7=b[3];
  ushort h0=f2bf(v0),h1=f2bf(v1),h2=f2bf(v2),h3=f2bf(v3);
  ushort h4=f2bf(v4),h5=f2bf(v5),h6=f2bf(v6),h7=f2bf(v7);
  ushort l0=f2bf(v0-bf2f(h0)),l1=f2bf(v1-bf2f(h1)),l2=f2bf(v2-bf2f(h2)),l3=f2bf(v3-bf2f(h3));
  ushort l4=f2bf(v4-bf2f(h4)),l5=f2bf(v5-bf2f(h5)),l6=f2bf(v6-bf2f(h6)),l7=f2bf(v7-bf2f(h7));
  uint4 ph, pl;
  ph.x = h0 | ((unsigned)h1<<16); ph.y = h2 | ((unsigned)h3<<16);
  ph.z = h4 | ((unsigned)h5<<16); ph.w = h6 | ((unsigned)h7<<16);
  pl.x = l0 | ((unsigned)l1<<16); pl.y = l2 | ((unsigned)l3<<16);
  pl.z = l4 | ((unsigned)l5<<16); pl.w = l6 | ((unsigned)l7<<16);
  *(uint4*)(xhi + i) = ph;
  *(uint4*)(xlo + i) = pl;
}

// ---------------------------------------------------------------- cvt_w ----
__global__ __launch_bounds__(256) void cvt_w_k(
    const float* __restrict__ Wq, const float* __restrict__ Wk,
    const float* __restrict__ Wv, const float* __restrict__ Wo,
    const float* __restrict__ bq, const float* __restrict__ bk, const float* __restrict__ bv,
    ushort* __restrict__ Wthi, ushort* __restrict__ Wtlo, ushort* __restrict__ Wot,
    float* __restrict__ fb){
  int r = blockIdx.x, t = threadIdx.x;
  if (r < 1536) {
    const float* W = (r < 512) ? Wq : ((r < 1024) ? Wk : Wv);
    int o = r & 511;
    bool dolo = (r < 1024);
    for (int i = t; i < 512; i += 256) {
      float f = W[(size_t)i*512 + o];
      ushort hi = f2bf(f);
      Wthi[(size_t)r*512 + i] = hi;
      if (dolo) Wtlo[(size_t)r*512 + i] = f2bf(f - bf2f(hi));
    }
  } else if (r < 2048) {
    int o = r - 1536;
    for (int i = t; i < 512; i += 256)
      Wot[(size_t)o*512 + i] = f2bf(Wo[(size_t)i*512 + o]);
  } else {
    for (int i = t; i < 1536; i += 256)
      fb[i] = (i < 512) ? bq[i] : ((i < 1024) ? bk[i-512] : bv[i-1024]);
  }
}

// ------------------------------------------------------------ prior_eff ----
// writes pe in the attn fragment-permuted order: slot(j) with
// kt = (j>>5)*2 | ((j>>2)&1), g = (j>>3)&3, r = j&3 -> slot = kt*16+g*4+r
__global__ __launch_bounds__(256) void prior_k(const float* __restrict__ prior,
    const float* __restrict__ fimp, float* __restrict__ pe){
  int i = blockIdx.x, j = threadIdx.x;
  int kt = ((j >> 5) << 1) | ((j >> 2) & 1);
  int g  = (j >> 3) & 3;
  int r  = j & 3;
  int slot = (kt << 4) | (g << 2) | r;
  pe[(size_t)i*256 + slot] = prior[(size_t)i*256 + j] * fimp[i] * fimp[j];
}

// -------------------------------------------------------------- pv path ----
__global__ __launch_bounds__(256) void pv_mean_k(const float* __restrict__ x,
                                                 float* __restrict__ comb){
  int b = blockIdx.x, t = threadIdx.x;
  const float* xb = x + (size_t)b * 131072;
  float p0=0.f,p1=0.f,q0=0.f,q1=0.f;
  for (int n = 0; n < 128; n++){ p0 += xb[n*512 + t]; p1 += xb[n*512 + t + 256]; }
  for (int n = 128; n < 256; n++){ q0 += xb[n*512 + t]; q1 += xb[n*512 + t + 256]; }
  const float s = 1.0f/128.0f;
  comb[(size_t)b*1024 + t]         = p0*s;
  comb[(size_t)b*1024 + t + 256]   = p1*s;
  comb[(size_t)b*1024 + 512 + t]       = q0*s;
  comb[(size_t)b*1024 + 512 + t + 256] = q1*s;
}

// hidden GEMM: hid[64][512] = silu(comb[64,1024] @ W1 + b1); 32 blocks,
// W1 read once total (128 KB slice per block).
__global__ __launch_bounds__(256) void pv_hid_k(const float* __restrict__ comb,
    const float* __restrict__ W1, const float* __restrict__ b1,
    float* __restrict__ hid){
  int ct = blockIdx.x & 15, rt = blockIdx.x >> 4;
  int t = threadIdx.x;
  int col = ct*32 + (t & 31), rs = t >> 5;       // rs 0..7
  int row0 = rt*32 + rs;
  float bb = b1[col];
  float acc[4] = {bb, bb, bb, bb};
  for (int i = 0; i < 1024; i++){
    float wv = W1[(size_t)i*512 + col];
    #pragma unroll
    for (int j = 0; j < 4; j++)
      acc[j] = fmaf(comb[(size_t)(row0 + j*8)*1024 + i], wv, acc[j]);
  }
  #pragma unroll
  for (int j = 0; j < 4; j++){
    float a = acc[j];
    hid[(size_t)(row0 + j*8)*512 + col] = a / (1.0f + __expf(-a));
  }
}

// reduce: pvc[b] = sigmoid(hid[b]·W2 + b2)
__global__ __launch_bounds__(256) void pv_out_k(const float* __restrict__ hid,
    const float* __restrict__ W2, const float* __restrict__ b2,
    float* __restrict__ pvc){
  __shared__ float red[4];
  int b = blockIdx.x, t = threadIdx.x, lane = t & 63, w = t >> 6;
  float s = fmaf(hid[(size_t)b*512 + t], W2[t], hid[(size_t)b*512 + t + 256] * W2[t + 256]);
  s += __shfl_down(s, 32); s += __shfl_down(s, 16);
  s += __shfl_down(s, 8);  s += __shfl_down(s, 4);
  s += __shfl_down(s, 2);  s += __shfl_down(s, 1);
  if (lane == 0) red[w] = s;
  __syncthreads();
  if (t == 0){
    float tot = red[0] + red[1] + red[2] + red[3];
    pvc[b] = 1.0f / (1.0f + __expf(-(tot + b2[0])));
  }
}

// ------------------------------------------------ split GEMM for q and k ---
__global__ __launch_bounds__(256) void gemm_qk(
    const ushort* __restrict__ Ahi, const ushort* __restrict__ Alo,
    const ushort* __restrict__ Bhi, const ushort* __restrict__ Blo,
    const float* __restrict__ bias,
    ushort* __restrict__ qhi, ushort* __restrict__ qlo,
    ushort* __restrict__ khi, ushort* __restrict__ klo)
{
  __shared__ __align__(16) ushort As[2][128][40];
  __shared__ __align__(16) ushort Bs[2][128][40];
  int n0 = blockIdx.x * 128, m0 = blockIdx.y * 128;
  int tid = threadIdx.x, lane = tid & 63, w = tid >> 6, wm = w >> 1, wn = w & 1;
  float4v acc[4][4] = {};
  for (int k0 = 0; k0 < 512; k0 += 32){
    for (int c = tid; c < 512; c += 256){
      int row = c >> 2, ch = c & 3;
      *(uint4*)(&As[0][row][ch*8]) = *(const uint4*)(Ahi + (size_t)(m0+row)*512 + k0 + ch*8);
      *(uint4*)(&As[1][row][ch*8]) = *(const uint4*)(Alo + (size_t)(m0+row)*512 + k0 + ch*8);
      *(uint4*)(&Bs[0][row][ch*8]) = *(const uint4*)(Bhi + (size_t)(n0+row)*512 + k0 + ch*8);
      *(uint4*)(&Bs[1][row][ch*8]) = *(const uint4*)(Blo + (size_t)(n0+row)*512 + k0 + ch*8);
    }
    __syncthreads();
    short8 ah[4], al[4], bh[4], bl[4];
    #pragma unroll
    for (int i = 0; i < 4; i++){
      ah[i] = *(const short8*)(&As[0][wm*64 + i*16 + (lane&15)][(lane>>4)*8]);
      al[i] = *(const short8*)(&As[1][wm*64 + i*16 + (lane&15)][(lane>>4)*8]);
      bh[i] = *(const short8*)(&Bs[0][wn*64 + i*16 + (lane&15)][(lane>>4)*8]);
      bl[i] = *(const short8*)(&Bs[1][wn*64 + i*16 + (lane&15)][(lane>>4)*8]);
    }
    #pragma unroll
    for (int mi = 0; mi < 4; mi++){
      #pragma unroll
      for (int ni = 0; ni < 4; ni++){
        acc[mi][ni] = MFMA16(ah[mi], bh[ni], acc[mi][ni]);
        acc[mi][ni] = MFMA16(ah[mi], bl[ni], acc[mi][ni]);
        acc[mi][ni] = MFMA16(al[mi], bh[ni], acc[mi][ni]);
      }
    }
    __syncthreads();
  }
  #pragma unroll
  for (int mi = 0; mi < 4; mi++){
    #pragma unroll
    for (int ni = 0; ni < 4; ni++){
      #pragma unroll
      for (int r = 0; r < 4; r++){
        int rg = m0 + wm*64 + mi*16 + ((lane>>4)<<2) + r;
        int cg = n0 + wn*64 + ni*16 + (lane&15);
        float val = acc[mi][ni][r] + bias[cg];
        int which = cg >> 9, within = cg & 511;
        int bb = rg >> 8, seq = rg & 255, hh = within >> 6, hd = within & 63;
        size_t idx = ((size_t)((bb*8 + hh)*256 + seq))*64 + hd;
        ushort hi_ = f2bf(val);
        ushort lo_ = f2bf(val - bf2f(hi_));
        if (which == 0) { qhi[idx] = hi_; qlo[idx] = lo_; }
        else            { khi[idx] = hi_; klo[idx] = lo_; }
      }
    }
  }
}

// ------------------------------------------- plain bf16 GEMM (v, out-proj) -
// EPI=0: out = bf16 V in MFMA-fragment layout: (k,hd) of head (b,h) at
//        ((b*8+h)<<14) + ((k>>5)*64 + hd)*32 + (k&31).
// EPI=1: out = fp32 [M][512].
template<int EPI>
__global__ __launch_bounds__(256) void gemm_pl(
    const ushort* __restrict__ A, const ushort* __restrict__ Bt,
    const float* __restrict__ bias, void* __restrict__ outp)
{
  __shared__ __align__(16) ushort As[128][40];
  __shared__ __align__(16) ushort Bs[128][40];
  int n0 = blockIdx.x * 128, m0 = blockIdx.y * 128;
  int tid = threadIdx.x, lane = tid & 63, w = tid >> 6, wm = w >> 1, wn = w & 1;
  float4v acc[4][4] = {};
  for (int k0 = 0; k0 < 512; k0 += 32){
    for (int c = tid; c < 512; c += 256){
      int row = c >> 2, ch = c & 3;
      *(uint4*)(&As[row][ch*8]) = *(const uint4*)(A  + (size_t)(m0+row)*512 + k0 + ch*8);
      *(uint4*)(&Bs[row][ch*8]) = *(const uint4*)(Bt + (size_t)(n0+row)*512 + k0 + ch*8);
    }
    __syncthreads();
    short8 af[4], bg4[4];
    #pragma unroll
    for (int i = 0; i < 4; i++){
      af[i]  = *(const short8*)(&As[wm*64 + i*16 + (lane&15)][(lane>>4)*8]);
      bg4[i] = *(const short8*)(&Bs[wn*64 + i*16 + (lane&15)][(lane>>4)*8]);
    }
    #pragma unroll
    for (int mi = 0; mi < 4; mi++){
      #pragma unroll
      for (int ni = 0; ni < 4; ni++)
        acc[mi][ni] = MFMA16(af[mi], bg4[ni], acc[mi][ni]);
    }
    __syncthreads();
  }
  #pragma unroll
  for (int mi = 0; mi < 4; mi++){
    #pragma unroll
    for (int ni = 0; ni < 4; ni++){
      int rg0 = m0 + wm*64 + mi*16 + ((lane>>4)<<2);
      int cg  = n0 + wn*64 + ni*16 + (lane&15);
      if (EPI == 0){
        int bb = rg0 >> 8, seq0 = rg0 & 255;
        int hh = cg >> 6, hd = cg & 63;
        int kb = seq0 >> 5, wi = seq0 & 31;
        float b_ = bias[cg];
        uint2 pk;
        pk.x = (unsigned)f2bf(acc[mi][ni][0] + b_) | ((unsigned)f2bf(acc[mi][ni][1] + b_) << 16);
        pk.y = (unsigned)f2bf(acc[mi][ni][2] + b_) | ((unsigned)f2bf(acc[mi][ni][3] + b_) << 16);
        size_t off = ((size_t)(bb*8 + hh) << 14) + (size_t)(((kb<<6) + hd) << 5) + wi;
        *(uint2*)((ushort*)outp + off) = pk;
      } else {
        float b_ = bias[cg];
        #pragma unroll
        for (int r = 0; r < 4; r++)
          ((float*)outp)[(size_t)(rg0 + r)*512 + cg] = acc[mi][ni][r] + b_;
      }
    }
  }
}

// ------------------------------------------------------ fused attention ----
// 1024 blocks = (half-major, bh XCD-swizzled). 8 waves x 16 q-rows = 128 rows.
// LDS 64 KB = K hi/lo (rho-permuted, fragment-major). After QK^T the K region
// is overwritten with V (staged under the topk VALU phase). pe pre-permuted,
// L2-resident because all concurrent blocks share one 128 KB half.
__global__ __launch_bounds__(512, 4) void attn_k(
    const ushort* __restrict__ qhi_, const ushort* __restrict__ qlo_,
    const ushort* __restrict__ khi_, const ushort* __restrict__ klo_,
    const ushort* __restrict__ vt, const float* __restrict__ pe,
    const float* __restrict__ pvc, ushort* __restrict__ ao)
{
  extern __shared__ char sm[];   // 64KB: Khi 0..32K | Klo 32..64K; V -> 0..32K

  int bid = (int)blockIdx.x;
  int half = bid >> 9, s = bid & 511;
  int bh = ((s & 7) << 6) + (s >> 3);        // XCD swizzle (512 = 8*64)
  int b = bh >> 3, h = bh & 7;
  int tid = threadIdx.x, lane = tid & 63, w = tid >> 6;
  int g = lane >> 4, q15 = lane & 15;
  size_t base = (size_t)bh << 14;            // *16384 elements per (b,h)
  int qbase = (half << 7) + (w << 4);
  int qg = qbase + q15;
  float pvb = pvc[b] * 0.5f;

  // prefetch q fragments (hi+lo) while staging K
  const ushort* qp1 = qhi_ + base + (size_t)qg*64 + (g<<3);
  const ushort* qp2 = qlo_ + base + (size_t)qg*64 + (g<<3);
  short8 qh0 = *(const short8*)(qp1);
  short8 qh1 = *(const short8*)(qp1 + 32);
  short8 ql0 = *(const short8*)(qp2);
  short8 ql1 = *(const short8*)(qp2 + 32);

  // ---- stage K hi/lo: 64 spans of 1KB, 8 per wave, rho-permuted rows
  #pragma unroll
  for (int t = 0; t < 8; t++){
    int sp = (w<<3) + t;                     // 0..63
    int mat = sp >> 5, s5 = sp & 31, kt = s5 >> 1, hf = s5 & 1;
    int R = ((kt>>1)<<5) + ((q15>>2)<<3) + ((kt&1)<<2) + (q15&3);
    const ushort* gp = (mat ? klo_ : khi_) + base + (size_t)R*64 + hf*32 + g*8;
    gl_lds16(gp, sm + sp*1024);
  }
  __syncthreads();

  // ---- QK^T (split 3-mfma x 2 halves)
  float4v acc[16];
  #pragma unroll
  for (int kt = 0; kt < 16; kt++){
    short8 kh0 = *(const short8*)(sm +         kt*2048 +        lane*16);
    short8 kh1 = *(const short8*)(sm +         kt*2048 + 1024 + lane*16);
    short8 kl0 = *(const short8*)(sm + 32768 + kt*2048 +        lane*16);
    short8 kl1 = *(const short8*)(sm + 32768 + kt*2048 + 1024 + lane*16);
    float4v a = {0.f,0.f,0.f,0.f};
    a = MFMA16(kh0, qh0, a);
    a = MFMA16(kh1, qh1, a);
    a = MFMA16(kh0, ql0, a);
    a = MFMA16(kh1, ql1, a);
    a = MFMA16(kl0, qh0, a);
    a = MFMA16(kl1, qh1, a);
    acc[kt] = a;
  }
  __syncthreads();                           // all K LDS reads complete

  // ---- stage V into the K region (latency hides under bias/topk/softmax)
  #pragma unroll
  for (int t = 0; t < 4; t++){
    int vsp = (w<<2) + t;                    // 0..31
    int mM = vsp >> 2, ht = vsp & 3;
    gl_lds16(vt + base + mM*2048 + (ht*16 + q15)*32 + g*8, sm + vsp*1024);
  }

  // ---- scale + permuted prior + price/vol cross-block bias
  bool qlow = (qg < 128);
  #pragma unroll
  for (int kt = 0; kt < 16; kt++){
    float4v p4 = *(const float4v*)(pe + qg*256 + (kt<<4) + (g<<2));
    float cb = (qlow != (kt < 8)) ? pvb : 0.0f;
    #pragma unroll
    for (int r = 0; r < 4; r++)
      acc[kt][r] = acc[kt][r]*0.125f + p4[r] + cb;
  }

  // ---- exact 128th-largest per row (MSB radix-select, sortable-uint space)
  unsigned thr = 0u; int done = 0;
  for (int bit = 31; bit >= 0; --bit){
    if (__all(done)) break;
    unsigned cand = thr | (1u << bit);
    float tf = unsort_u(cand);
    int cnt = 0;
    #pragma unroll
    for (int kt = 0; kt < 16; kt++){
      #pragma unroll
      for (int r = 0; r < 4; r++)
        cnt += (acc[kt][r] >= tf) ? 1 : 0;
    }
    cnt += __shfl_xor(cnt, 16);
    cnt += __shfl_xor(cnt, 32);
    if (!done && cnt >= 128) thr = cand;
    if (!done && cnt == 128) done = 1;
  }
  float thrf = unsort_u(thr);

  // ---- softmax over kept (row max always kept)
  float m = -1e30f;
  #pragma unroll
  for (int kt = 0; kt < 16; kt++)
    m = fmaxf(m, fmaxf(fmaxf(acc[kt][0], acc[kt][1]), fmaxf(acc[kt][2], acc[kt][3])));
  m = fmaxf(m, __shfl_xor(m, 16));
  m = fmaxf(m, __shfl_xor(m, 32));
  float sum = 0.0f;
  #pragma unroll
  for (int kt = 0; kt < 16; kt++){
    #pragma unroll
    for (int r = 0; r < 4; r++){
      float e = (acc[kt][r] >= thrf) ? __expf(acc[kt][r] - m) : 0.0f;
      acc[kt][r] = e;
      sum += e;
    }
  }
  sum += __shfl_xor(sum, 16);
  sum += __shfl_xor(sum, 32);
  float inv = 1.0f / sum;

  __syncthreads();                           // V staged (vmcnt drained)

  // ---- PV fully in-register; V fragments from LDS
  float4v oa[4] = {};
  #pragma unroll
  for (int mM = 0; mM < 8; mM++){
    uint4 pk;
    pk.x = cvt_pk_bf16(acc[2*mM][0]*inv,   acc[2*mM][1]*inv);
    pk.y = cvt_pk_bf16(acc[2*mM][2]*inv,   acc[2*mM][3]*inv);
    pk.z = cvt_pk_bf16(acc[2*mM+1][0]*inv, acc[2*mM+1][1]*inv);
    pk.w = cvt_pk_bf16(acc[2*mM+1][2]*inv, acc[2*mM+1][3]*inv);
    short8 pf = *(short8*)&pk;
    #pragma unroll
    for (int ht = 0; ht < 4; ht++){
      short8 vf = *(const short8*)(sm + (mM*4 + ht)*1024 + lane*16);
      oa[ht] = MFMA16(pf, vf, oa[ht]);
    }
  }
  #pragma unroll
  for (int ht = 0; ht < 4; ht++){
    #pragma unroll
    for (int r = 0; r < 4; r++){
      int qo = qbase + (g<<2) + r;
      ao[((size_t)(b*256 + qo) << 9) + (h<<6) + (ht<<4) + q15] = f2bf(oa[ht][r]);
    }
  }
}

// ---------------------------------------------------------------------------
extern "C" void kernel_launch(void* const* d_in, const int* in_sizes, int n_in,
                              void* d_out, int out_size, void* d_ws, size_t ws_size,
                              hipStream_t stream)
{
  const float* x     = (const float*)d_in[0];
  const float* Wq    = (const float*)d_in[1];
  const float* bq    = (const float*)d_in[2];
  const float* Wk    = (const float*)d_in[3];
  const float* bk    = (const float*)d_in[4];
  const float* Wv    = (const float*)d_in[5];
  const float* bv    = (const float*)d_in[6];
  const float* Wo    = (const float*)d_in[7];
  const float* bo    = (const float*)d_in[8];
  const float* prior = (const float*)d_in[9];
  const float* fimp  = (const float*)d_in[10];
  const float* W1    = (const float*)d_in[11];
  const float* b1    = (const float*)d_in[12];
  const float* W2    = (const float*)d_in[13];
  const float* b2    = (const float*)d_in[14];

  char* ws = (char*)d_ws;
  ushort* xhi  = (ushort*)(ws + 0);
  ushort* xlo  = (ushort*)(ws + 16777216);
  ushort* qhi  = (ushort*)(ws + 33554432);
  ushort* qlo  = (ushort*)(ws + 50331648);
  ushort* khi  = (ushort*)(ws + 67108864);
  ushort* klo  = (ushort*)(ws + 83886080);
  ushort* vt   = (ushort*)(ws + 100663296);    // V in MFMA fragment layout
  ushort* Wthi = (ushort*)(ws + 117440512);
  ushort* Wtlo = (ushort*)(ws + 119013376);
  ushort* Wot  = (ushort*)(ws + 120061952);
  float*  fb   = (float*) (ws + 120586240);
  float*  comb = (float*) (ws + 120592384);
  float*  pvc  = (float*) (ws + 120854528);
  float*  pe   = (float*) (ws + 120854784);    // 256 KB (perm layout)
  float*  hid  = (float*) (ws + 121116928);    // 128 KB
  ushort* ao   = xhi;   // alias: xhi dead after the projection GEMMs

  (void)hipFuncSetAttribute((const void*)attn_k,
      hipFuncAttributeMaxDynamicSharedMemorySize, 65536);

  cvt_x_k <<<4096, 256, 0, stream>>>(x, xhi, xlo);
  cvt_w_k <<<2049, 256, 0, stream>>>(Wq, Wk, Wv, Wo, bq, bk, bv, Wthi, Wtlo, Wot, fb);
  prior_k <<<256, 256, 0, stream>>>(prior, fimp, pe);
  pv_mean_k<<<64, 256, 0, stream>>>(x, comb);
  pv_hid_k <<<32, 256, 0, stream>>>(comb, W1, b1, hid);
  pv_out_k <<<64, 256, 0, stream>>>(hid, W2, b2, pvc);
  gemm_qk <<<dim3(8,128), 256, 0, stream>>>(xhi, xlo, Wthi, Wtlo, fb, qhi, qlo, khi, klo);
  gemm_pl<0><<<dim3(4,128), 256, 0, stream>>>(xhi, Wthi + (size_t)1024*512, fb + 1024, vt);
  attn_k  <<<1024, 512, 65536, stream>>>(qhi, qlo, khi, klo, vt, pe, pvc, ao);
  gemm_pl<1><<<dim3(4,128), 256, 0, stream>>>(ao, Wot, bo, d_out);

  (void)in_sizes; (void)n_in; (void)out_size; (void)ws_size;
}

// Round 6
// 290.723 us; speedup vs baseline: 1.9677x; 1.0322x over previous
//
#include <hip/hip_runtime.h>

// ---------------------------------------------------------------------------
// TabularDiffFlow sparse-attention pipeline, MI355X (gfx950)
// B=64, N=256, D=512, H=8, HD=64, top-k = 128 of 256 per score row.
//
// Precision: q,k projections and QK^T in split-bf16 (hi+lo, 3 MFMAs); v/P/
// out-proj plain bf16 (absmax 3.9e-3 vs 4.65e-3 threshold, R1-R5).
//
// R6: GEMMs switched to m97-style global_load_lds(16B) staging with LINEAR
// row-major LDS tiles and coalesced global sources (R3's regression was a
// frag-permuted global source = uncoalesced; this keeps both sides linear).
// attn: exp2-domain fold (pe pre-multiplied by log2e; scale = 0.125*log2e),
// monotone => identical top-k selection, cheaper exp.
// ---------------------------------------------------------------------------

typedef __attribute__((ext_vector_type(8))) short short8;
typedef __attribute__((ext_vector_type(4))) float float4v;

#define MFMA16(A,B,C) __builtin_amdgcn_mfma_f32_16x16x32_bf16((A),(B),(C),0,0,0)
#define LOG2E 1.4426950408889634f

__device__ __forceinline__ ushort f2bf(float f){
  unsigned u = __float_as_uint(f);
  unsigned r = u + 0x7FFFu + ((u >> 16) & 1u);   // round-to-nearest-even
  return (ushort)(r >> 16);
}
__device__ __forceinline__ float bf2f(ushort h){
  return __uint_as_float(((unsigned)h) << 16);
}
// inverse of the "sortable uint" map (monotone uint <-> float bits)
__device__ __forceinline__ float unsort_u(unsigned u){
  unsigned b = (u & 0x80000000u) ? (u ^ 0x80000000u) : ~u;
  return __uint_as_float(b);
}
// async global -> LDS, 16 bytes per lane; LDS dest = wave-uniform base + lane*16
__device__ __forceinline__ void gl_lds16(const void* g, void* l){
  __builtin_amdgcn_global_load_lds(
      (const __attribute__((address_space(1))) unsigned int*)g,
      (__attribute__((address_space(3))) unsigned int*)l, 16, 0, 0);
}
// pack two f32 -> one u32 of two bf16 (RNE), low16 = a, high16 = b
__device__ __forceinline__ unsigned cvt_pk_bf16(float a, float b){
  unsigned r;
  asm("v_cvt_pk_bf16_f32 %0, %1, %2" : "=v"(r) : "v"(a), "v"(b));
  return r;
}

// ---------------------------------------------------------------- cvt_x ----
__global__ __launch_bounds__(256) void cvt_x_k(const float* __restrict__ x,
                                               ushort* __restrict__ xhi,
                                               ushort* __restrict__ xlo){
  size_t i = ((size_t)blockIdx.x * 256 + threadIdx.x) * 8;
  float4v a = *(const float4v*)(x + i);
  float4v b = *(const float4v*)(x + i + 4);
  float v0=a[0],v1=a[1],v2=a[2],v3=a[3],v4=b[0],v5=b[1],v6=b[2],v7=b[3];
  ushort h0=f2bf(v0),h1=f2bf(v1),h2=f2bf(v2),h3=f2bf(v3);
  ushort h4=f2bf(v4),h5=f2bf(v5),h6=f2bf(v6),h7=f2bf(v7);
  ushort l0=f2bf(v0-bf2f(h0)),l1=f2bf(v1-bf2f(h1)),l2=f2bf(v2-bf2f(h2)),l3=f2bf(v3-bf2f(h3));
  ushort l4=f2bf(v4-bf2f(h4)),l5=f2bf(v5-bf2f(h5)),l6=f2bf(v6-bf2f(h6)),l7=f2bf(v7-bf2f(h7));
  uint4 ph, pl;
  ph.x = h0 | ((unsigned)h1<<16); ph.y = h2 | ((unsigned)h3<<16);
  ph.z = h4 | ((unsigned)h5<<16); ph.w = h6 | ((unsigned)h7<<16);
  pl.x = l0 | ((unsigned)l1<<16); pl.y = l2 | ((unsigned)l3<<16);
  pl.z = l4 | ((unsigned)l5<<16); pl.w = l6 | ((unsigned)l7<<16);
  *(uint4*)(xhi + i) = ph;
  *(uint4*)(xlo + i) = pl;
}

// ---------------------------------------------------------------- cvt_w ----
__global__ __launch_bounds__(256) void cvt_w_k(
    const float* __restrict__ Wq, const float* __restrict__ Wk,
    const float* __restrict__ Wv, const float* __restrict__ Wo,
    const float* __restrict__ bq, const float* __restrict__ bk, const float* __restrict__ bv,
    ushort* __restrict__ Wthi, ushort* __restrict__ Wtlo, ushort* __restrict__ Wot,
    float* __restrict__ fb){
  int r = blockIdx.x, t = threadIdx.x;
  if (r < 1536) {
    const float* W = (r < 512) ? Wq : ((r < 1024) ? Wk : Wv);
    int o = r & 511;
    bool dolo = (r < 1024);
    for (int i = t; i < 512; i += 256) {
      float f = W[(size_t)i*512 + o];
      ushort hi = f2bf(f);
      Wthi[(size_t)r*512 + i] = hi;
      if (dolo) Wtlo[(size_t)r*512 + i] = f2bf(f - bf2f(hi));
    }
  } else if (r < 2048) {
    int o = r - 1536;
    for (int i = t; i < 512; i += 256)
      Wot[(size_t)o*512 + i] = f2bf(Wo[(size_t)i*512 + o]);
  } else {
    for (int i = t; i < 1536; i += 256)
      fb[i] = (i < 512) ? bq[i] : ((i < 1024) ? bk[i-512] : bv[i-1024]);
  }
}

// ------------------------------------------------------------ prior_eff ----
// writes pe2 = prior*imp_i*imp_j*LOG2E in the attn fragment-permuted order
__global__ __launch_bounds__(256) void prior_k(const float* __restrict__ prior,
    const float* __restrict__ fimp, float* __restrict__ pe){
  int i = blockIdx.x, j = threadIdx.x;
  int kt = ((j >> 5) << 1) | ((j >> 2) & 1);
  int g  = (j >> 3) & 3;
  int r  = j & 3;
  int slot = (kt << 4) | (g << 2) | r;
  pe[(size_t)i*256 + slot] = prior[(size_t)i*256 + j] * fimp[i] * fimp[j] * LOG2E;
}

// -------------------------------------------------------------- pv path ----
__global__ __launch_bounds__(256) void pv_mean_k(const float* __restrict__ x,
                                                 float* __restrict__ comb){
  int b = blockIdx.x, t = threadIdx.x;
  const float* xb = x + (size_t)b * 131072;
  float p0=0.f,p1=0.f,q0=0.f,q1=0.f;
  for (int n = 0; n < 128; n++){ p0 += xb[n*512 + t]; p1 += xb[n*512 + t + 256]; }
  for (int n = 128; n < 256; n++){ q0 += xb[n*512 + t]; q1 += xb[n*512 + t + 256]; }
  const float s = 1.0f/128.0f;
  comb[(size_t)b*1024 + t]         = p0*s;
  comb[(size_t)b*1024 + t + 256]   = p1*s;
  comb[(size_t)b*1024 + 512 + t]       = q0*s;
  comb[(size_t)b*1024 + 512 + t + 256] = q1*s;
}

// hidden GEMM: hid[64][512] = silu(comb @ W1 + b1); 32 blocks
__global__ __launch_bounds__(256) void pv_hid_k(const float* __restrict__ comb,
    const float* __restrict__ W1, const float* __restrict__ b1,
    float* __restrict__ hid){
  int ct = blockIdx.x & 15, rt = blockIdx.x >> 4;
  int t = threadIdx.x;
  int col = ct*32 + (t & 31), rs = t >> 5;
  int row0 = rt*32 + rs;
  float bb = b1[col];
  float acc[4] = {bb, bb, bb, bb};
  for (int i = 0; i < 1024; i++){
    float wv = W1[(size_t)i*512 + col];
    #pragma unroll
    for (int j = 0; j < 4; j++)
      acc[j] = fmaf(comb[(size_t)(row0 + j*8)*1024 + i], wv, acc[j]);
  }
  #pragma unroll
  for (int j = 0; j < 4; j++){
    float a = acc[j];
    hid[(size_t)(row0 + j*8)*512 + col] = a / (1.0f + __expf(-a));
  }
}

__global__ __launch_bounds__(256) void pv_out_k(const float* __restrict__ hid,
    const float* __restrict__ W2, const float* __restrict__ b2,
    float* __restrict__ pvc){
  __shared__ float red[4];
  int b = blockIdx.x, t = threadIdx.x, lane = t & 63, w = t >> 6;
  float s = fmaf(hid[(size_t)b*512 + t], W2[t], hid[(size_t)b*512 + t + 256] * W2[t + 256]);
  s += __shfl_down(s, 32); s += __shfl_down(s, 16);
  s += __shfl_down(s, 8);  s += __shfl_down(s, 4);
  s += __shfl_down(s, 2);  s += __shfl_down(s, 1);
  if (lane == 0) red[w] = s;
  __syncthreads();
  if (t == 0){
    float tot = red[0] + red[1] + red[2] + red[3];
    pvc[b] = 1.0f / (1.0f + __expf(-(tot + b2[0])));
  }
}

// ------------------------------------------------ split GEMM for q and k ---
// m97-style: global_load_lds(16B) into LINEAR [128][32] LDS tiles (1 per
// matrix), coalesced global source (4 lanes = 64B run per row). 2-barrier.
__global__ __launch_bounds__(256) void gemm_qk(
    const ushort* __restrict__ Ahi, const ushort* __restrict__ Alo,
    const ushort* __restrict__ Bhi, const ushort* __restrict__ Blo,
    const float* __restrict__ bias,
    ushort* __restrict__ qhi, ushort* __restrict__ qlo,
    ushort* __restrict__ khi, ushort* __restrict__ klo)
{
  __shared__ __align__(16) char sm[32768];   // Ahi | Alo | Bhi | Blo (8K each)
  int flat = (int)blockIdx.x;                // 1024 blocks
  int round = flat >> 7, rem = flat & 127;
  int sw = (round << 7) + ((rem & 7) << 4) + (rem >> 3);  // XCD-chunked swizzle
  int n0 = (sw & 7) * 128, m0 = (sw >> 3) * 128;
  int tid = threadIdx.x, lane = tid & 63, w = tid >> 6, wm = w >> 1, wn = w & 1;
  int q15 = lane & 15, g = lane >> 4;
  int lrow = lane >> 2, lcol = (lane & 3) * 8;   // staging: 16 rows x 64B per wave
  float4v acc[4][4] = {};
  for (int k0 = 0; k0 < 512; k0 += 32){
    #pragma unroll
    for (int t = 0; t < 8; t++){
      int id = (w << 3) + t;                 // 0..31
      int mat = id >> 3, sp = id & 7;
      int row = ((mat < 2) ? m0 : n0) + sp*16 + lrow;
      const ushort* src;
      if      (mat == 0) src = Ahi + (size_t)row*512 + k0 + lcol;
      else if (mat == 1) src = Alo + (size_t)row*512 + k0 + lcol;
      else if (mat == 2) src = Bhi + (size_t)row*512 + k0 + lcol;
      else               src = Blo + (size_t)row*512 + k0 + lcol;
      gl_lds16(src, sm + (id << 10));
    }
    __syncthreads();
    short8 ah[4], al[4], bh[4], bl[4];
    #pragma unroll
    for (int i = 0; i < 4; i++){
      int ra = (wm*64 + i*16 + q15)*64 + g*16;
      int rb = (wn*64 + i*16 + q15)*64 + g*16;
      ah[i] = *(const short8*)(sm +         ra);
      al[i] = *(const short8*)(sm + 8192  + ra);
      bh[i] = *(const short8*)(sm + 16384 + rb);
      bl[i] = *(const short8*)(sm + 24576 + rb);
    }
    #pragma unroll
    for (int mi = 0; mi < 4; mi++){
      #pragma unroll
      for (int ni = 0; ni < 4; ni++){
        acc[mi][ni] = MFMA16(ah[mi], bh[ni], acc[mi][ni]);
        acc[mi][ni] = MFMA16(ah[mi], bl[ni], acc[mi][ni]);
        acc[mi][ni] = MFMA16(al[mi], bh[ni], acc[mi][ni]);
      }
    }
    __syncthreads();
  }
  #pragma unroll
  for (int mi = 0; mi < 4; mi++){
    #pragma unroll
    for (int ni = 0; ni < 4; ni++){
      #pragma unroll
      for (int r = 0; r < 4; r++){
        int rg = m0 + wm*64 + mi*16 + (g<<2) + r;
        int cg = n0 + wn*64 + ni*16 + q15;
        float val = acc[mi][ni][r] + bias[cg];
        int which = cg >> 9, within = cg & 511;
        int bb = rg >> 8, seq = rg & 255, hh = within >> 6, hd = within & 63;
        size_t idx = ((size_t)((bb*8 + hh)*256 + seq))*64 + hd;
        ushort hi_ = f2bf(val);
        ushort lo_ = f2bf(val - bf2f(hi_));
        if (which == 0) { qhi[idx] = hi_; qlo[idx] = lo_; }
        else            { khi[idx] = hi_; klo[idx] = lo_; }
      }
    }
  }
}

// ------------------------------------------- plain bf16 GEMM (v, out-proj) -
// EPI=0: out = bf16 V in MFMA-fragment layout: (k,hd) of head (b,h) at
//        ((b*8+h)<<14) + ((k>>5)*64 + hd)*32 + (k&31).
// EPI=1: out = fp32 [M][512].
template<int EPI>
__global__ __launch_bounds__(256) void gemm_pl(
    const ushort* __restrict__ A, const ushort* __restrict__ Bt,
    const float* __restrict__ bias, void* __restrict__ outp)
{
  __shared__ __align__(16) char sm[16384];   // A 0..8K | B 8K..16K
  int flat = (int)blockIdx.x;                // 512 blocks
  int round = flat >> 7, rem = flat & 127;
  int sw = (round << 7) + ((rem & 7) << 4) + (rem >> 3);
  int n0 = (sw & 3) * 128, m0 = (sw >> 2) * 128;
  int tid = threadIdx.x, lane = tid & 63, w = tid >> 6, wm = w >> 1, wn = w & 1;
  int q15 = lane & 15, g = lane >> 4;
  int lrow = lane >> 2, lcol = (lane & 3) * 8;
  float4v acc[4][4] = {};
  for (int k0 = 0; k0 < 512; k0 += 32){
    #pragma unroll
    for (int t = 0; t < 4; t++){
      int id = (w << 2) + t;                 // 0..15
      int mat = id >> 3, sp = id & 7;
      int row = ((mat == 0) ? m0 : n0) + sp*16 + lrow;
      const ushort* src = ((mat == 0) ? A : Bt) + (size_t)row*512 + k0 + lcol;
      gl_lds16(src, sm + (id << 10));
    }
    __syncthreads();
    short8 af[4], bg4[4];
    #pragma unroll
    for (int i = 0; i < 4; i++){
      int ra = (wm*64 + i*16 + q15)*64 + g*16;
      int rb = (wn*64 + i*16 + q15)*64 + g*16;
      af[i]  = *(const short8*)(sm +        ra);
      bg4[i] = *(const short8*)(sm + 8192 + rb);
    }
    #pragma unroll
    for (int mi = 0; mi < 4; mi++){
      #pragma unroll
      for (int ni = 0; ni < 4; ni++)
        acc[mi][ni] = MFMA16(af[mi], bg4[ni], acc[mi][ni]);
    }
    __syncthreads();
  }
  #pragma unroll
  for (int mi = 0; mi < 4; mi++){
    #pragma unroll
    for (int ni = 0; ni < 4; ni++){
      int rg0 = m0 + wm*64 + mi*16 + (g<<2);
      int cg  = n0 + wn*64 + ni*16 + q15;
      if (EPI == 0){
        int bb = rg0 >> 8, seq0 = rg0 & 255;
        int hh = cg >> 6, hd = cg & 63;
        int kb = seq0 >> 5, wi = seq0 & 31;
        float b_ = bias[cg];
        uint2 pk;
        pk.x = (unsigned)f2bf(acc[mi][ni][0] + b_) | ((unsigned)f2bf(acc[mi][ni][1] + b_) << 16);
        pk.y = (unsigned)f2bf(acc[mi][ni][2] + b_) | ((unsigned)f2bf(acc[mi][ni][3] + b_) << 16);
        size_t off = ((size_t)(bb*8 + hh) << 14) + (size_t)(((kb<<6) + hd) << 5) + wi;
        *(uint2*)((ushort*)outp + off) = pk;
      } else {
        float b_ = bias[cg];
        #pragma unroll
        for (int r = 0; r < 4; r++)
          ((float*)outp)[(size_t)(rg0 + r)*512 + cg] = acc[mi][ni][r] + b_;
      }
    }
  }
}

// ------------------------------------------------------ fused attention ----
// 1024 blocks = (half-major, bh XCD-swizzled), 8 waves x 16 q-rows.
// LDS 64 KB = K hi/lo (rho-permuted fragment-major); V overwrites K region
// after QK^T. All score math in the exp2 (log2e-scaled) domain: selection is
// monotone-invariant, softmax exp becomes raw v_exp_f32.
__global__ __launch_bounds__(512, 4) void attn_k(
    const ushort* __restrict__ qhi_, const ushort* __restrict__ qlo_,
    const ushort* __restrict__ khi_, const ushort* __restrict__ klo_,
    const ushort* __restrict__ vt, const float* __restrict__ pe,
    const float* __restrict__ pvc, ushort* __restrict__ ao)
{
  extern __shared__ char sm[];   // 64KB: Khi 0..32K | Klo 32..64K; V -> 0..32K

  int bid = (int)blockIdx.x;
  int half = bid >> 9, s = bid & 511;
  int bh = ((s & 7) << 6) + (s >> 3);        // XCD swizzle (512 = 8*64)
  int b = bh >> 3, h = bh & 7;
  int tid = threadIdx.x, lane = tid & 63, w = tid >> 6;
  int g = lane >> 4, q15 = lane & 15;
  size_t base = (size_t)bh << 14;
  int qbase = (half << 7) + (w << 4);
  int qg = qbase + q15;
  float pvb2 = pvc[b] * (0.5f * LOG2E);
  const float scale2 = 0.125f * LOG2E;

  const ushort* qp1 = qhi_ + base + (size_t)qg*64 + (g<<3);
  const ushort* qp2 = qlo_ + base + (size_t)qg*64 + (g<<3);
  short8 qh0 = *(const short8*)(qp1);
  short8 qh1 = *(const short8*)(qp1 + 32);
  short8 ql0 = *(const short8*)(qp2);
  short8 ql1 = *(const short8*)(qp2 + 32);

  // ---- stage K hi/lo: 64 spans of 1KB, 8 per wave, rho-permuted rows
  #pragma unroll
  for (int t = 0; t < 8; t++){
    int sp = (w<<3) + t;
    int mat = sp >> 5, s5 = sp & 31, kt = s5 >> 1, hf = s5 & 1;
    int R = ((kt>>1)<<5) + ((q15>>2)<<3) + ((kt&1)<<2) + (q15&3);
    const ushort* gp = (mat ? klo_ : khi_) + base + (size_t)R*64 + hf*32 + g*8;
    gl_lds16(gp, sm + sp*1024);
  }
  __syncthreads();

  // ---- QK^T (split 3-mfma x 2 halves)
  float4v acc[16];
  #pragma unroll
  for (int kt = 0; kt < 16; kt++){
    short8 kh0 = *(const short8*)(sm +         kt*2048 +        lane*16);
    short8 kh1 = *(const short8*)(sm +         kt*2048 + 1024 + lane*16);
    short8 kl0 = *(const short8*)(sm + 32768 + kt*2048 +        lane*16);
    short8 kl1 = *(const short8*)(sm + 32768 + kt*2048 + 1024 + lane*16);
    float4v a = {0.f,0.f,0.f,0.f};
    a = MFMA16(kh0, qh0, a);
    a = MFMA16(kh1, qh1, a);
    a = MFMA16(kh0, ql0, a);
    a = MFMA16(kh1, ql1, a);
    a = MFMA16(kl0, qh0, a);
    a = MFMA16(kl1, qh1, a);
    acc[kt] = a;
  }
  __syncthreads();                           // all K LDS reads complete

  // ---- stage V into the K region (latency hides under bias/topk/softmax)
  #pragma unroll
  for (int t = 0; t < 4; t++){
    int vsp = (w<<2) + t;
    int mM = vsp >> 2, ht = vsp & 3;
    gl_lds16(vt + base + mM*2048 + (ht*16 + q15)*32 + g*8, sm + vsp*1024);
  }

  // ---- scaled-domain bias: s2 = raw*scale2 + pe2 + cb2
  bool qlow = (qg < 128);
  #pragma unroll
  for (int kt = 0; kt < 16; kt++){
    float4v p4 = *(const float4v*)(pe + qg*256 + (kt<<4) + (g<<2));
    float cb = (qlow != (kt < 8)) ? pvb2 : 0.0f;
    #pragma unroll
    for (int r = 0; r < 4; r++)
      acc[kt][r] = fmaf(acc[kt][r], scale2, p4[r] + cb);
  }

  // ---- exact 128th-largest per row (MSB radix-select, sortable-uint space)
  unsigned thr = 0u; int done = 0;
  for (int bit = 31; bit >= 0; --bit){
    if (__all(done)) break;
    unsigned cand = thr | (1u << bit);
    float tf = unsort_u(cand);
    int cnt = 0;
    #pragma unroll
    for (int kt = 0; kt < 16; kt++){
      #pragma unroll
      for (int r = 0; r < 4; r++)
        cnt += (acc[kt][r] >= tf) ? 1 : 0;
    }
    cnt += __shfl_xor(cnt, 16);
    cnt += __shfl_xor(cnt, 32);
    if (!done && cnt >= 128) thr = cand;
    if (!done && cnt == 128) done = 1;
  }
  float thrf = unsort_u(thr);

  // ---- softmax over kept (scaled domain: exp2)
  float m = -1e30f;
  #pragma unroll
  for (int kt = 0; kt < 16; kt++)
    m = fmaxf(m, fmaxf(fmaxf(acc[kt][0], acc[kt][1]), fmaxf(acc[kt][2], acc[kt][3])));
  m = fmaxf(m, __shfl_xor(m, 16));
  m = fmaxf(m, __shfl_xor(m, 32));
  float sum = 0.0f;
  #pragma unroll
  for (int kt = 0; kt < 16; kt++){
    #pragma unroll
    for (int r = 0; r < 4; r++){
      float e = (acc[kt][r] >= thrf) ? exp2f(acc[kt][r] - m) : 0.0f;
      acc[kt][r] = e;
      sum += e;
    }
  }
  sum += __shfl_xor(sum, 16);
  sum += __shfl_xor(sum, 32);
  float inv = 1.0f / sum;

  __syncthreads();                           // V staged (vmcnt drained)

  // ---- PV fully in-register; V fragments from LDS
  float4v oa[4] = {};
  #pragma unroll
  for (int mM = 0; mM < 8; mM++){
    uint4 pk;
    pk.x = cvt_pk_bf16(acc[2*mM][0]*inv,   acc[2*mM][1]*inv);
    pk.y = cvt_pk_bf16(acc[2*mM][2]*inv,   acc[2*mM][3]*inv);
    pk.z = cvt_pk_bf16(acc[2*mM+1][0]*inv, acc[2*mM+1][1]*inv);
    pk.w = cvt_pk_bf16(acc[2*mM+1][2]*inv, acc[2*mM+1][3]*inv);
    short8 pf = *(short8*)&pk;
    #pragma unroll
    for (int ht = 0; ht < 4; ht++){
      short8 vf = *(const short8*)(sm + (mM*4 + ht)*1024 + lane*16);
      oa[ht] = MFMA16(pf, vf, oa[ht]);
    }
  }
  #pragma unroll
  for (int ht = 0; ht < 4; ht++){
    #pragma unroll
    for (int r = 0; r < 4; r++){
      int qo = qbase + (g<<2) + r;
      ao[((size_t)(b*256 + qo) << 9) + (h<<6) + (ht<<4) + q15] = f2bf(oa[ht][r]);
    }
  }
}

// ---------------------------------------------------------------------------
extern "C" void kernel_launch(void* const* d_in, const int* in_sizes, int n_in,
                              void* d_out, int out_size, void* d_ws, size_t ws_size,
                              hipStream_t stream)
{
  const float* x     = (const float*)d_in[0];
  const float* Wq    = (const float*)d_in[1];
  const float* bq    = (const float*)d_in[2];
  const float* Wk    = (const float*)d_in[3];
  const float* bk    = (const float*)d_in[4];
  const float* Wv    = (const float*)d_in[5];
  const float* bv    = (const float*)d_in[6];
  const float* Wo    = (const float*)d_in[7];
  const float* bo    = (const float*)d_in[8];
  const float* prior = (const float*)d_in[9];
  const float* fimp  = (const float*)d_in[10];
  const float* W1    = (const float*)d_in[11];
  const float* b1    = (const float*)d_in[12];
  const float* W2    = (const float*)d_in[13];
  const float* b2    = (const float*)d_in[14];

  char* ws = (char*)d_ws;
  ushort* xhi  = (ushort*)(ws + 0);
  ushort* xlo  = (ushort*)(ws + 16777216);
  ushort* qhi  = (ushort*)(ws + 33554432);
  ushort* qlo  = (ushort*)(ws + 50331648);
  ushort* khi  = (ushort*)(ws + 67108864);
  ushort* klo  = (ushort*)(ws + 83886080);
  ushort* vt   = (ushort*)(ws + 100663296);    // V in MFMA fragment layout
  ushort* Wthi = (ushort*)(ws + 117440512);
  ushort* Wtlo = (ushort*)(ws + 119013376);
  ushort* Wot  = (ushort*)(ws + 120061952);
  float*  fb   = (float*) (ws + 120586240);
  float*  comb = (float*) (ws + 120592384);
  float*  pvc  = (float*) (ws + 120854528);
  float*  pe   = (float*) (ws + 120854784);    // 256 KB (perm layout, *log2e)
  float*  hid  = (float*) (ws + 121116928);    // 128 KB
  ushort* ao   = xhi;   // alias: xhi dead after the projection GEMMs

  (void)hipFuncSetAttribute((const void*)attn_k,
      hipFuncAttributeMaxDynamicSharedMemorySize, 65536);

  cvt_x_k <<<4096, 256, 0, stream>>>(x, xhi, xlo);
  cvt_w_k <<<2049, 256, 0, stream>>>(Wq, Wk, Wv, Wo, bq, bk, bv, Wthi, Wtlo, Wot, fb);
  prior_k <<<256, 256, 0, stream>>>(prior, fimp, pe);
  pv_mean_k<<<64, 256, 0, stream>>>(x, comb);
  pv_hid_k <<<32, 256, 0, stream>>>(comb, W1, b1, hid);
  pv_out_k <<<64, 256, 0, stream>>>(hid, W2, b2, pvc);
  gemm_qk <<<1024, 256, 0, stream>>>(xhi, xlo, Wthi, Wtlo, fb, qhi, qlo, khi, klo);
  gemm_pl<0><<<512, 256, 0, stream>>>(xhi, Wthi + (size_t)1024*512, fb + 1024, vt);
  attn_k  <<<1024, 512, 65536, stream>>>(qhi, qlo, khi, klo, vt, pe, pvc, ao);
  gemm_pl<1><<<512, 256, 0, stream>>>(ao, Wot, bo, d_out);

  (void)in_sizes; (void)n_in; (void)out_size; (void)ws_size;
}

// Round 8
// 268.720 us; speedup vs baseline: 2.1289x; 1.0819x over previous
//
#include <hip/hip_runtime.h>

// ---------------------------------------------------------------------------
// TabularDiffFlow sparse-attention pipeline, MI355X (gfx950)
// B=64, N=256, D=512, H=8, HD=64, top-k = 128 of 256 per score row.
//
// Precision: q,k projections and QK^T in split-bf16 (hi+lo, 3 MFMAs); v/P/
// out-proj plain bf16 (absmax 3.9e-3 vs 4.65e-3 threshold, R1-R6).
//
// R7b: R7 with the d_out cast fixed. top-k via float-domain bisection on
// [rowmin,rowmax] (~12 iters vs ~26 radix; identical kept-set incl. ties),
// softmax max-pass removed (exp2-domain scores bounded). Launch fusion:
// 10 -> 5 kernels.
// ---------------------------------------------------------------------------

typedef __attribute__((ext_vector_type(8))) short short8;
typedef __attribute__((ext_vector_type(4))) float float4v;

#define MFMA16(A,B,C) __builtin_amdgcn_mfma_f32_16x16x32_bf16((A),(B),(C),0,0,0)
#define LOG2E 1.4426950408889634f

__device__ __forceinline__ ushort f2bf(float f){
  unsigned u = __float_as_uint(f);
  unsigned r = u + 0x7FFFu + ((u >> 16) & 1u);   // round-to-nearest-even
  return (ushort)(r >> 16);
}
__device__ __forceinline__ float bf2f(ushort h){
  return __uint_as_float(((unsigned)h) << 16);
}
// async global -> LDS, 16 bytes per lane; LDS dest = wave-uniform base + lane*16
__device__ __forceinline__ void gl_lds16(const void* g, void* l){
  __builtin_amdgcn_global_load_lds(
      (const __attribute__((address_space(1))) unsigned int*)g,
      (__attribute__((address_space(3))) unsigned int*)l, 16, 0, 0);
}
// pack two f32 -> one u32 of two bf16 (RNE), low16 = a, high16 = b
__device__ __forceinline__ unsigned cvt_pk_bf16(float a, float b){
  unsigned r;
  asm("v_cvt_pk_bf16_f32 %0, %1, %2" : "=v"(r) : "v"(a), "v"(b));
  return r;
}

// ---------------------------------------------------------------- prep -----
// blocks [0,4096): x -> bf16 hi/lo.  [4096,6144): weight transposes.
// [6144,6400): prior (permuted, *log2e) (+ fb fill on first block).
// [6400,6464): pv means.
__global__ __launch_bounds__(256) void prep_k(
    const float* __restrict__ x,
    const float* __restrict__ Wq, const float* __restrict__ Wk,
    const float* __restrict__ Wv, const float* __restrict__ Wo,
    const float* __restrict__ bq, const float* __restrict__ bk,
    const float* __restrict__ bv,
    const float* __restrict__ prior, const float* __restrict__ fimp,
    ushort* __restrict__ xhi, ushort* __restrict__ xlo,
    ushort* __restrict__ Wthi, ushort* __restrict__ Wtlo,
    ushort* __restrict__ Wot, float* __restrict__ fb,
    float* __restrict__ pe, float* __restrict__ comb)
{
  int bid = (int)blockIdx.x, t = threadIdx.x;
  if (bid < 4096){
    size_t i = ((size_t)bid * 256 + t) * 8;
    float4v a = *(const float4v*)(x + i);
    float4v b = *(const float4v*)(x + i + 4);
    float v0=a[0],v1=a[1],v2=a[2],v3=a[3],v4=b[0],v5=b[1],v6=b[2],v7=b[3];
    ushort h0=f2bf(v0),h1=f2bf(v1),h2=f2bf(v2),h3=f2bf(v3);
    ushort h4=f2bf(v4),h5=f2bf(v5),h6=f2bf(v6),h7=f2bf(v7);
    ushort l0=f2bf(v0-bf2f(h0)),l1=f2bf(v1-bf2f(h1)),l2=f2bf(v2-bf2f(h2)),l3=f2bf(v3-bf2f(h3));
    ushort l4=f2bf(v4-bf2f(h4)),l5=f2bf(v5-bf2f(h5)),l6=f2bf(v6-bf2f(h6)),l7=f2bf(v7-bf2f(h7));
    uint4 ph, pl;
    ph.x = h0 | ((unsigned)h1<<16); ph.y = h2 | ((unsigned)h3<<16);
    ph.z = h4 | ((unsigned)h5<<16); ph.w = h6 | ((unsigned)h7<<16);
    pl.x = l0 | ((unsigned)l1<<16); pl.y = l2 | ((unsigned)l3<<16);
    pl.z = l4 | ((unsigned)l5<<16); pl.w = l6 | ((unsigned)l7<<16);
    *(uint4*)(xhi + i) = ph;
    *(uint4*)(xlo + i) = pl;
  } else if (bid < 6144){
    int r = bid - 4096;
    if (r < 1536){
      const float* W = (r < 512) ? Wq : ((r < 1024) ? Wk : Wv);
      int o = r & 511;
      bool dolo = (r < 1024);
      for (int i = t; i < 512; i += 256){
        float f = W[(size_t)i*512 + o];
        ushort hi = f2bf(f);
        Wthi[(size_t)r*512 + i] = hi;
        if (dolo) Wtlo[(size_t)r*512 + i] = f2bf(f - bf2f(hi));
      }
    } else {
      int o = r - 1536;
      for (int i = t; i < 512; i += 256)
        Wot[(size_t)o*512 + i] = f2bf(Wo[(size_t)i*512 + o]);
    }
  } else if (bid < 6400){
    int i = bid - 6144, j = t;
    int kt = ((j >> 5) << 1) | ((j >> 2) & 1);
    int g  = (j >> 3) & 3;
    int r  = j & 3;
    int slot = (kt << 4) | (g << 2) | r;
    pe[(size_t)i*256 + slot] = prior[(size_t)i*256 + j] * fimp[i] * fimp[j] * LOG2E;
    if (bid == 6144){
      for (int q = t; q < 1536; q += 256)
        fb[q] = (q < 512) ? bq[q] : ((q < 1024) ? bk[q-512] : bv[q-1024]);
    }
  } else {
    int b = bid - 6400;
    const float* xb = x + (size_t)b * 131072;
    float p0=0.f,p1=0.f,q0=0.f,q1=0.f;
    for (int n = 0; n < 128; n++){ p0 += xb[n*512 + t]; p1 += xb[n*512 + t + 256]; }
    for (int n = 128; n < 256; n++){ q0 += xb[n*512 + t]; q1 += xb[n*512 + t + 256]; }
    const float s = 1.0f/128.0f;
    comb[(size_t)b*1024 + t]             = p0*s;
    comb[(size_t)b*1024 + t + 256]       = p1*s;
    comb[(size_t)b*1024 + 512 + t]       = q0*s;
    comb[(size_t)b*1024 + 512 + t + 256] = q1*s;
  }
}

// -------------------------------------------------------------- pv path ----
// 32 blocks; each computes silu(comb@W1+b1) for its 32-col slice and the
// partial W2-dot -> pvp[b][ct]. attn sums the 16 partials + sigmoid.
__global__ __launch_bounds__(256) void pv_hid_k(const float* __restrict__ comb,
    const float* __restrict__ W1, const float* __restrict__ b1,
    const float* __restrict__ W2, float* __restrict__ pvp){
  int ct = blockIdx.x & 15, rt = blockIdx.x >> 4;
  int t = threadIdx.x;
  int col = ct*32 + (t & 31), rs = t >> 5;
  float bb = b1[col];
  float acc[4] = {bb, bb, bb, bb};
  for (int i = 0; i < 1024; i++){
    float wv = W1[(size_t)i*512 + col];
    #pragma unroll
    for (int j = 0; j < 4; j++)
      acc[j] = fmaf(comb[(size_t)(rt*32 + rs + j*8)*1024 + i], wv, acc[j]);
  }
  float w2 = W2[col];
  #pragma unroll
  for (int j = 0; j < 4; j++){
    float a = acc[j];
    float p = (a / (1.0f + __expf(-a))) * w2;
    p += __shfl_xor(p, 16); p += __shfl_xor(p, 8);
    p += __shfl_xor(p, 4);  p += __shfl_xor(p, 2);  p += __shfl_xor(p, 1);
    if ((t & 31) == 0)
      pvp[(size_t)(rt*32 + rs + j*8)*16 + ct] = p;
  }
}

// --------------------------------------- fused projection GEMMs (qk + v) ---
// blocks [0,1024): split-bf16 qk GEMM. [1024,1536): plain v GEMM with
// fragment-layout epilogue. m97-style global_load_lds staging, linear LDS.
__global__ __launch_bounds__(256) void gemm_proj(
    const ushort* __restrict__ xhi_, const ushort* __restrict__ xlo_,
    const ushort* __restrict__ Wthi, const ushort* __restrict__ Wtlo,
    const float* __restrict__ fb,
    ushort* __restrict__ qhi, ushort* __restrict__ qlo,
    ushort* __restrict__ khi, ushort* __restrict__ klo,
    ushort* __restrict__ vt)
{
  __shared__ __align__(16) char sm[32768];
  int bid = (int)blockIdx.x;
  int tid = threadIdx.x, lane = tid & 63, w = tid >> 6, wm = w >> 1, wn = w & 1;
  int q15 = lane & 15, g = lane >> 4;
  int lrow = lane >> 2, lcol = (lane & 3) * 8;

  if (bid < 1024){
    int round = bid >> 7, rem = bid & 127;
    int sw = (round << 7) + ((rem & 7) << 4) + (rem >> 3);
    int n0 = (sw & 7) * 128, m0 = (sw >> 3) * 128;
    float4v acc[4][4] = {};
    for (int k0 = 0; k0 < 512; k0 += 32){
      #pragma unroll
      for (int t = 0; t < 8; t++){
        int id = (w << 3) + t;
        int mat = id >> 3, sp = id & 7;
        int row = ((mat < 2) ? m0 : n0) + sp*16 + lrow;
        const ushort* src;
        if      (mat == 0) src = xhi_ + (size_t)row*512 + k0 + lcol;
        else if (mat == 1) src = xlo_ + (size_t)row*512 + k0 + lcol;
        else if (mat == 2) src = Wthi + (size_t)row*512 + k0 + lcol;
        else               src = Wtlo + (size_t)row*512 + k0 + lcol;
        gl_lds16(src, sm + (id << 10));
      }
      __syncthreads();
      short8 ah[4], al[4], bh[4], bl[4];
      #pragma unroll
      for (int i = 0; i < 4; i++){
        int ra = (wm*64 + i*16 + q15)*64 + g*16;
        int rb = (wn*64 + i*16 + q15)*64 + g*16;
        ah[i] = *(const short8*)(sm +         ra);
        al[i] = *(const short8*)(sm + 8192  + ra);
        bh[i] = *(const short8*)(sm + 16384 + rb);
        bl[i] = *(const short8*)(sm + 24576 + rb);
      }
      #pragma unroll
      for (int mi = 0; mi < 4; mi++){
        #pragma unroll
        for (int ni = 0; ni < 4; ni++){
          acc[mi][ni] = MFMA16(ah[mi], bh[ni], acc[mi][ni]);
          acc[mi][ni] = MFMA16(ah[mi], bl[ni], acc[mi][ni]);
          acc[mi][ni] = MFMA16(al[mi], bh[ni], acc[mi][ni]);
        }
      }
      __syncthreads();
    }
    #pragma unroll
    for (int mi = 0; mi < 4; mi++){
      #pragma unroll
      for (int ni = 0; ni < 4; ni++){
        #pragma unroll
        for (int r = 0; r < 4; r++){
          int rg = m0 + wm*64 + mi*16 + (g<<2) + r;
          int cg = n0 + wn*64 + ni*16 + q15;
          float val = acc[mi][ni][r] + fb[cg];
          int which = cg >> 9, within = cg & 511;
          int bb = rg >> 8, seq = rg & 255, hh = within >> 6, hd = within & 63;
          size_t idx = ((size_t)((bb*8 + hh)*256 + seq))*64 + hd;
          ushort hi_ = f2bf(val);
          ushort lo_ = f2bf(val - bf2f(hi_));
          if (which == 0) { qhi[idx] = hi_; qlo[idx] = lo_; }
          else            { khi[idx] = hi_; klo[idx] = lo_; }
        }
      }
    }
  } else {
    int flat = bid - 1024;
    int round = flat >> 7, rem = flat & 127;
    int sw = (round << 7) + ((rem & 7) << 4) + (rem >> 3);
    int n0 = (sw & 3) * 128, m0 = (sw >> 2) * 128;
    const ushort* Bt = Wthi + (size_t)1024*512;
    const float* bias = fb + 1024;
    float4v acc[4][4] = {};
    for (int k0 = 0; k0 < 512; k0 += 32){
      #pragma unroll
      for (int t = 0; t < 4; t++){
        int id = (w << 2) + t;
        int mat = id >> 3, sp = id & 7;
        int row = ((mat == 0) ? m0 : n0) + sp*16 + lrow;
        const ushort* src = ((mat == 0) ? xhi_ : Bt) + (size_t)row*512 + k0 + lcol;
        gl_lds16(src, sm + (id << 10));
      }
      __syncthreads();
      short8 af[4], bg4[4];
      #pragma unroll
      for (int i = 0; i < 4; i++){
        int ra = (wm*64 + i*16 + q15)*64 + g*16;
        int rb = (wn*64 + i*16 + q15)*64 + g*16;
        af[i]  = *(const short8*)(sm +        ra);
        bg4[i] = *(const short8*)(sm + 8192 + rb);
      }
      #pragma unroll
      for (int mi = 0; mi < 4; mi++){
        #pragma unroll
        for (int ni = 0; ni < 4; ni++)
          acc[mi][ni] = MFMA16(af[mi], bg4[ni], acc[mi][ni]);
      }
      __syncthreads();
    }
    #pragma unroll
    for (int mi = 0; mi < 4; mi++){
      #pragma unroll
      for (int ni = 0; ni < 4; ni++){
        int rg0 = m0 + wm*64 + mi*16 + (g<<2);
        int cg  = n0 + wn*64 + ni*16 + q15;
        int bb = rg0 >> 8, seq0 = rg0 & 255;
        int hh = cg >> 6, hd = cg & 63;
        int kb = seq0 >> 5, wi = seq0 & 31;
        float b_ = bias[cg];
        uint2 pk;
        pk.x = (unsigned)f2bf(acc[mi][ni][0] + b_) | ((unsigned)f2bf(acc[mi][ni][1] + b_) << 16);
        pk.y = (unsigned)f2bf(acc[mi][ni][2] + b_) | ((unsigned)f2bf(acc[mi][ni][3] + b_) << 16);
        size_t off = ((size_t)(bb*8 + hh) << 14) + (size_t)(((kb<<6) + hd) << 5) + wi;
        *(uint2*)(vt + off) = pk;
      }
    }
  }
}

// -------------------------------------------------- out-projection GEMM ----
__global__ __launch_bounds__(256) void gemm_out(
    const ushort* __restrict__ A, const ushort* __restrict__ Bt,
    const float* __restrict__ bias, float* __restrict__ outp)
{
  __shared__ __align__(16) char sm[16384];
  int flat = (int)blockIdx.x;
  int round = flat >> 7, rem = flat & 127;
  int sw = (round << 7) + ((rem & 7) << 4) + (rem >> 3);
  int n0 = (sw & 3) * 128, m0 = (sw >> 2) * 128;
  int tid = threadIdx.x, lane = tid & 63, w = tid >> 6, wm = w >> 1, wn = w & 1;
  int q15 = lane & 15, g = lane >> 4;
  int lrow = lane >> 2, lcol = (lane & 3) * 8;
  float4v acc[4][4] = {};
  for (int k0 = 0; k0 < 512; k0 += 32){
    #pragma unroll
    for (int t = 0; t < 4; t++){
      int id = (w << 2) + t;
      int mat = id >> 3, sp = id & 7;
      int row = ((mat == 0) ? m0 : n0) + sp*16 + lrow;
      const ushort* src = ((mat == 0) ? A : Bt) + (size_t)row*512 + k0 + lcol;
      gl_lds16(src, sm + (id << 10));
    }
    __syncthreads();
    short8 af[4], bg4[4];
    #pragma unroll
    for (int i = 0; i < 4; i++){
      int ra = (wm*64 + i*16 + q15)*64 + g*16;
      int rb = (wn*64 + i*16 + q15)*64 + g*16;
      af[i]  = *(const short8*)(sm +        ra);
      bg4[i] = *(const short8*)(sm + 8192 + rb);
    }
    #pragma unroll
    for (int mi = 0; mi < 4; mi++){
      #pragma unroll
      for (int ni = 0; ni < 4; ni++)
        acc[mi][ni] = MFMA16(af[mi], bg4[ni], acc[mi][ni]);
    }
    __syncthreads();
  }
  #pragma unroll
  for (int mi = 0; mi < 4; mi++){
    #pragma unroll
    for (int ni = 0; ni < 4; ni++){
      int rg0 = m0 + wm*64 + mi*16 + (g<<2);
      int cg  = n0 + wn*64 + ni*16 + q15;
      float b_ = bias[cg];
      #pragma unroll
      for (int r = 0; r < 4; r++)
        outp[(size_t)(rg0 + r)*512 + cg] = acc[mi][ni][r] + b_;
    }
  }
}

// ------------------------------------------------------ fused attention ----
// 1024 blocks = (half-major, bh XCD-swizzled), 8 waves x 16 q-rows.
// LDS 64 KB = K hi/lo (rho-permuted fragment-major); V overwrites K region
// after QK^T. exp2-domain scores. Top-k = float bisection on [rowmin,rowmax]
// (exact kept-set incl. tie semantics); softmax without max-subtraction
// (bounded exponents). pvp partial logits summed + sigmoid here (uniform).
__global__ __launch_bounds__(512, 4) void attn_k(
    const ushort* __restrict__ qhi_, const ushort* __restrict__ qlo_,
    const ushort* __restrict__ khi_, const ushort* __restrict__ klo_,
    const ushort* __restrict__ vt, const float* __restrict__ pe,
    const float* __restrict__ pvp, const float* __restrict__ b2,
    ushort* __restrict__ ao)
{
  extern __shared__ char sm[];   // 64KB: Khi 0..32K | Klo 32..64K; V -> 0..32K

  int bid = (int)blockIdx.x;
  int half = bid >> 9, s = bid & 511;
  int bh = ((s & 7) << 6) + (s >> 3);        // XCD swizzle (512 = 8*64)
  int b = bh >> 3, h = bh & 7;
  int tid = threadIdx.x, lane = tid & 63, w = tid >> 6;
  int g = lane >> 4, q15 = lane & 15;
  size_t base = (size_t)bh << 14;
  int qbase = (half << 7) + (w << 4);
  int qg = qbase + q15;

  // price/vol logit: sum of 16 partials + bias, sigmoid (uniform -> s_loads)
  float pvl = b2[0];
  #pragma unroll
  for (int i = 0; i < 16; i++) pvl += pvp[b*16 + i];
  float pvb2 = (1.0f / (1.0f + __expf(-pvl))) * (0.5f * LOG2E);
  const float scale2 = 0.125f * LOG2E;

  const ushort* qp1 = qhi_ + base + (size_t)qg*64 + (g<<3);
  const ushort* qp2 = qlo_ + base + (size_t)qg*64 + (g<<3);
  short8 qh0 = *(const short8*)(qp1);
  short8 qh1 = *(const short8*)(qp1 + 32);
  short8 ql0 = *(const short8*)(qp2);
  short8 ql1 = *(const short8*)(qp2 + 32);

  // ---- stage K hi/lo: 64 spans of 1KB, 8 per wave, rho-permuted rows
  #pragma unroll
  for (int t = 0; t < 8; t++){
    int sp = (w<<3) + t;
    int mat = sp >> 5, s5 = sp & 31, kt = s5 >> 1, hf = s5 & 1;
    int R = ((kt>>1)<<5) + ((q15>>2)<<3) + ((kt&1)<<2) + (q15&3);
    const ushort* gp = (mat ? klo_ : khi_) + base + (size_t)R*64 + hf*32 + g*8;
    gl_lds16(gp, sm + sp*1024);
  }
  __syncthreads();

  // ---- QK^T (split 3-mfma x 2 halves)
  float4v acc[16];
  #pragma unroll
  for (int kt = 0; kt < 16; kt++){
    short8 kh0 = *(const short8*)(sm +         kt*2048 +        lane*16);
    short8 kh1 = *(const short8*)(sm +         kt*2048 + 1024 + lane*16);
    short8 kl0 = *(const short8*)(sm + 32768 + kt*2048 +        lane*16);
    short8 kl1 = *(const short8*)(sm + 32768 + kt*2048 + 1024 + lane*16);
    float4v a = {0.f,0.f,0.f,0.f};
    a = MFMA16(kh0, qh0, a);
    a = MFMA16(kh1, qh1, a);
    a = MFMA16(kh0, ql0, a);
    a = MFMA16(kh1, ql1, a);
    a = MFMA16(kl0, qh0, a);
    a = MFMA16(kl1, qh1, a);
    acc[kt] = a;
  }
  __syncthreads();                           // all K LDS reads complete

  // ---- stage V into the K region (latency hides under topk VALU phase)
  #pragma unroll
  for (int t = 0; t < 4; t++){
    int vsp = (w<<2) + t;
    int mM = vsp >> 2, ht = vsp & 3;
    gl_lds16(vt + base + mM*2048 + (ht*16 + q15)*32 + g*8, sm + vsp*1024);
  }

  // ---- scaled-domain bias: s2 = raw*scale2 + pe2 + cb2
  bool qlow = (qg < 128);
  #pragma unroll
  for (int kt = 0; kt < 16; kt++){
    float4v p4 = *(const float4v*)(pe + qg*256 + (kt<<4) + (g<<2));
    float cb = (qlow != (kt < 8)) ? pvb2 : 0.0f;
    #pragma unroll
    for (int r = 0; r < 4; r++)
      acc[kt][r] = fmaf(acc[kt][r], scale2, p4[r] + cb);
  }

  // ---- row min/max across the 4-lane group
  float rmin = acc[0][0], rmax = acc[0][0];
  #pragma unroll
  for (int kt = 0; kt < 16; kt++){
    #pragma unroll
    for (int r = 0; r < 4; r++){
      rmin = fminf(rmin, acc[kt][r]);
      rmax = fmaxf(rmax, acc[kt][r]);
    }
  }
  rmin = fminf(rmin, __shfl_xor(rmin, 16));
  rmin = fminf(rmin, __shfl_xor(rmin, 32));
  rmax = fmaxf(rmax, __shfl_xor(rmax, 16));
  rmax = fmaxf(rmax, __shfl_xor(rmax, 32));

  // ---- exact 128th-largest: bisection on value space.
  // Invariant: cnt(>=lo) >= 128 > cnt(>=hi). Terminates on cnt==128 (lo=mid
  // works) or when no representable mid remains (tie at boundary: lo = s128,
  // kept set includes ties -- matches the reference's `>= kth` rule).
  float lo = rmin, hi = rmax;
  #pragma unroll 1
  for (int it = 0; it < 40; ++it){
    float mid = 0.5f*(lo + hi);
    if (!(mid > lo && mid < hi)) break;
    int cnt = 0;
    #pragma unroll
    for (int kt = 0; kt < 16; kt++){
      #pragma unroll
      for (int r = 0; r < 4; r++)
        cnt += (acc[kt][r] >= mid) ? 1 : 0;
    }
    cnt += __shfl_xor(cnt, 16);
    cnt += __shfl_xor(cnt, 32);
    if (cnt >= 128){
      lo = mid;
      if (cnt == 128) break;
    } else hi = mid;
  }
  float thrf = lo;

  // ---- softmax over kept (exp2 domain, no max subtraction: |s2| bounded)
  float sum = 0.0f;
  #pragma unroll
  for (int kt = 0; kt < 16; kt++){
    #pragma unroll
    for (int r = 0; r < 4; r++){
      float e = (acc[kt][r] >= thrf) ? exp2f(acc[kt][r]) : 0.0f;
      acc[kt][r] = e;
      sum += e;
    }
  }
  sum += __shfl_xor(sum, 16);
  sum += __shfl_xor(sum, 32);
  float inv = 1.0f / sum;

  __syncthreads();                           // V staged (vmcnt drained)

  // ---- PV fully in-register; V fragments from LDS
  float4v oa[4] = {};
  #pragma unroll
  for (int mM = 0; mM < 8; mM++){
    uint4 pk;
    pk.x = cvt_pk_bf16(acc[2*mM][0]*inv,   acc[2*mM][1]*inv);
    pk.y = cvt_pk_bf16(acc[2*mM][2]*inv,   acc[2*mM][3]*inv);
    pk.z = cvt_pk_bf16(acc[2*mM+1][0]*inv, acc[2*mM+1][1]*inv);
    pk.w = cvt_pk_bf16(acc[2*mM+1][2]*inv, acc[2*mM+1][3]*inv);
    short8 pf = *(short8*)&pk;
    #pragma unroll
    for (int ht = 0; ht < 4; ht++){
      short8 vf = *(const short8*)(sm + (mM*4 + ht)*1024 + lane*16);
      oa[ht] = MFMA16(pf, vf, oa[ht]);
    }
  }
  #pragma unroll
  for (int ht = 0; ht < 4; ht++){
    #pragma unroll
    for (int r = 0; r < 4; r++){
      int qo = qbase + (g<<2) + r;
      ao[((size_t)(b*256 + qo) << 9) + (h<<6) + (ht<<4) + q15] = f2bf(oa[ht][r]);
    }
  }
}

// ---------------------------------------------------------------------------
extern "C" void kernel_launch(void* const* d_in, const int* in_sizes, int n_in,
                              void* d_out, int out_size, void* d_ws, size_t ws_size,
                              hipStream_t stream)
{
  const float* x     = (const float*)d_in[0];
  const float* Wq    = (const float*)d_in[1];
  const float* bq    = (const float*)d_in[2];
  const float* Wk    = (const float*)d_in[3];
  const float* bk    = (const float*)d_in[4];
  const float* Wv    = (const float*)d_in[5];
  const float* bv    = (const float*)d_in[6];
  const float* Wo    = (const float*)d_in[7];
  const float* bo    = (const float*)d_in[8];
  const float* prior = (const float*)d_in[9];
  const float* fimp  = (const float*)d_in[10];
  const float* W1    = (const float*)d_in[11];
  const float* b1    = (const float*)d_in[12];
  const float* W2    = (const float*)d_in[13];
  const float* b2    = (const float*)d_in[14];

  char* ws = (char*)d_ws;
  ushort* xhi  = (ushort*)(ws + 0);
  ushort* xlo  = (ushort*)(ws + 16777216);
  ushort* qhi  = (ushort*)(ws + 33554432);
  ushort* qlo  = (ushort*)(ws + 50331648);
  ushort* khi  = (ushort*)(ws + 67108864);
  ushort* klo  = (ushort*)(ws + 83886080);
  ushort* vt   = (ushort*)(ws + 100663296);    // V in MFMA fragment layout
  ushort* Wthi = (ushort*)(ws + 117440512);
  ushort* Wtlo = (ushort*)(ws + 119013376);
  ushort* Wot  = (ushort*)(ws + 120061952);
  float*  fb   = (float*) (ws + 120586240);
  float*  comb = (float*) (ws + 120592384);
  float*  pvp  = (float*) (ws + 120854528);    // [64][16] partial logits
  float*  pe   = (float*) (ws + 120858624);    // 256 KB (perm layout, *log2e)
  ushort* ao   = xhi;   // alias: xhi dead after the projection GEMMs

  (void)hipFuncSetAttribute((const void*)attn_k,
      hipFuncAttributeMaxDynamicSharedMemorySize, 65536);

  prep_k   <<<6464, 256, 0, stream>>>(x, Wq, Wk, Wv, Wo, bq, bk, bv, prior, fimp,
                                      xhi, xlo, Wthi, Wtlo, Wot, fb, pe, comb);
  pv_hid_k <<<32, 256, 0, stream>>>(comb, W1, b1, W2, pvp);
  gemm_proj<<<1536, 256, 0, stream>>>(xhi, xlo, Wthi, Wtlo, fb,
                                      qhi, qlo, khi, klo, vt);
  attn_k   <<<1024, 512, 65536, stream>>>(qhi, qlo, khi, klo, vt, pe, pvp, b2, ao);
  gemm_out <<<512, 256, 0, stream>>>(ao, Wot, bo, (float*)d_out);

  (void)in_sizes; (void)n_in; (void)out_size; (void)ws_size;
}

// Round 9
// 251.499 us; speedup vs baseline: 2.2746x; 1.0685x over previous
//
#include <hip/hip_runtime.h>

// ---------------------------------------------------------------------------
// TabularDiffFlow sparse-attention pipeline, MI355X (gfx950)
// B=64, N=256, D=512, H=8, HD=64, top-k = 128 of 256 per score row.
//
// Precision: q,k projections and QK^T in split-bf16 (hi+lo, 3 MFMAs); v/P/
// out-proj plain bf16 (absmax 3.9e-3 vs 4.65e-3 threshold, R1-R8).
//
// R9: GEMMs get T3-minimum 2-phase double-buffered staging — issue
// global_load_lds for K-tile t+1 BEFORE computing tile t, ONE barrier per
// K-step (its vmcnt(0) drain covers the prefetch, whose latency hides under
// the current tile's MFMAs). attn/prep/pv unchanged from R8.
// ---------------------------------------------------------------------------

typedef __attribute__((ext_vector_type(8))) short short8;
typedef __attribute__((ext_vector_type(4))) float float4v;

#define MFMA16(A,B,C) __builtin_amdgcn_mfma_f32_16x16x32_bf16((A),(B),(C),0,0,0)
#define LOG2E 1.4426950408889634f

__device__ __forceinline__ ushort f2bf(float f){
  unsigned u = __float_as_uint(f);
  unsigned r = u + 0x7FFFu + ((u >> 16) & 1u);   // round-to-nearest-even
  return (ushort)(r >> 16);
}
__device__ __forceinline__ float bf2f(ushort h){
  return __uint_as_float(((unsigned)h) << 16);
}
// async global -> LDS, 16 bytes per lane; LDS dest = wave-uniform base + lane*16
__device__ __forceinline__ void gl_lds16(const void* g, void* l){
  __builtin_amdgcn_global_load_lds(
      (const __attribute__((address_space(1))) unsigned int*)g,
      (__attribute__((address_space(3))) unsigned int*)l, 16, 0, 0);
}
// pack two f32 -> one u32 of two bf16 (RNE), low16 = a, high16 = b
__device__ __forceinline__ unsigned cvt_pk_bf16(float a, float b){
  unsigned r;
  asm("v_cvt_pk_bf16_f32 %0, %1, %2" : "=v"(r) : "v"(a), "v"(b));
  return r;
}

// ---------------------------------------------------------------- prep -----
// blocks [0,4096): x -> bf16 hi/lo.  [4096,6144): weight transposes.
// [6144,6400): prior (permuted, *log2e) (+ fb fill on first block).
// [6400,6464): pv means.
__global__ __launch_bounds__(256) void prep_k(
    const float* __restrict__ x,
    const float* __restrict__ Wq, const float* __restrict__ Wk,
    const float* __restrict__ Wv, const float* __restrict__ Wo,
    const float* __restrict__ bq, const float* __restrict__ bk,
    const float* __restrict__ bv,
    const float* __restrict__ prior, const float* __restrict__ fimp,
    ushort* __restrict__ xhi, ushort* __restrict__ xlo,
    ushort* __restrict__ Wthi, ushort* __restrict__ Wtlo,
    ushort* __restrict__ Wot, float* __restrict__ fb,
    float* __restrict__ pe, float* __restrict__ comb)
{
  int bid = (int)blockIdx.x, t = threadIdx.x;
  if (bid < 4096){
    size_t i = ((size_t)bid * 256 + t) * 8;
    float4v a = *(const float4v*)(x + i);
    float4v b = *(const float4v*)(x + i + 4);
    float v0=a[0],v1=a[1],v2=a[2],v3=a[3],v4=b[0],v5=b[1],v6=b[2],v7=b[3];
    ushort h0=f2bf(v0),h1=f2bf(v1),h2=f2bf(v2),h3=f2bf(v3);
    ushort h4=f2bf(v4),h5=f2bf(v5),h6=f2bf(v6),h7=f2bf(v7);
    ushort l0=f2bf(v0-bf2f(h0)),l1=f2bf(v1-bf2f(h1)),l2=f2bf(v2-bf2f(h2)),l3=f2bf(v3-bf2f(h3));
    ushort l4=f2bf(v4-bf2f(h4)),l5=f2bf(v5-bf2f(h5)),l6=f2bf(v6-bf2f(h6)),l7=f2bf(v7-bf2f(h7));
    uint4 ph, pl;
    ph.x = h0 | ((unsigned)h1<<16); ph.y = h2 | ((unsigned)h3<<16);
    ph.z = h4 | ((unsigned)h5<<16); ph.w = h6 | ((unsigned)h7<<16);
    pl.x = l0 | ((unsigned)l1<<16); pl.y = l2 | ((unsigned)l3<<16);
    pl.z = l4 | ((unsigned)l5<<16); pl.w = l6 | ((unsigned)l7<<16);
    *(uint4*)(xhi + i) = ph;
    *(uint4*)(xlo + i) = pl;
  } else if (bid < 6144){
    int r = bid - 4096;
    if (r < 1536){
      const float* W = (r < 512) ? Wq : ((r < 1024) ? Wk : Wv);
      int o = r & 511;
      bool dolo = (r < 1024);
      for (int i = t; i < 512; i += 256){
        float f = W[(size_t)i*512 + o];
        ushort hi = f2bf(f);
        Wthi[(size_t)r*512 + i] = hi;
        if (dolo) Wtlo[(size_t)r*512 + i] = f2bf(f - bf2f(hi));
      }
    } else {
      int o = r - 1536;
      for (int i = t; i < 512; i += 256)
        Wot[(size_t)o*512 + i] = f2bf(Wo[(size_t)i*512 + o]);
    }
  } else if (bid < 6400){
    int i = bid - 6144, j = t;
    int kt = ((j >> 5) << 1) | ((j >> 2) & 1);
    int g  = (j >> 3) & 3;
    int r  = j & 3;
    int slot = (kt << 4) | (g << 2) | r;
    pe[(size_t)i*256 + slot] = prior[(size_t)i*256 + j] * fimp[i] * fimp[j] * LOG2E;
    if (bid == 6144){
      for (int q = t; q < 1536; q += 256)
        fb[q] = (q < 512) ? bq[q] : ((q < 1024) ? bk[q-512] : bv[q-1024]);
    }
  } else {
    int b = bid - 6400;
    const float* xb = x + (size_t)b * 131072;
    float p0=0.f,p1=0.f,q0=0.f,q1=0.f;
    for (int n = 0; n < 128; n++){ p0 += xb[n*512 + t]; p1 += xb[n*512 + t + 256]; }
    for (int n = 128; n < 256; n++){ q0 += xb[n*512 + t]; q1 += xb[n*512 + t + 256]; }
    const float s = 1.0f/128.0f;
    comb[(size_t)b*1024 + t]             = p0*s;
    comb[(size_t)b*1024 + t + 256]       = p1*s;
    comb[(size_t)b*1024 + 512 + t]       = q0*s;
    comb[(size_t)b*1024 + 512 + t + 256] = q1*s;
  }
}

// -------------------------------------------------------------- pv path ----
// 32 blocks; each computes silu(comb@W1+b1) for its 32-col slice and the
// partial W2-dot -> pvp[b][ct]. attn sums the 16 partials + sigmoid.
__global__ __launch_bounds__(256) void pv_hid_k(const float* __restrict__ comb,
    const float* __restrict__ W1, const float* __restrict__ b1,
    const float* __restrict__ W2, float* __restrict__ pvp){
  int ct = blockIdx.x & 15, rt = blockIdx.x >> 4;
  int t = threadIdx.x;
  int col = ct*32 + (t & 31), rs = t >> 5;
  float bb = b1[col];
  float acc[4] = {bb, bb, bb, bb};
  for (int i = 0; i < 1024; i++){
    float wv = W1[(size_t)i*512 + col];
    #pragma unroll
    for (int j = 0; j < 4; j++)
      acc[j] = fmaf(comb[(size_t)(rt*32 + rs + j*8)*1024 + i], wv, acc[j]);
  }
  float w2 = W2[col];
  #pragma unroll
  for (int j = 0; j < 4; j++){
    float a = acc[j];
    float p = (a / (1.0f + __expf(-a))) * w2;
    p += __shfl_xor(p, 16); p += __shfl_xor(p, 8);
    p += __shfl_xor(p, 4);  p += __shfl_xor(p, 2);  p += __shfl_xor(p, 1);
    if ((t & 31) == 0)
      pvp[(size_t)(rt*32 + rs + j*8)*16 + ct] = p;
  }
}

// --------------------------------------- fused projection GEMMs (qk + v) ---
// blocks [0,1024): split-bf16 qk GEMM (dbuf 2x32KB). [1024,1536): plain v
// GEMM, frag-layout epilogue (dbuf 2x16KB). 2-phase prefetched staging.
__global__ __launch_bounds__(256) void gemm_proj(
    const ushort* __restrict__ xhi_, const ushort* __restrict__ xlo_,
    const ushort* __restrict__ Wthi, const ushort* __restrict__ Wtlo,
    const float* __restrict__ fb,
    ushort* __restrict__ qhi, ushort* __restrict__ qlo,
    ushort* __restrict__ khi, ushort* __restrict__ klo,
    ushort* __restrict__ vt)
{
  extern __shared__ __align__(16) char smx[];   // 64KB (qk) / 32KB used (v)
  int bid = (int)blockIdx.x;
  int tid = threadIdx.x, lane = tid & 63, w = tid >> 6, wm = w >> 1, wn = w & 1;
  int q15 = lane & 15, g = lane >> 4;
  int lrow = lane >> 2, lcol = (lane & 3) * 8;

  if (bid < 1024){
    int round = bid >> 7, rem = bid & 127;
    int sw = (round << 7) + ((rem & 7) << 4) + (rem >> 3);
    int n0 = (sw & 7) * 128, m0 = (sw >> 3) * 128;
    float4v acc[4][4] = {};

    auto STAGE = [&](int buf, int k0){
      #pragma unroll
      for (int t = 0; t < 8; t++){
        int id = (w << 3) + t;
        int mat = id >> 3, sp = id & 7;
        int row = ((mat < 2) ? m0 : n0) + sp*16 + lrow;
        const ushort* src;
        if      (mat == 0) src = xhi_ + (size_t)row*512 + k0 + lcol;
        else if (mat == 1) src = xlo_ + (size_t)row*512 + k0 + lcol;
        else if (mat == 2) src = Wthi + (size_t)row*512 + k0 + lcol;
        else               src = Wtlo + (size_t)row*512 + k0 + lcol;
        gl_lds16(src, smx + buf*32768 + (id << 10));
      }
    };

    STAGE(0, 0);
    __syncthreads();
    int buf = 0;
    for (int k0 = 0; k0 < 512; k0 += 32){
      if (k0 + 32 < 512) STAGE(buf ^ 1, k0 + 32);
      const char* sb = smx + buf*32768;
      short8 ah[4], al[4], bh[4], bl[4];
      #pragma unroll
      for (int i = 0; i < 4; i++){
        int ra = (wm*64 + i*16 + q15)*64 + g*16;
        int rb = (wn*64 + i*16 + q15)*64 + g*16;
        ah[i] = *(const short8*)(sb +         ra);
        al[i] = *(const short8*)(sb + 8192  + ra);
        bh[i] = *(const short8*)(sb + 16384 + rb);
        bl[i] = *(const short8*)(sb + 24576 + rb);
      }
      #pragma unroll
      for (int mi = 0; mi < 4; mi++){
        #pragma unroll
        for (int ni = 0; ni < 4; ni++){
          acc[mi][ni] = MFMA16(ah[mi], bh[ni], acc[mi][ni]);
          acc[mi][ni] = MFMA16(ah[mi], bl[ni], acc[mi][ni]);
          acc[mi][ni] = MFMA16(al[mi], bh[ni], acc[mi][ni]);
        }
      }
      __syncthreads();           // drains prefetch (vmcnt0) + frees buf
      buf ^= 1;
    }
    #pragma unroll
    for (int mi = 0; mi < 4; mi++){
      #pragma unroll
      for (int ni = 0; ni < 4; ni++){
        #pragma unroll
        for (int r = 0; r < 4; r++){
          int rg = m0 + wm*64 + mi*16 + (g<<2) + r;
          int cg = n0 + wn*64 + ni*16 + q15;
          float val = acc[mi][ni][r] + fb[cg];
          int which = cg >> 9, within = cg & 511;
          int bb = rg >> 8, seq = rg & 255, hh = within >> 6, hd = within & 63;
          size_t idx = ((size_t)((bb*8 + hh)*256 + seq))*64 + hd;
          ushort hi_ = f2bf(val);
          ushort lo_ = f2bf(val - bf2f(hi_));
          if (which == 0) { qhi[idx] = hi_; qlo[idx] = lo_; }
          else            { khi[idx] = hi_; klo[idx] = lo_; }
        }
      }
    }
  } else {
    int flat = bid - 1024;
    int round = flat >> 7, rem = flat & 127;
    int sw = (round << 7) + ((rem & 7) << 4) + (rem >> 3);
    int n0 = (sw & 3) * 128, m0 = (sw >> 2) * 128;
    const ushort* Bt = Wthi + (size_t)1024*512;
    const float* bias = fb + 1024;
    float4v acc[4][4] = {};

    auto STAGE = [&](int buf, int k0){
      #pragma unroll
      for (int t = 0; t < 4; t++){
        int id = (w << 2) + t;
        int mat = id >> 3, sp = id & 7;
        int row = ((mat == 0) ? m0 : n0) + sp*16 + lrow;
        const ushort* src = ((mat == 0) ? xhi_ : Bt) + (size_t)row*512 + k0 + lcol;
        gl_lds16(src, smx + buf*16384 + (id << 10));
      }
    };

    STAGE(0, 0);
    __syncthreads();
    int buf = 0;
    for (int k0 = 0; k0 < 512; k0 += 32){
      if (k0 + 32 < 512) STAGE(buf ^ 1, k0 + 32);
      const char* sb = smx + buf*16384;
      short8 af[4], bg4[4];
      #pragma unroll
      for (int i = 0; i < 4; i++){
        int ra = (wm*64 + i*16 + q15)*64 + g*16;
        int rb = (wn*64 + i*16 + q15)*64 + g*16;
        af[i]  = *(const short8*)(sb +        ra);
        bg4[i] = *(const short8*)(sb + 8192 + rb);
      }
      #pragma unroll
      for (int mi = 0; mi < 4; mi++){
        #pragma unroll
        for (int ni = 0; ni < 4; ni++)
          acc[mi][ni] = MFMA16(af[mi], bg4[ni], acc[mi][ni]);
      }
      __syncthreads();
      buf ^= 1;
    }
    #pragma unroll
    for (int mi = 0; mi < 4; mi++){
      #pragma unroll
      for (int ni = 0; ni < 4; ni++){
        int rg0 = m0 + wm*64 + mi*16 + (g<<2);
        int cg  = n0 + wn*64 + ni*16 + q15;
        int bb = rg0 >> 8, seq0 = rg0 & 255;
        int hh = cg >> 6, hd = cg & 63;
        int kb = seq0 >> 5, wi = seq0 & 31;
        float b_ = bias[cg];
        uint2 pk;
        pk.x = (unsigned)f2bf(acc[mi][ni][0] + b_) | ((unsigned)f2bf(acc[mi][ni][1] + b_) << 16);
        pk.y = (unsigned)f2bf(acc[mi][ni][2] + b_) | ((unsigned)f2bf(acc[mi][ni][3] + b_) << 16);
        size_t off = ((size_t)(bb*8 + hh) << 14) + (size_t)(((kb<<6) + hd) << 5) + wi;
        *(uint2*)(vt + off) = pk;
      }
    }
  }
}

// -------------------------------------------------- out-projection GEMM ----
__global__ __launch_bounds__(256) void gemm_out(
    const ushort* __restrict__ A, const ushort* __restrict__ Bt,
    const float* __restrict__ bias, float* __restrict__ outp)
{
  __shared__ __align__(16) char sm[32768];   // 2 x 16KB double buffer
  int flat = (int)blockIdx.x;
  int round = flat >> 7, rem = flat & 127;
  int sw = (round << 7) + ((rem & 7) << 4) + (rem >> 3);
  int n0 = (sw & 3) * 128, m0 = (sw >> 2) * 128;
  int tid = threadIdx.x, lane = tid & 63, w = tid >> 6, wm = w >> 1, wn = w & 1;
  int q15 = lane & 15, g = lane >> 4;
  int lrow = lane >> 2, lcol = (lane & 3) * 8;
  float4v acc[4][4] = {};

  auto STAGE = [&](int buf, int k0){
    #pragma unroll
    for (int t = 0; t < 4; t++){
      int id = (w << 2) + t;
      int mat = id >> 3, sp = id & 7;
      int row = ((mat == 0) ? m0 : n0) + sp*16 + lrow;
      const ushort* src = ((mat == 0) ? A : Bt) + (size_t)row*512 + k0 + lcol;
      gl_lds16(src, sm + buf*16384 + (id << 10));
    }
  };

  STAGE(0, 0);
  __syncthreads();
  int buf = 0;
  for (int k0 = 0; k0 < 512; k0 += 32){
    if (k0 + 32 < 512) STAGE(buf ^ 1, k0 + 32);
    const char* sb = sm + buf*16384;
    short8 af[4], bg4[4];
    #pragma unroll
    for (int i = 0; i < 4; i++){
      int ra = (wm*64 + i*16 + q15)*64 + g*16;
      int rb = (wn*64 + i*16 + q15)*64 + g*16;
      af[i]  = *(const short8*)(sb +        ra);
      bg4[i] = *(const short8*)(sb + 8192 + rb);
    }
    #pragma unroll
    for (int mi = 0; mi < 4; mi++){
      #pragma unroll
      for (int ni = 0; ni < 4; ni++)
        acc[mi][ni] = MFMA16(af[mi], bg4[ni], acc[mi][ni]);
    }
    __syncthreads();
    buf ^= 1;
  }
  #pragma unroll
  for (int mi = 0; mi < 4; mi++){
    #pragma unroll
    for (int ni = 0; ni < 4; ni++){
      int rg0 = m0 + wm*64 + mi*16 + (g<<2);
      int cg  = n0 + wn*64 + ni*16 + q15;
      float b_ = bias[cg];
      #pragma unroll
      for (int r = 0; r < 4; r++)
        outp[(size_t)(rg0 + r)*512 + cg] = acc[mi][ni][r] + b_;
    }
  }
}

// ------------------------------------------------------ fused attention ----
// 1024 blocks = (half-major, bh XCD-swizzled), 8 waves x 16 q-rows.
// LDS 64 KB = K hi/lo (rho-permuted fragment-major); V overwrites K region
// after QK^T. exp2-domain scores. Top-k = float bisection on [rowmin,rowmax]
// (exact kept-set incl. tie semantics); softmax without max-subtraction
// (bounded exponents). pvp partial logits summed + sigmoid here (uniform).
__global__ __launch_bounds__(512, 4) void attn_k(
    const ushort* __restrict__ qhi_, const ushort* __restrict__ qlo_,
    const ushort* __restrict__ khi_, const ushort* __restrict__ klo_,
    const ushort* __restrict__ vt, const float* __restrict__ pe,
    const float* __restrict__ pvp, const float* __restrict__ b2,
    ushort* __restrict__ ao)
{
  extern __shared__ char sm[];   // 64KB: Khi 0..32K | Klo 32..64K; V -> 0..32K

  int bid = (int)blockIdx.x;
  int half = bid >> 9, s = bid & 511;
  int bh = ((s & 7) << 6) + (s >> 3);        // XCD swizzle (512 = 8*64)
  int b = bh >> 3, h = bh & 7;
  int tid = threadIdx.x, lane = tid & 63, w = tid >> 6;
  int g = lane >> 4, q15 = lane & 15;
  size_t base = (size_t)bh << 14;
  int qbase = (half << 7) + (w << 4);
  int qg = qbase + q15;

  // price/vol logit: sum of 16 partials + bias, sigmoid (uniform -> s_loads)
  float pvl = b2[0];
  #pragma unroll
  for (int i = 0; i < 16; i++) pvl += pvp[b*16 + i];
  float pvb2 = (1.0f / (1.0f + __expf(-pvl))) * (0.5f * LOG2E);
  const float scale2 = 0.125f * LOG2E;

  const ushort* qp1 = qhi_ + base + (size_t)qg*64 + (g<<3);
  const ushort* qp2 = qlo_ + base + (size_t)qg*64 + (g<<3);
  short8 qh0 = *(const short8*)(qp1);
  short8 qh1 = *(const short8*)(qp1 + 32);
  short8 ql0 = *(const short8*)(qp2);
  short8 ql1 = *(const short8*)(qp2 + 32);

  // ---- stage K hi/lo: 64 spans of 1KB, 8 per wave, rho-permuted rows
  #pragma unroll
  for (int t = 0; t < 8; t++){
    int sp = (w<<3) + t;
    int mat = sp >> 5, s5 = sp & 31, kt = s5 >> 1, hf = s5 & 1;
    int R = ((kt>>1)<<5) + ((q15>>2)<<3) + ((kt&1)<<2) + (q15&3);
    const ushort* gp = (mat ? klo_ : khi_) + base + (size_t)R*64 + hf*32 + g*8;
    gl_lds16(gp, sm + sp*1024);
  }
  __syncthreads();

  // ---- QK^T (split 3-mfma x 2 halves)
  float4v acc[16];
  #pragma unroll
  for (int kt = 0; kt < 16; kt++){
    short8 kh0 = *(const short8*)(sm +         kt*2048 +        lane*16);
    short8 kh1 = *(const short8*)(sm +         kt*2048 + 1024 + lane*16);
    short8 kl0 = *(const short8*)(sm + 32768 + kt*2048 +        lane*16);
    short8 kl1 = *(const short8*)(sm + 32768 + kt*2048 + 1024 + lane*16);
    float4v a = {0.f,0.f,0.f,0.f};
    a = MFMA16(kh0, qh0, a);
    a = MFMA16(kh1, qh1, a);
    a = MFMA16(kh0, ql0, a);
    a = MFMA16(kh1, ql1, a);
    a = MFMA16(kl0, qh0, a);
    a = MFMA16(kl1, qh1, a);
    acc[kt] = a;
  }
  __syncthreads();                           // all K LDS reads complete

  // ---- stage V into the K region (latency hides under topk VALU phase)
  #pragma unroll
  for (int t = 0; t < 4; t++){
    int vsp = (w<<2) + t;
    int mM = vsp >> 2, ht = vsp & 3;
    gl_lds16(vt + base + mM*2048 + (ht*16 + q15)*32 + g*8, sm + vsp*1024);
  }

  // ---- scaled-domain bias: s2 = raw*scale2 + pe2 + cb2
  bool qlow = (qg < 128);
  #pragma unroll
  for (int kt = 0; kt < 16; kt++){
    float4v p4 = *(const float4v*)(pe + qg*256 + (kt<<4) + (g<<2));
    float cb = (qlow != (kt < 8)) ? pvb2 : 0.0f;
    #pragma unroll
    for (int r = 0; r < 4; r++)
      acc[kt][r] = fmaf(acc[kt][r], scale2, p4[r] + cb);
  }

  // ---- row min/max across the 4-lane group
  float rmin = acc[0][0], rmax = acc[0][0];
  #pragma unroll
  for (int kt = 0; kt < 16; kt++){
    #pragma unroll
    for (int r = 0; r < 4; r++){
      rmin = fminf(rmin, acc[kt][r]);
      rmax = fmaxf(rmax, acc[kt][r]);
    }
  }
  rmin = fminf(rmin, __shfl_xor(rmin, 16));
  rmin = fminf(rmin, __shfl_xor(rmin, 32));
  rmax = fmaxf(rmax, __shfl_xor(rmax, 16));
  rmax = fmaxf(rmax, __shfl_xor(rmax, 32));

  // ---- exact 128th-largest: bisection on value space.
  // Invariant: cnt(>=lo) >= 128 > cnt(>=hi). Terminates on cnt==128 (lo=mid
  // works) or when no representable mid remains (tie at boundary: lo = s128,
  // kept set includes ties -- matches the reference's `>= kth` rule).
  float lo = rmin, hi = rmax;
  #pragma unroll 1
  for (int it = 0; it < 40; ++it){
    float mid = 0.5f*(lo + hi);
    if (!(mid > lo && mid < hi)) break;
    int cnt = 0;
    #pragma unroll
    for (int kt = 0; kt < 16; kt++){
      #pragma unroll
      for (int r = 0; r < 4; r++)
        cnt += (acc[kt][r] >= mid) ? 1 : 0;
    }
    cnt += __shfl_xor(cnt, 16);
    cnt += __shfl_xor(cnt, 32);
    if (cnt >= 128){
      lo = mid;
      if (cnt == 128) break;
    } else hi = mid;
  }
  float thrf = lo;

  // ---- softmax over kept (exp2 domain, no max subtraction: |s2| bounded)
  float sum = 0.0f;
  #pragma unroll
  for (int kt = 0; kt < 16; kt++){
    #pragma unroll
    for (int r = 0; r < 4; r++){
      float e = (acc[kt][r] >= thrf) ? exp2f(acc[kt][r]) : 0.0f;
      acc[kt][r] = e;
      sum += e;
    }
  }
  sum += __shfl_xor(sum, 16);
  sum += __shfl_xor(sum, 32);
  float inv = 1.0f / sum;

  __syncthreads();                           // V staged (vmcnt drained)

  // ---- PV fully in-register; V fragments from LDS
  float4v oa[4] = {};
  #pragma unroll
  for (int mM = 0; mM < 8; mM++){
    uint4 pk;
    pk.x = cvt_pk_bf16(acc[2*mM][0]*inv,   acc[2*mM][1]*inv);
    pk.y = cvt_pk_bf16(acc[2*mM][2]*inv,   acc[2*mM][3]*inv);
    pk.z = cvt_pk_bf16(acc[2*mM+1][0]*inv, acc[2*mM+1][1]*inv);
    pk.w = cvt_pk_bf16(acc[2*mM+1][2]*inv, acc[2*mM+1][3]*inv);
    short8 pf = *(short8*)&pk;
    #pragma unroll
    for (int ht = 0; ht < 4; ht++){
      short8 vf = *(const short8*)(sm + (mM*4 + ht)*1024 + lane*16);
      oa[ht] = MFMA16(pf, vf, oa[ht]);
    }
  }
  #pragma unroll
  for (int ht = 0; ht < 4; ht++){
    #pragma unroll
    for (int r = 0; r < 4; r++){
      int qo = qbase + (g<<2) + r;
      ao[((size_t)(b*256 + qo) << 9) + (h<<6) + (ht<<4) + q15] = f2bf(oa[ht][r]);
    }
  }
}

// ---------------------------------------------------------------------------
extern "C" void kernel_launch(void* const* d_in, const int* in_sizes, int n_in,
                              void* d_out, int out_size, void* d_ws, size_t ws_size,
                              hipStream_t stream)
{
  const float* x     = (const float*)d_in[0];
  const float* Wq    = (const float*)d_in[1];
  const float* bq    = (const float*)d_in[2];
  const float* Wk    = (const float*)d_in[3];
  const float* bk    = (const float*)d_in[4];
  const float* Wv    = (const float*)d_in[5];
  const float* bv    = (const float*)d_in[6];
  const float* Wo    = (const float*)d_in[7];
  const float* bo    = (const float*)d_in[8];
  const float* prior = (const float*)d_in[9];
  const float* fimp  = (const float*)d_in[10];
  const float* W1    = (const float*)d_in[11];
  const float* b1    = (const float*)d_in[12];
  const float* W2    = (const float*)d_in[13];
  const float* b2    = (const float*)d_in[14];

  char* ws = (char*)d_ws;
  ushort* xhi  = (ushort*)(ws + 0);
  ushort* xlo  = (ushort*)(ws + 16777216);
  ushort* qhi  = (ushort*)(ws + 33554432);
  ushort* qlo  = (ushort*)(ws + 50331648);
  ushort* khi  = (ushort*)(ws + 67108864);
  ushort* klo  = (ushort*)(ws + 83886080);
  ushort* vt   = (ushort*)(ws + 100663296);    // V in MFMA fragment layout
  ushort* Wthi = (ushort*)(ws + 117440512);
  ushort* Wtlo = (ushort*)(ws + 119013376);
  ushort* Wot  = (ushort*)(ws + 120061952);
  float*  fb   = (float*) (ws + 120586240);
  float*  comb = (float*) (ws + 120592384);
  float*  pvp  = (float*) (ws + 120854528);    // [64][16] partial logits
  float*  pe   = (float*) (ws + 120858624);    // 256 KB (perm layout, *log2e)
  ushort* ao   = xhi;   // alias: xhi dead after the projection GEMMs

  (void)hipFuncSetAttribute((const void*)attn_k,
      hipFuncAttributeMaxDynamicSharedMemorySize, 65536);
  (void)hipFuncSetAttribute((const void*)gemm_proj,
      hipFuncAttributeMaxDynamicSharedMemorySize, 65536);

  prep_k   <<<6464, 256, 0, stream>>>(x, Wq, Wk, Wv, Wo, bq, bk, bv, prior, fimp,
                                      xhi, xlo, Wthi, Wtlo, Wot, fb, pe, comb);
  pv_hid_k <<<32, 256, 0, stream>>>(comb, W1, b1, W2, pvp);
  gemm_proj<<<1536, 256, 65536, stream>>>(xhi, xlo, Wthi, Wtlo, fb,
                                          qhi, qlo, khi, klo, vt);
  attn_k   <<<1024, 512, 65536, stream>>>(qhi, qlo, khi, klo, vt, pe, pvp, b2, ao);
  gemm_out <<<512, 256, 0, stream>>>(ao, Wot, bo, (float*)d_out);

  (void)in_sizes; (void)n_in; (void)out_size; (void)ws_size;
}

// Round 10
// 233.796 us; speedup vs baseline: 2.4469x; 1.0757x over previous
//
#include <hip/hip_runtime.h>

// ---------------------------------------------------------------------------
// TabularDiffFlow sparse-attention pipeline, MI355X (gfx950)
// B=64, N=256, D=512, H=8, HD=64, top-k = 128 of 256 per score row.
//
// Precision: q,k projections and QK^T in split-bf16 (hi+lo, 3 MFMAs); v/P/
// out-proj plain bf16 (absmax 3.9e-3 vs 4.65e-3 threshold, R1-R9).
//
// R10: pv hidden GEMM fused INTO gemm_proj as 128 extra blocks (was an 82 µs
// serialized latency-bound kernel at 1.2% occupancy) — parallel scheme:
// 64-lane coalesced W1 reads, comb in LDS, unroll-8 ILP, wave-reduce to
// pvp[64][8]. GEMMs keep R9's 2-phase dbuf prefetch. attn unchanged except
// 8-partial pv logit sum.
// ---------------------------------------------------------------------------

typedef __attribute__((ext_vector_type(8))) short short8;
typedef __attribute__((ext_vector_type(4))) float float4v;

#define MFMA16(A,B,C) __builtin_amdgcn_mfma_f32_16x16x32_bf16((A),(B),(C),0,0,0)
#define LOG2E 1.4426950408889634f

__device__ __forceinline__ ushort f2bf(float f){
  unsigned u = __float_as_uint(f);
  unsigned r = u + 0x7FFFu + ((u >> 16) & 1u);   // round-to-nearest-even
  return (ushort)(r >> 16);
}
__device__ __forceinline__ float bf2f(ushort h){
  return __uint_as_float(((unsigned)h) << 16);
}
// async global -> LDS, 16 bytes per lane; LDS dest = wave-uniform base + lane*16
__device__ __forceinline__ void gl_lds16(const void* g, void* l){
  __builtin_amdgcn_global_load_lds(
      (const __attribute__((address_space(1))) unsigned int*)g,
      (__attribute__((address_space(3))) unsigned int*)l, 16, 0, 0);
}
// pack two f32 -> one u32 of two bf16 (RNE), low16 = a, high16 = b
__device__ __forceinline__ unsigned cvt_pk_bf16(float a, float b){
  unsigned r;
  asm("v_cvt_pk_bf16_f32 %0, %1, %2" : "=v"(r) : "v"(a), "v"(b));
  return r;
}

// ---------------------------------------------------------------- prep -----
// blocks [0,4096): x -> bf16 hi/lo.  [4096,6144): weight transposes.
// [6144,6400): prior (permuted, *log2e) (+ fb fill on first block).
// [6400,6464): pv means.
__global__ __launch_bounds__(256) void prep_k(
    const float* __restrict__ x,
    const float* __restrict__ Wq, const float* __restrict__ Wk,
    const float* __restrict__ Wv, const float* __restrict__ Wo,
    const float* __restrict__ bq, const float* __restrict__ bk,
    const float* __restrict__ bv,
    const float* __restrict__ prior, const float* __restrict__ fimp,
    ushort* __restrict__ xhi, ushort* __restrict__ xlo,
    ushort* __restrict__ Wthi, ushort* __restrict__ Wtlo,
    ushort* __restrict__ Wot, float* __restrict__ fb,
    float* __restrict__ pe, float* __restrict__ comb)
{
  int bid = (int)blockIdx.x, t = threadIdx.x;
  if (bid < 4096){
    size_t i = ((size_t)bid * 256 + t) * 8;
    float4v a = *(const float4v*)(x + i);
    float4v b = *(const float4v*)(x + i + 4);
    float v0=a[0],v1=a[1],v2=a[2],v3=a[3],v4=b[0],v5=b[1],v6=b[2],v7=b[3];
    ushort h0=f2bf(v0),h1=f2bf(v1),h2=f2bf(v2),h3=f2bf(v3);
    ushort h4=f2bf(v4),h5=f2bf(v5),h6=f2bf(v6),h7=f2bf(v7);
    ushort l0=f2bf(v0-bf2f(h0)),l1=f2bf(v1-bf2f(h1)),l2=f2bf(v2-bf2f(h2)),l3=f2bf(v3-bf2f(h3));
    ushort l4=f2bf(v4-bf2f(h4)),l5=f2bf(v5-bf2f(h5)),l6=f2bf(v6-bf2f(h6)),l7=f2bf(v7-bf2f(h7));
    uint4 ph, pl;
    ph.x = h0 | ((unsigned)h1<<16); ph.y = h2 | ((unsigned)h3<<16);
    ph.z = h4 | ((unsigned)h5<<16); ph.w = h6 | ((unsigned)h7<<16);
    pl.x = l0 | ((unsigned)l1<<16); pl.y = l2 | ((unsigned)l3<<16);
    pl.z = l4 | ((unsigned)l5<<16); pl.w = l6 | ((unsigned)l7<<16);
    *(uint4*)(xhi + i) = ph;
    *(uint4*)(xlo + i) = pl;
  } else if (bid < 6144){
    int r = bid - 4096;
    if (r < 1536){
      const float* W = (r < 512) ? Wq : ((r < 1024) ? Wk : Wv);
      int o = r & 511;
      bool dolo = (r < 1024);
      for (int i = t; i < 512; i += 256){
        float f = W[(size_t)i*512 + o];
        ushort hi = f2bf(f);
        Wthi[(size_t)r*512 + i] = hi;
        if (dolo) Wtlo[(size_t)r*512 + i] = f2bf(f - bf2f(hi));
      }
    } else {
      int o = r - 1536;
      for (int i = t; i < 512; i += 256)
        Wot[(size_t)o*512 + i] = f2bf(Wo[(size_t)i*512 + o]);
    }
  } else if (bid < 6400){
    int i = bid - 6144, j = t;
    int kt = ((j >> 5) << 1) | ((j >> 2) & 1);
    int g  = (j >> 3) & 3;
    int r  = j & 3;
    int slot = (kt << 4) | (g << 2) | r;
    pe[(size_t)i*256 + slot] = prior[(size_t)i*256 + j] * fimp[i] * fimp[j] * LOG2E;
    if (bid == 6144){
      for (int q = t; q < 1536; q += 256)
        fb[q] = (q < 512) ? bq[q] : ((q < 1024) ? bk[q-512] : bv[q-1024]);
    }
  } else {
    int b = bid - 6400;
    const float* xb = x + (size_t)b * 131072;
    float p0=0.f,p1=0.f,q0=0.f,q1=0.f;
    for (int n = 0; n < 128; n++){ p0 += xb[n*512 + t]; p1 += xb[n*512 + t + 256]; }
    for (int n = 128; n < 256; n++){ q0 += xb[n*512 + t]; q1 += xb[n*512 + t + 256]; }
    const float s = 1.0f/128.0f;
    comb[(size_t)b*1024 + t]             = p0*s;
    comb[(size_t)b*1024 + t + 256]       = p1*s;
    comb[(size_t)b*1024 + 512 + t]       = q0*s;
    comb[(size_t)b*1024 + 512 + t + 256] = q1*s;
  }
}

// --------------------------- fused projection GEMMs + pv hidden layer ------
// blocks [0,1024): split-bf16 qk GEMM (dbuf 2x32KB).
// [1024,1536): plain v GEMM, frag-layout epilogue (dbuf 2x16KB).
// [1536,1664): pv hidden GEMM: hid = silu(comb@W1+b1), partial W2-dot ->
//              pvp[64][8]. 64-lane coalesced W1 reads, comb in LDS.
__global__ __launch_bounds__(256) void gemm_proj(
    const ushort* __restrict__ xhi_, const ushort* __restrict__ xlo_,
    const ushort* __restrict__ Wthi, const ushort* __restrict__ Wtlo,
    const float* __restrict__ fb,
    const float* __restrict__ comb, const float* __restrict__ W1,
    const float* __restrict__ b1, const float* __restrict__ W2,
    float* __restrict__ pvp,
    ushort* __restrict__ qhi, ushort* __restrict__ qlo,
    ushort* __restrict__ khi, ushort* __restrict__ klo,
    ushort* __restrict__ vt)
{
  extern __shared__ __align__(16) char smx[];   // 64KB (qk) / 32KB (v) / 16KB (pv)
  int bid = (int)blockIdx.x;
  int tid = threadIdx.x, lane = tid & 63, w = tid >> 6, wm = w >> 1, wn = w & 1;
  int q15 = lane & 15, g = lane >> 4;
  int lrow = lane >> 2, lcol = (lane & 3) * 8;

  if (bid < 1024){
    int round = bid >> 7, rem = bid & 127;
    int sw = (round << 7) + ((rem & 7) << 4) + (rem >> 3);
    int n0 = (sw & 7) * 128, m0 = (sw >> 3) * 128;
    float4v acc[4][4] = {};

    auto STAGE = [&](int buf, int k0){
      #pragma unroll
      for (int t = 0; t < 8; t++){
        int id = (w << 3) + t;
        int mat = id >> 3, sp = id & 7;
        int row = ((mat < 2) ? m0 : n0) + sp*16 + lrow;
        const ushort* src;
        if      (mat == 0) src = xhi_ + (size_t)row*512 + k0 + lcol;
        else if (mat == 1) src = xlo_ + (size_t)row*512 + k0 + lcol;
        else if (mat == 2) src = Wthi + (size_t)row*512 + k0 + lcol;
        else               src = Wtlo + (size_t)row*512 + k0 + lcol;
        gl_lds16(src, smx + buf*32768 + (id << 10));
      }
    };

    STAGE(0, 0);
    __syncthreads();
    int buf = 0;
    for (int k0 = 0; k0 < 512; k0 += 32){
      if (k0 + 32 < 512) STAGE(buf ^ 1, k0 + 32);
      const char* sb = smx + buf*32768;
      short8 ah[4], al[4], bh[4], bl[4];
      #pragma unroll
      for (int i = 0; i < 4; i++){
        int ra = (wm*64 + i*16 + q15)*64 + g*16;
        int rb = (wn*64 + i*16 + q15)*64 + g*16;
        ah[i] = *(const short8*)(sb +         ra);
        al[i] = *(const short8*)(sb + 8192  + ra);
        bh[i] = *(const short8*)(sb + 16384 + rb);
        bl[i] = *(const short8*)(sb + 24576 + rb);
      }
      #pragma unroll
      for (int mi = 0; mi < 4; mi++){
        #pragma unroll
        for (int ni = 0; ni < 4; ni++){
          acc[mi][ni] = MFMA16(ah[mi], bh[ni], acc[mi][ni]);
          acc[mi][ni] = MFMA16(ah[mi], bl[ni], acc[mi][ni]);
          acc[mi][ni] = MFMA16(al[mi], bh[ni], acc[mi][ni]);
        }
      }
      __syncthreads();           // drains prefetch (vmcnt0) + frees buf
      buf ^= 1;
    }
    #pragma unroll
    for (int mi = 0; mi < 4; mi++){
      #pragma unroll
      for (int ni = 0; ni < 4; ni++){
        #pragma unroll
        for (int r = 0; r < 4; r++){
          int rg = m0 + wm*64 + mi*16 + (g<<2) + r;
          int cg = n0 + wn*64 + ni*16 + q15;
          float val = acc[mi][ni][r] + fb[cg];
          int which = cg >> 9, within = cg & 511;
          int bb = rg >> 8, seq = rg & 255, hh = within >> 6, hd = within & 63;
          size_t idx = ((size_t)((bb*8 + hh)*256 + seq))*64 + hd;
          ushort hi_ = f2bf(val);
          ushort lo_ = f2bf(val - bf2f(hi_));
          if (which == 0) { qhi[idx] = hi_; qlo[idx] = lo_; }
          else            { khi[idx] = hi_; klo[idx] = lo_; }
        }
      }
    }
  } else if (bid < 1536){
    int flat = bid - 1024;
    int round = flat >> 7, rem = flat & 127;
    int sw = (round << 7) + ((rem & 7) << 4) + (rem >> 3);
    int n0 = (sw & 3) * 128, m0 = (sw >> 2) * 128;
    const ushort* Bt = Wthi + (size_t)1024*512;
    const float* bias = fb + 1024;
    float4v acc[4][4] = {};

    auto STAGE = [&](int buf, int k0){
      #pragma unroll
      for (int t = 0; t < 4; t++){
        int id = (w << 2) + t;
        int mat = id >> 3, sp = id & 7;
        int row = ((mat == 0) ? m0 : n0) + sp*16 + lrow;
        const ushort* src = ((mat == 0) ? xhi_ : Bt) + (size_t)row*512 + k0 + lcol;
        gl_lds16(src, smx + buf*16384 + (id << 10));
      }
    };

    STAGE(0, 0);
    __syncthreads();
    int buf = 0;
    for (int k0 = 0; k0 < 512; k0 += 32){
      if (k0 + 32 < 512) STAGE(buf ^ 1, k0 + 32);
      const char* sb = smx + buf*16384;
      short8 af[4], bg4[4];
      #pragma unroll
      for (int i = 0; i < 4; i++){
        int ra = (wm*64 + i*16 + q15)*64 + g*16;
        int rb = (wn*64 + i*16 + q15)*64 + g*16;
        af[i]  = *(const short8*)(sb +        ra);
        bg4[i] = *(const short8*)(sb + 8192 + rb);
      }
      #pragma unroll
      for (int mi = 0; mi < 4; mi++){
        #pragma unroll
        for (int ni = 0; ni < 4; ni++)
          acc[mi][ni] = MFMA16(af[mi], bg4[ni], acc[mi][ni]);
      }
      __syncthreads();
      buf ^= 1;
    }
    #pragma unroll
    for (int mi = 0; mi < 4; mi++){
      #pragma unroll
      for (int ni = 0; ni < 4; ni++){
        int rg0 = m0 + wm*64 + mi*16 + (g<<2);
        int cg  = n0 + wn*64 + ni*16 + q15;
        int bb = rg0 >> 8, seq0 = rg0 & 255;
        int hh = cg >> 6, hd = cg & 63;
        int kb = seq0 >> 5, wi = seq0 & 31;
        float b_ = bias[cg];
        uint2 pk;
        pk.x = (unsigned)f2bf(acc[mi][ni][0] + b_) | ((unsigned)f2bf(acc[mi][ni][1] + b_) << 16);
        pk.y = (unsigned)f2bf(acc[mi][ni][2] + b_) | ((unsigned)f2bf(acc[mi][ni][3] + b_) << 16);
        size_t off = ((size_t)(bb*8 + hh) << 14) + (size_t)(((kb<<6) + hd) << 5) + wi;
        *(uint2*)(vt + off) = pk;
      }
    }
  } else {
    // ---- pv hidden-layer branch: 128 blocks = 8 col-tiles x 16 batch-tiles
    int flat2 = bid - 1536;
    int ct = flat2 & 7, bt = flat2 >> 3;
    float* cs = (float*)smx;                 // [4][1024] comb rows
    for (int j = tid; j < 4096; j += 256)
      cs[j] = comb[(size_t)(bt*4)*1024 + j];
    __syncthreads();
    int col = (ct << 6) + lane;              // wave w handles batch bt*4+w
    const float* csb = cs + (w << 10);
    float acc = b1[col];
    #pragma unroll 8
    for (int i = 0; i < 1024; i++)
      acc = fmaf(csb[i], W1[(size_t)i*512 + col], acc);
    float p = (acc / (1.0f + __expf(-acc))) * W2[col];
    p += __shfl_xor(p, 32); p += __shfl_xor(p, 16); p += __shfl_xor(p, 8);
    p += __shfl_xor(p, 4);  p += __shfl_xor(p, 2);  p += __shfl_xor(p, 1);
    if (lane == 0) pvp[((bt << 2) + w)*8 + ct] = p;
  }
}

// -------------------------------------------------- out-projection GEMM ----
__global__ __launch_bounds__(256) void gemm_out(
    const ushort* __restrict__ A, const ushort* __restrict__ Bt,
    const float* __restrict__ bias, float* __restrict__ outp)
{
  __shared__ __align__(16) char sm[32768];   // 2 x 16KB double buffer
  int flat = (int)blockIdx.x;
  int round = flat >> 7, rem = flat & 127;
  int sw = (round << 7) + ((rem & 7) << 4) + (rem >> 3);
  int n0 = (sw & 3) * 128, m0 = (sw >> 2) * 128;
  int tid = threadIdx.x, lane = tid & 63, w = tid >> 6, wm = w >> 1, wn = w & 1;
  int q15 = lane & 15, g = lane >> 4;
  int lrow = lane >> 2, lcol = (lane & 3) * 8;
  float4v acc[4][4] = {};

  auto STAGE = [&](int buf, int k0){
    #pragma unroll
    for (int t = 0; t < 4; t++){
      int id = (w << 2) + t;
      int mat = id >> 3, sp = id & 7;
      int row = ((mat == 0) ? m0 : n0) + sp*16 + lrow;
      const ushort* src = ((mat == 0) ? A : Bt) + (size_t)row*512 + k0 + lcol;
      gl_lds16(src, sm + buf*16384 + (id << 10));
    }
  };

  STAGE(0, 0);
  __syncthreads();
  int buf = 0;
  for (int k0 = 0; k0 < 512; k0 += 32){
    if (k0 + 32 < 512) STAGE(buf ^ 1, k0 + 32);
    const char* sb = sm + buf*16384;
    short8 af[4], bg4[4];
    #pragma unroll
    for (int i = 0; i < 4; i++){
      int ra = (wm*64 + i*16 + q15)*64 + g*16;
      int rb = (wn*64 + i*16 + q15)*64 + g*16;
      af[i]  = *(const short8*)(sb +        ra);
      bg4[i] = *(const short8*)(sb + 8192 + rb);
    }
    #pragma unroll
    for (int mi = 0; mi < 4; mi++){
      #pragma unroll
      for (int ni = 0; ni < 4; ni++)
        acc[mi][ni] = MFMA16(af[mi], bg4[ni], acc[mi][ni]);
    }
    __syncthreads();
    buf ^= 1;
  }
  #pragma unroll
  for (int mi = 0; mi < 4; mi++){
    #pragma unroll
    for (int ni = 0; ni < 4; ni++){
      int rg0 = m0 + wm*64 + mi*16 + (g<<2);
      int cg  = n0 + wn*64 + ni*16 + q15;
      float b_ = bias[cg];
      #pragma unroll
      for (int r = 0; r < 4; r++)
        outp[(size_t)(rg0 + r)*512 + cg] = acc[mi][ni][r] + b_;
    }
  }
}

// ------------------------------------------------------ fused attention ----
// 1024 blocks = (half-major, bh XCD-swizzled), 8 waves x 16 q-rows.
// LDS 64 KB = K hi/lo (rho-permuted fragment-major); V overwrites K region
// after QK^T. exp2-domain scores. Top-k = float bisection on [rowmin,rowmax]
// (exact kept-set incl. tie semantics); softmax without max-subtraction
// (bounded exponents). pvp partial logits (8) summed + sigmoid here.
__global__ __launch_bounds__(512, 4) void attn_k(
    const ushort* __restrict__ qhi_, const ushort* __restrict__ qlo_,
    const ushort* __restrict__ khi_, const ushort* __restrict__ klo_,
    const ushort* __restrict__ vt, const float* __restrict__ pe,
    const float* __restrict__ pvp, const float* __restrict__ b2,
    ushort* __restrict__ ao)
{
  extern __shared__ char sm[];   // 64KB: Khi 0..32K | Klo 32..64K; V -> 0..32K

  int bid = (int)blockIdx.x;
  int half = bid >> 9, s = bid & 511;
  int bh = ((s & 7) << 6) + (s >> 3);        // XCD swizzle (512 = 8*64)
  int b = bh >> 3, h = bh & 7;
  int tid = threadIdx.x, lane = tid & 63, w = tid >> 6;
  int g = lane >> 4, q15 = lane & 15;
  size_t base = (size_t)bh << 14;
  int qbase = (half << 7) + (w << 4);
  int qg = qbase + q15;

  // price/vol logit: sum of 8 partials + bias, sigmoid (uniform -> s_loads)
  float pvl = b2[0];
  #pragma unroll
  for (int i = 0; i < 8; i++) pvl += pvp[b*8 + i];
  float pvb2 = (1.0f / (1.0f + __expf(-pvl))) * (0.5f * LOG2E);
  const float scale2 = 0.125f * LOG2E;

  const ushort* qp1 = qhi_ + base + (size_t)qg*64 + (g<<3);
  const ushort* qp2 = qlo_ + base + (size_t)qg*64 + (g<<3);
  short8 qh0 = *(const short8*)(qp1);
  short8 qh1 = *(const short8*)(qp1 + 32);
  short8 ql0 = *(const short8*)(qp2);
  short8 ql1 = *(const short8*)(qp2 + 32);

  // ---- stage K hi/lo: 64 spans of 1KB, 8 per wave, rho-permuted rows
  #pragma unroll
  for (int t = 0; t < 8; t++){
    int sp = (w<<3) + t;
    int mat = sp >> 5, s5 = sp & 31, kt = s5 >> 1, hf = s5 & 1;
    int R = ((kt>>1)<<5) + ((q15>>2)<<3) + ((kt&1)<<2) + (q15&3);
    const ushort* gp = (mat ? klo_ : khi_) + base + (size_t)R*64 + hf*32 + g*8;
    gl_lds16(gp, sm + sp*1024);
  }
  __syncthreads();

  // ---- QK^T (split 3-mfma x 2 halves)
  float4v acc[16];
  #pragma unroll
  for (int kt = 0; kt < 16; kt++){
    short8 kh0 = *(const short8*)(sm +         kt*2048 +        lane*16);
    short8 kh1 = *(const short8*)(sm +         kt*2048 + 1024 + lane*16);
    short8 kl0 = *(const short8*)(sm + 32768 + kt*2048 +        lane*16);
    short8 kl1 = *(const short8*)(sm + 32768 + kt*2048 + 1024 + lane*16);
    float4v a = {0.f,0.f,0.f,0.f};
    a = MFMA16(kh0, qh0, a);
    a = MFMA16(kh1, qh1, a);
    a = MFMA16(kh0, ql0, a);
    a = MFMA16(kh1, ql1, a);
    a = MFMA16(kl0, qh0, a);
    a = MFMA16(kl1, qh1, a);
    acc[kt] = a;
  }
  __syncthreads();                           // all K LDS reads complete

  // ---- stage V into the K region (latency hides under topk VALU phase)
  #pragma unroll
  for (int t = 0; t < 4; t++){
    int vsp = (w<<2) + t;
    int mM = vsp >> 2, ht = vsp & 3;
    gl_lds16(vt + base + mM*2048 + (ht*16 + q15)*32 + g*8, sm + vsp*1024);
  }

  // ---- scaled-domain bias: s2 = raw*scale2 + pe2 + cb2
  bool qlow = (qg < 128);
  #pragma unroll
  for (int kt = 0; kt < 16; kt++){
    float4v p4 = *(const float4v*)(pe + qg*256 + (kt<<4) + (g<<2));
    float cb = (qlow != (kt < 8)) ? pvb2 : 0.0f;
    #pragma unroll
    for (int r = 0; r < 4; r++)
      acc[kt][r] = fmaf(acc[kt][r], scale2, p4[r] + cb);
  }

  // ---- row min/max across the 4-lane group
  float rmin = acc[0][0], rmax = acc[0][0];
  #pragma unroll
  for (int kt = 0; kt < 16; kt++){
    #pragma unroll
    for (int r = 0; r < 4; r++){
      rmin = fminf(rmin, acc[kt][r]);
      rmax = fmaxf(rmax, acc[kt][r]);
    }
  }
  rmin = fminf(rmin, __shfl_xor(rmin, 16));
  rmin = fminf(rmin, __shfl_xor(rmin, 32));
  rmax = fmaxf(rmax, __shfl_xor(rmax, 16));
  rmax = fmaxf(rmax, __shfl_xor(rmax, 32));

  // ---- exact 128th-largest: bisection on value space.
  float lo = rmin, hi = rmax;
  #pragma unroll 1
  for (int it = 0; it < 40; ++it){
    float mid = 0.5f*(lo + hi);
    if (!(mid > lo && mid < hi)) break;
    int cnt = 0;
    #pragma unroll
    for (int kt = 0; kt < 16; kt++){
      #pragma unroll
      for (int r = 0; r < 4; r++)
        cnt += (acc[kt][r] >= mid) ? 1 : 0;
    }
    cnt += __shfl_xor(cnt, 16);
    cnt += __shfl_xor(cnt, 32);
    if (cnt >= 128){
      lo = mid;
      if (cnt == 128) break;
    } else hi = mid;
  }
  float thrf = lo;

  // ---- softmax over kept (exp2 domain, no max subtraction: |s2| bounded)
  float sum = 0.0f;
  #pragma unroll
  for (int kt = 0; kt < 16; kt++){
    #pragma unroll
    for (int r = 0; r < 4; r++){
      float e = (acc[kt][r] >= thrf) ? exp2f(acc[kt][r]) : 0.0f;
      acc[kt][r] = e;
      sum += e;
    }
  }
  sum += __shfl_xor(sum, 16);
  sum += __shfl_xor(sum, 32);
  float inv = 1.0f / sum;

  __syncthreads();                           // V staged (vmcnt drained)

  // ---- PV fully in-register; V fragments from LDS
  float4v oa[4] = {};
  #pragma unroll
  for (int mM = 0; mM < 8; mM++){
    uint4 pk;
    pk.x = cvt_pk_bf16(acc[2*mM][0]*inv,   acc[2*mM][1]*inv);
    pk.y = cvt_pk_bf16(acc[2*mM][2]*inv,   acc[2*mM][3]*inv);
    pk.z = cvt_pk_bf16(acc[2*mM+1][0]*inv, acc[2*mM+1][1]*inv);
    pk.w = cvt_pk_bf16(acc[2*mM+1][2]*inv, acc[2*mM+1][3]*inv);
    short8 pf = *(short8*)&pk;
    #pragma unroll
    for (int ht = 0; ht < 4; ht++){
      short8 vf = *(const short8*)(sm + (mM*4 + ht)*1024 + lane*16);
      oa[ht] = MFMA16(pf, vf, oa[ht]);
    }
  }
  #pragma unroll
  for (int ht = 0; ht < 4; ht++){
    #pragma unroll
    for (int r = 0; r < 4; r++){
      int qo = qbase + (g<<2) + r;
      ao[((size_t)(b*256 + qo) << 9) + (h<<6) + (ht<<4) + q15] = f2bf(oa[ht][r]);
    }
  }
}

// ---------------------------------------------------------------------------
extern "C" void kernel_launch(void* const* d_in, const int* in_sizes, int n_in,
                              void* d_out, int out_size, void* d_ws, size_t ws_size,
                              hipStream_t stream)
{
  const float* x     = (const float*)d_in[0];
  const float* Wq    = (const float*)d_in[1];
  const float* bq    = (const float*)d_in[2];
  const float* Wk    = (const float*)d_in[3];
  const float* bk    = (const float*)d_in[4];
  const float* Wv    = (const float*)d_in[5];
  const float* bv    = (const float*)d_in[6];
  const float* Wo    = (const float*)d_in[7];
  const float* bo    = (const float*)d_in[8];
  const float* prior = (const float*)d_in[9];
  const float* fimp  = (const float*)d_in[10];
  const float* W1    = (const float*)d_in[11];
  const float* b1    = (const float*)d_in[12];
  const float* W2    = (const float*)d_in[13];
  const float* b2    = (const float*)d_in[14];

  char* ws = (char*)d_ws;
  ushort* xhi  = (ushort*)(ws + 0);
  ushort* xlo  = (ushort*)(ws + 16777216);
  ushort* qhi  = (ushort*)(ws + 33554432);
  ushort* qlo  = (ushort*)(ws + 50331648);
  ushort* khi  = (ushort*)(ws + 67108864);
  ushort* klo  = (ushort*)(ws + 83886080);
  ushort* vt   = (ushort*)(ws + 100663296);    // V in MFMA fragment layout
  ushort* Wthi = (ushort*)(ws + 117440512);
  ushort* Wtlo = (ushort*)(ws + 119013376);
  ushort* Wot  = (ushort*)(ws + 120061952);
  float*  fb   = (float*) (ws + 120586240);
  float*  comb = (float*) (ws + 120592384);
  float*  pvp  = (float*) (ws + 120854528);    // [64][8] partial logits
  float*  pe   = (float*) (ws + 120858624);    // 256 KB (perm layout, *log2e)
  ushort* ao   = xhi;   // alias: xhi dead after the projection GEMMs

  (void)hipFuncSetAttribute((const void*)attn_k,
      hipFuncAttributeMaxDynamicSharedMemorySize, 65536);
  (void)hipFuncSetAttribute((const void*)gemm_proj,
      hipFuncAttributeMaxDynamicSharedMemorySize, 65536);

  prep_k   <<<6464, 256, 0, stream>>>(x, Wq, Wk, Wv, Wo, bq, bk, bv, prior, fimp,
                                      xhi, xlo, Wthi, Wtlo, Wot, fb, pe, comb);
  gemm_proj<<<1664, 256, 65536, stream>>>(xhi, xlo, Wthi, Wtlo, fb,
                                          comb, W1, b1, W2, pvp,
                                          qhi, qlo, khi, klo, vt);
  attn_k   <<<1024, 512, 65536, stream>>>(qhi, qlo, khi, klo, vt, pe, pvp, b2, ao);
  gemm_out <<<512, 256, 0, stream>>>(ao, Wot, bo, (float*)d_out);

  (void)in_sizes; (void)n_in; (void)out_size; (void)ws_size;
}

// Round 11
// 204.246 us; speedup vs baseline: 2.8009x; 1.1447x over previous
//
#include <hip/hip_runtime.h>

// ---------------------------------------------------------------------------
// TabularDiffFlow sparse-attention pipeline, MI355X (gfx950)
// B=64, N=256, D=512, H=8, HD=64, top-k = 128 of 256 per score row.
//
// Precision: q,k projections and QK^T in split-bf16 (hi+lo, 3 MFMAs); v/P/
// out-proj plain bf16 (absmax 3.9e-3 vs 4.65e-3 threshold, R1-R10).
//
// R11: pv hidden layer back to its own kernel but PARALLEL: 512 blocks
// (8 col-tiles x 64 batches), K=1024 split across 4 waves (256 iters each,
// unroll-8 ILP), LDS partial reduce -> silu -> W2 dot. R10's in-GEMM fusion
// straggled 70 µs (latency-serialized tail inside gemm_proj). gemm_proj
// reverted to the measured-good R9 1536-block form.
// ---------------------------------------------------------------------------

typedef __attribute__((ext_vector_type(8))) short short8;
typedef __attribute__((ext_vector_type(4))) float float4v;

#define MFMA16(A,B,C) __builtin_amdgcn_mfma_f32_16x16x32_bf16((A),(B),(C),0,0,0)
#define LOG2E 1.4426950408889634f

__device__ __forceinline__ ushort f2bf(float f){
  unsigned u = __float_as_uint(f);
  unsigned r = u + 0x7FFFu + ((u >> 16) & 1u);   // round-to-nearest-even
  return (ushort)(r >> 16);
}
__device__ __forceinline__ float bf2f(ushort h){
  return __uint_as_float(((unsigned)h) << 16);
}
// async global -> LDS, 16 bytes per lane; LDS dest = wave-uniform base + lane*16
__device__ __forceinline__ void gl_lds16(const void* g, void* l){
  __builtin_amdgcn_global_load_lds(
      (const __attribute__((address_space(1))) unsigned int*)g,
      (__attribute__((address_space(3))) unsigned int*)l, 16, 0, 0);
}
// pack two f32 -> one u32 of two bf16 (RNE), low16 = a, high16 = b
__device__ __forceinline__ unsigned cvt_pk_bf16(float a, float b){
  unsigned r;
  asm("v_cvt_pk_bf16_f32 %0, %1, %2" : "=v"(r) : "v"(a), "v"(b));
  return r;
}

// ---------------------------------------------------------------- prep -----
// blocks [0,4096): x -> bf16 hi/lo.  [4096,6144): weight transposes.
// [6144,6400): prior (permuted, *log2e) (+ fb fill on first block).
// [6400,6464): pv means.
__global__ __launch_bounds__(256) void prep_k(
    const float* __restrict__ x,
    const float* __restrict__ Wq, const float* __restrict__ Wk,
    const float* __restrict__ Wv, const float* __restrict__ Wo,
    const float* __restrict__ bq, const float* __restrict__ bk,
    const float* __restrict__ bv,
    const float* __restrict__ prior, const float* __restrict__ fimp,
    ushort* __restrict__ xhi, ushort* __restrict__ xlo,
    ushort* __restrict__ Wthi, ushort* __restrict__ Wtlo,
    ushort* __restrict__ Wot, float* __restrict__ fb,
    float* __restrict__ pe, float* __restrict__ comb)
{
  int bid = (int)blockIdx.x, t = threadIdx.x;
  if (bid < 4096){
    size_t i = ((size_t)bid * 256 + t) * 8;
    float4v a = *(const float4v*)(x + i);
    float4v b = *(const float4v*)(x + i + 4);
    float v0=a[0],v1=a[1],v2=a[2],v3=a[3],v4=b[0],v5=b[1],v6=b[2],v7=b[3];
    ushort h0=f2bf(v0),h1=f2bf(v1),h2=f2bf(v2),h3=f2bf(v3);
    ushort h4=f2bf(v4),h5=f2bf(v5),h6=f2bf(v6),h7=f2bf(v7);
    ushort l0=f2bf(v0-bf2f(h0)),l1=f2bf(v1-bf2f(h1)),l2=f2bf(v2-bf2f(h2)),l3=f2bf(v3-bf2f(h3));
    ushort l4=f2bf(v4-bf2f(h4)),l5=f2bf(v5-bf2f(h5)),l6=f2bf(v6-bf2f(h6)),l7=f2bf(v7-bf2f(h7));
    uint4 ph, pl;
    ph.x = h0 | ((unsigned)h1<<16); ph.y = h2 | ((unsigned)h3<<16);
    ph.z = h4 | ((unsigned)h5<<16); ph.w = h6 | ((unsigned)h7<<16);
    pl.x = l0 | ((unsigned)l1<<16); pl.y = l2 | ((unsigned)l3<<16);
    pl.z = l4 | ((unsigned)l5<<16); pl.w = l6 | ((unsigned)l7<<16);
    *(uint4*)(xhi + i) = ph;
    *(uint4*)(xlo + i) = pl;
  } else if (bid < 6144){
    int r = bid - 4096;
    if (r < 1536){
      const float* W = (r < 512) ? Wq : ((r < 1024) ? Wk : Wv);
      int o = r & 511;
      bool dolo = (r < 1024);
      for (int i = t; i < 512; i += 256){
        float f = W[(size_t)i*512 + o];
        ushort hi = f2bf(f);
        Wthi[(size_t)r*512 + i] = hi;
        if (dolo) Wtlo[(size_t)r*512 + i] = f2bf(f - bf2f(hi));
      }
    } else {
      int o = r - 1536;
      for (int i = t; i < 512; i += 256)
        Wot[(size_t)o*512 + i] = f2bf(Wo[(size_t)i*512 + o]);
    }
  } else if (bid < 6400){
    int i = bid - 6144, j = t;
    int kt = ((j >> 5) << 1) | ((j >> 2) & 1);
    int g  = (j >> 3) & 3;
    int r  = j & 3;
    int slot = (kt << 4) | (g << 2) | r;
    pe[(size_t)i*256 + slot] = prior[(size_t)i*256 + j] * fimp[i] * fimp[j] * LOG2E;
    if (bid == 6144){
      for (int q = t; q < 1536; q += 256)
        fb[q] = (q < 512) ? bq[q] : ((q < 1024) ? bk[q-512] : bv[q-1024]);
    }
  } else {
    int b = bid - 6400;
    const float* xb = x + (size_t)b * 131072;
    float p0=0.f,p1=0.f,q0=0.f,q1=0.f;
    for (int n = 0; n < 128; n++){ p0 += xb[n*512 + t]; p1 += xb[n*512 + t + 256]; }
    for (int n = 128; n < 256; n++){ q0 += xb[n*512 + t]; q1 += xb[n*512 + t + 256]; }
    const float s = 1.0f/128.0f;
    comb[(size_t)b*1024 + t]             = p0*s;
    comb[(size_t)b*1024 + t + 256]       = p1*s;
    comb[(size_t)b*1024 + 512 + t]       = q0*s;
    comb[(size_t)b*1024 + 512 + t + 256] = q1*s;
  }
}

// -------------------------------------------------------------- pv path ----
// 512 blocks = 8 col-tiles(64 cols) x 64 batches; the K=1024 dim is split
// across the 4 waves (256 iters each, unroll-8 -> 8 loads in flight), LDS
// partial reduce, silu + W2-dot in wave 0 -> pvp[64][8].
__global__ __launch_bounds__(256) void pv_hid_k(const float* __restrict__ comb,
    const float* __restrict__ W1, const float* __restrict__ b1,
    const float* __restrict__ W2, float* __restrict__ pvp){
  __shared__ float cs[1024];
  __shared__ float red[4][64];
  int ct = blockIdx.x & 7, b = blockIdx.x >> 3;
  int t = threadIdx.x, lane = t & 63, w = t >> 6;
  for (int i = t; i < 1024; i += 256) cs[i] = comb[(size_t)b*1024 + i];
  __syncthreads();
  int col = (ct << 6) + lane;
  const float* w1p = W1 + (size_t)(w << 8)*512 + col;
  const float* csp = cs + (w << 8);
  float acc = 0.f;
  #pragma unroll 8
  for (int i = 0; i < 256; i++)
    acc = fmaf(csp[i], w1p[(size_t)i*512], acc);
  red[w][lane] = acc;
  __syncthreads();
  if (w == 0){
    float a = red[0][lane] + red[1][lane] + red[2][lane] + red[3][lane] + b1[col];
    float p = (a / (1.0f + __expf(-a))) * W2[col];
    p += __shfl_xor(p, 32); p += __shfl_xor(p, 16); p += __shfl_xor(p, 8);
    p += __shfl_xor(p, 4);  p += __shfl_xor(p, 2);  p += __shfl_xor(p, 1);
    if (lane == 0) pvp[b*8 + ct] = p;
  }
}

// --------------------------------------- fused projection GEMMs (qk + v) ---
// blocks [0,1024): split-bf16 qk GEMM (dbuf 2x32KB). [1024,1536): plain v
// GEMM, frag-layout epilogue (dbuf 2x16KB). 2-phase prefetched staging.
__global__ __launch_bounds__(256) void gemm_proj(
    const ushort* __restrict__ xhi_, const ushort* __restrict__ xlo_,
    const ushort* __restrict__ Wthi, const ushort* __restrict__ Wtlo,
    const float* __restrict__ fb,
    ushort* __restrict__ qhi, ushort* __restrict__ qlo,
    ushort* __restrict__ khi, ushort* __restrict__ klo,
    ushort* __restrict__ vt)
{
  extern __shared__ __align__(16) char smx[];   // 64KB (qk) / 32KB used (v)
  int bid = (int)blockIdx.x;
  int tid = threadIdx.x, lane = tid & 63, w = tid >> 6, wm = w >> 1, wn = w & 1;
  int q15 = lane & 15, g = lane >> 4;
  int lrow = lane >> 2, lcol = (lane & 3) * 8;

  if (bid < 1024){
    int round = bid >> 7, rem = bid & 127;
    int sw = (round << 7) + ((rem & 7) << 4) + (rem >> 3);
    int n0 = (sw & 7) * 128, m0 = (sw >> 3) * 128;
    float4v acc[4][4] = {};

    auto STAGE = [&](int buf, int k0){
      #pragma unroll
      for (int t = 0; t < 8; t++){
        int id = (w << 3) + t;
        int mat = id >> 3, sp = id & 7;
        int row = ((mat < 2) ? m0 : n0) + sp*16 + lrow;
        const ushort* src;
        if      (mat == 0) src = xhi_ + (size_t)row*512 + k0 + lcol;
        else if (mat == 1) src = xlo_ + (size_t)row*512 + k0 + lcol;
        else if (mat == 2) src = Wthi + (size_t)row*512 + k0 + lcol;
        else               src = Wtlo + (size_t)row*512 + k0 + lcol;
        gl_lds16(src, smx + buf*32768 + (id << 10));
      }
    };

    STAGE(0, 0);
    __syncthreads();
    int buf = 0;
    for (int k0 = 0; k0 < 512; k0 += 32){
      if (k0 + 32 < 512) STAGE(buf ^ 1, k0 + 32);
      const char* sb = smx + buf*32768;
      short8 ah[4], al[4], bh[4], bl[4];
      #pragma unroll
      for (int i = 0; i < 4; i++){
        int ra = (wm*64 + i*16 + q15)*64 + g*16;
        int rb = (wn*64 + i*16 + q15)*64 + g*16;
        ah[i] = *(const short8*)(sb +         ra);
        al[i] = *(const short8*)(sb + 8192  + ra);
        bh[i] = *(const short8*)(sb + 16384 + rb);
        bl[i] = *(const short8*)(sb + 24576 + rb);
      }
      #pragma unroll
      for (int mi = 0; mi < 4; mi++){
        #pragma unroll
        for (int ni = 0; ni < 4; ni++){
          acc[mi][ni] = MFMA16(ah[mi], bh[ni], acc[mi][ni]);
          acc[mi][ni] = MFMA16(ah[mi], bl[ni], acc[mi][ni]);
          acc[mi][ni] = MFMA16(al[mi], bh[ni], acc[mi][ni]);
        }
      }
      __syncthreads();           // drains prefetch (vmcnt0) + frees buf
      buf ^= 1;
    }
    #pragma unroll
    for (int mi = 0; mi < 4; mi++){
      #pragma unroll
      for (int ni = 0; ni < 4; ni++){
        #pragma unroll
        for (int r = 0; r < 4; r++){
          int rg = m0 + wm*64 + mi*16 + (g<<2) + r;
          int cg = n0 + wn*64 + ni*16 + q15;
          float val = acc[mi][ni][r] + fb[cg];
          int which = cg >> 9, within = cg & 511;
          int bb = rg >> 8, seq = rg & 255, hh = within >> 6, hd = within & 63;
          size_t idx = ((size_t)((bb*8 + hh)*256 + seq))*64 + hd;
          ushort hi_ = f2bf(val);
          ushort lo_ = f2bf(val - bf2f(hi_));
          if (which == 0) { qhi[idx] = hi_; qlo[idx] = lo_; }
          else            { khi[idx] = hi_; klo[idx] = lo_; }
        }
      }
    }
  } else {
    int flat = bid - 1024;
    int round = flat >> 7, rem = flat & 127;
    int sw = (round << 7) + ((rem & 7) << 4) + (rem >> 3);
    int n0 = (sw & 3) * 128, m0 = (sw >> 2) * 128;
    const ushort* Bt = Wthi + (size_t)1024*512;
    const float* bias = fb + 1024;
    float4v acc[4][4] = {};

    auto STAGE = [&](int buf, int k0){
      #pragma unroll
      for (int t = 0; t < 4; t++){
        int id = (w << 2) + t;
        int mat = id >> 3, sp = id & 7;
        int row = ((mat == 0) ? m0 : n0) + sp*16 + lrow;
        const ushort* src = ((mat == 0) ? xhi_ : Bt) + (size_t)row*512 + k0 + lcol;
        gl_lds16(src, smx + buf*16384 + (id << 10));
      }
    };

    STAGE(0, 0);
    __syncthreads();
    int buf = 0;
    for (int k0 = 0; k0 < 512; k0 += 32){
      if (k0 + 32 < 512) STAGE(buf ^ 1, k0 + 32);
      const char* sb = smx + buf*16384;
      short8 af[4], bg4[4];
      #pragma unroll
      for (int i = 0; i < 4; i++){
        int ra = (wm*64 + i*16 + q15)*64 + g*16;
        int rb = (wn*64 + i*16 + q15)*64 + g*16;
        af[i]  = *(const short8*)(sb +        ra);
        bg4[i] = *(const short8*)(sb + 8192 + rb);
      }
      #pragma unroll
      for (int mi = 0; mi < 4; mi++){
        #pragma unroll
        for (int ni = 0; ni < 4; ni++)
          acc[mi][ni] = MFMA16(af[mi], bg4[ni], acc[mi][ni]);
      }
      __syncthreads();
      buf ^= 1;
    }
    #pragma unroll
    for (int mi = 0; mi < 4; mi++){
      #pragma unroll
      for (int ni = 0; ni < 4; ni++){
        int rg0 = m0 + wm*64 + mi*16 + (g<<2);
        int cg  = n0 + wn*64 + ni*16 + q15;
        int bb = rg0 >> 8, seq0 = rg0 & 255;
        int hh = cg >> 6, hd = cg & 63;
        int kb = seq0 >> 5, wi = seq0 & 31;
        float b_ = bias[cg];
        uint2 pk;
        pk.x = (unsigned)f2bf(acc[mi][ni][0] + b_) | ((unsigned)f2bf(acc[mi][ni][1] + b_) << 16);
        pk.y = (unsigned)f2bf(acc[mi][ni][2] + b_) | ((unsigned)f2bf(acc[mi][ni][3] + b_) << 16);
        size_t off = ((size_t)(bb*8 + hh) << 14) + (size_t)(((kb<<6) + hd) << 5) + wi;
        *(uint2*)(vt + off) = pk;
      }
    }
  }
}

// -------------------------------------------------- out-projection GEMM ----
__global__ __launch_bounds__(256) void gemm_out(
    const ushort* __restrict__ A, const ushort* __restrict__ Bt,
    const float* __restrict__ bias, float* __restrict__ outp)
{
  __shared__ __align__(16) char sm[32768];   // 2 x 16KB double buffer
  int flat = (int)blockIdx.x;
  int round = flat >> 7, rem = flat & 127;
  int sw = (round << 7) + ((rem & 7) << 4) + (rem >> 3);
  int n0 = (sw & 3) * 128, m0 = (sw >> 2) * 128;
  int tid = threadIdx.x, lane = tid & 63, w = tid >> 6, wm = w >> 1, wn = w & 1;
  int q15 = lane & 15, g = lane >> 4;
  int lrow = lane >> 2, lcol = (lane & 3) * 8;
  float4v acc[4][4] = {};

  auto STAGE = [&](int buf, int k0){
    #pragma unroll
    for (int t = 0; t < 4; t++){
      int id = (w << 2) + t;
      int mat = id >> 3, sp = id & 7;
      int row = ((mat == 0) ? m0 : n0) + sp*16 + lrow;
      const ushort* src = ((mat == 0) ? A : Bt) + (size_t)row*512 + k0 + lcol;
      gl_lds16(src, sm + buf*16384 + (id << 10));
    }
  };

  STAGE(0, 0);
  __syncthreads();
  int buf = 0;
  for (int k0 = 0; k0 < 512; k0 += 32){
    if (k0 + 32 < 512) STAGE(buf ^ 1, k0 + 32);
    const char* sb = sm + buf*16384;
    short8 af[4], bg4[4];
    #pragma unroll
    for (int i = 0; i < 4; i++){
      int ra = (wm*64 + i*16 + q15)*64 + g*16;
      int rb = (wn*64 + i*16 + q15)*64 + g*16;
      af[i]  = *(const short8*)(sb +        ra);
      bg4[i] = *(const short8*)(sb + 8192 + rb);
    }
    #pragma unroll
    for (int mi = 0; mi < 4; mi++){
      #pragma unroll
      for (int ni = 0; ni < 4; ni++)
        acc[mi][ni] = MFMA16(af[mi], bg4[ni], acc[mi][ni]);
    }
    __syncthreads();
    buf ^= 1;
  }
  #pragma unroll
  for (int mi = 0; mi < 4; mi++){
    #pragma unroll
    for (int ni = 0; ni < 4; ni++){
      int rg0 = m0 + wm*64 + mi*16 + (g<<2);
      int cg  = n0 + wn*64 + ni*16 + q15;
      float b_ = bias[cg];
      #pragma unroll
      for (int r = 0; r < 4; r++)
        outp[(size_t)(rg0 + r)*512 + cg] = acc[mi][ni][r] + b_;
    }
  }
}

// ------------------------------------------------------ fused attention ----
// 1024 blocks = (half-major, bh XCD-swizzled), 8 waves x 16 q-rows.
// LDS 64 KB = K hi/lo (rho-permuted fragment-major); V overwrites K region
// after QK^T. exp2-domain scores. Top-k = float bisection on [rowmin,rowmax]
// (exact kept-set incl. tie semantics); softmax without max-subtraction
// (bounded exponents). pvp partial logits (8) summed + sigmoid here.
__global__ __launch_bounds__(512, 4) void attn_k(
    const ushort* __restrict__ qhi_, const ushort* __restrict__ qlo_,
    const ushort* __restrict__ khi_, const ushort* __restrict__ klo_,
    const ushort* __restrict__ vt, const float* __restrict__ pe,
    const float* __restrict__ pvp, const float* __restrict__ b2,
    ushort* __restrict__ ao)
{
  extern __shared__ char sm[];   // 64KB: Khi 0..32K | Klo 32..64K; V -> 0..32K

  int bid = (int)blockIdx.x;
  int half = bid >> 9, s = bid & 511;
  int bh = ((s & 7) << 6) + (s >> 3);        // XCD swizzle (512 = 8*64)
  int b = bh >> 3, h = bh & 7;
  int tid = threadIdx.x, lane = tid & 63, w = tid >> 6;
  int g = lane >> 4, q15 = lane & 15;
  size_t base = (size_t)bh << 14;
  int qbase = (half << 7) + (w << 4);
  int qg = qbase + q15;

  // price/vol logit: sum of 8 partials + bias, sigmoid (uniform -> s_loads)
  float pvl = b2[0];
  #pragma unroll
  for (int i = 0; i < 8; i++) pvl += pvp[b*8 + i];
  float pvb2 = (1.0f / (1.0f + __expf(-pvl))) * (0.5f * LOG2E);
  const float scale2 = 0.125f * LOG2E;

  const ushort* qp1 = qhi_ + base + (size_t)qg*64 + (g<<3);
  const ushort* qp2 = qlo_ + base + (size_t)qg*64 + (g<<3);
  short8 qh0 = *(const short8*)(qp1);
  short8 qh1 = *(const short8*)(qp1 + 32);
  short8 ql0 = *(const short8*)(qp2);
  short8 ql1 = *(const short8*)(qp2 + 32);

  // ---- stage K hi/lo: 64 spans of 1KB, 8 per wave, rho-permuted rows
  #pragma unroll
  for (int t = 0; t < 8; t++){
    int sp = (w<<3) + t;
    int mat = sp >> 5, s5 = sp & 31, kt = s5 >> 1, hf = s5 & 1;
    int R = ((kt>>1)<<5) + ((q15>>2)<<3) + ((kt&1)<<2) + (q15&3);
    const ushort* gp = (mat ? klo_ : khi_) + base + (size_t)R*64 + hf*32 + g*8;
    gl_lds16(gp, sm + sp*1024);
  }
  __syncthreads();

  // ---- QK^T (split 3-mfma x 2 halves)
  float4v acc[16];
  #pragma unroll
  for (int kt = 0; kt < 16; kt++){
    short8 kh0 = *(const short8*)(sm +         kt*2048 +        lane*16);
    short8 kh1 = *(const short8*)(sm +         kt*2048 + 1024 + lane*16);
    short8 kl0 = *(const short8*)(sm + 32768 + kt*2048 +        lane*16);
    short8 kl1 = *(const short8*)(sm + 32768 + kt*2048 + 1024 + lane*16);
    float4v a = {0.f,0.f,0.f,0.f};
    a = MFMA16(kh0, qh0, a);
    a = MFMA16(kh1, qh1, a);
    a = MFMA16(kh0, ql0, a);
    a = MFMA16(kh1, ql1, a);
    a = MFMA16(kl0, qh0, a);
    a = MFMA16(kl1, qh1, a);
    acc[kt] = a;
  }
  __syncthreads();                           // all K LDS reads complete

  // ---- stage V into the K region (latency hides under topk VALU phase)
  #pragma unroll
  for (int t = 0; t < 4; t++){
    int vsp = (w<<2) + t;
    int mM = vsp >> 2, ht = vsp & 3;
    gl_lds16(vt + base + mM*2048 + (ht*16 + q15)*32 + g*8, sm + vsp*1024);
  }

  // ---- scaled-domain bias: s2 = raw*scale2 + pe2 + cb2
  bool qlow = (qg < 128);
  #pragma unroll
  for (int kt = 0; kt < 16; kt++){
    float4v p4 = *(const float4v*)(pe + qg*256 + (kt<<4) + (g<<2));
    float cb = (qlow != (kt < 8)) ? pvb2 : 0.0f;
    #pragma unroll
    for (int r = 0; r < 4; r++)
      acc[kt][r] = fmaf(acc[kt][r], scale2, p4[r] + cb);
  }

  // ---- row min/max across the 4-lane group
  float rmin = acc[0][0], rmax = acc[0][0];
  #pragma unroll
  for (int kt = 0; kt < 16; kt++){
    #pragma unroll
    for (int r = 0; r < 4; r++){
      rmin = fminf(rmin, acc[kt][r]);
      rmax = fmaxf(rmax, acc[kt][r]);
    }
  }
  rmin = fminf(rmin, __shfl_xor(rmin, 16));
  rmin = fminf(rmin, __shfl_xor(rmin, 32));
  rmax = fmaxf(rmax, __shfl_xor(rmax, 16));
  rmax = fmaxf(rmax, __shfl_xor(rmax, 32));

  // ---- exact 128th-largest: bisection on value space.
  float lo = rmin, hi = rmax;
  #pragma unroll 1
  for (int it = 0; it < 40; ++it){
    float mid = 0.5f*(lo + hi);
    if (!(mid > lo && mid < hi)) break;
    int cnt = 0;
    #pragma unroll
    for (int kt = 0; kt < 16; kt++){
      #pragma unroll
      for (int r = 0; r < 4; r++)
        cnt += (acc[kt][r] >= mid) ? 1 : 0;
    }
    cnt += __shfl_xor(cnt, 16);
    cnt += __shfl_xor(cnt, 32);
    if (cnt >= 128){
      lo = mid;
      if (cnt == 128) break;
    } else hi = mid;
  }
  float thrf = lo;

  // ---- softmax over kept (exp2 domain, no max subtraction: |s2| bounded)
  float sum = 0.0f;
  #pragma unroll
  for (int kt = 0; kt < 16; kt++){
    #pragma unroll
    for (int r = 0; r < 4; r++){
      float e = (acc[kt][r] >= thrf) ? exp2f(acc[kt][r]) : 0.0f;
      acc[kt][r] = e;
      sum += e;
    }
  }
  sum += __shfl_xor(sum, 16);
  sum += __shfl_xor(sum, 32);
  float inv = 1.0f / sum;

  __syncthreads();                           // V staged (vmcnt drained)

  // ---- PV fully in-register; V fragments from LDS
  float4v oa[4] = {};
  #pragma unroll
  for (int mM = 0; mM < 8; mM++){
    uint4 pk;
    pk.x = cvt_pk_bf16(acc[2*mM][0]*inv,   acc[2*mM][1]*inv);
    pk.y = cvt_pk_bf16(acc[2*mM][2]*inv,   acc[2*mM][3]*inv);
    pk.z = cvt_pk_bf16(acc[2*mM+1][0]*inv, acc[2*mM+1][1]*inv);
    pk.w = cvt_pk_bf16(acc[2*mM+1][2]*inv, acc[2*mM+1][3]*inv);
    short8 pf = *(short8*)&pk;
    #pragma unroll
    for (int ht = 0; ht < 4; ht++){
      short8 vf = *(const short8*)(sm + (mM*4 + ht)*1024 + lane*16);
      oa[ht] = MFMA16(pf, vf, oa[ht]);
    }
  }
  #pragma unroll
  for (int ht = 0; ht < 4; ht++){
    #pragma unroll
    for (int r = 0; r < 4; r++){
      int qo = qbase + (g<<2) + r;
      ao[((size_t)(b*256 + qo) << 9) + (h<<6) + (ht<<4) + q15] = f2bf(oa[ht][r]);
    }
  }
}

// ---------------------------------------------------------------------------
extern "C" void kernel_launch(void* const* d_in, const int* in_sizes, int n_in,
                              void* d_out, int out_size, void* d_ws, size_t ws_size,
                              hipStream_t stream)
{
  const float* x     = (const float*)d_in[0];
  const float* Wq    = (const float*)d_in[1];
  const float* bq    = (const float*)d_in[2];
  const float* Wk    = (const float*)d_in[3];
  const float* bk    = (const float*)d_in[4];
  const float* Wv    = (const float*)d_in[5];
  const float* bv    = (const float*)d_in[6];
  const float* Wo    = (const float*)d_in[7];
  const float* bo    = (const float*)d_in[8];
  const float* prior = (const float*)d_in[9];
  const float* fimp  = (const float*)d_in[10];
  const float* W1    = (const float*)d_in[11];
  const float* b1    = (const float*)d_in[12];
  const float* W2    = (const float*)d_in[13];
  const float* b2    = (const float*)d_in[14];

  char* ws = (char*)d_ws;
  ushort* xhi  = (ushort*)(ws + 0);
  ushort* xlo  = (ushort*)(ws + 16777216);
  ushort* qhi  = (ushort*)(ws + 33554432);
  ushort* qlo  = (ushort*)(ws + 50331648);
  ushort* khi  = (ushort*)(ws + 67108864);
  ushort* klo  = (ushort*)(ws + 83886080);
  ushort* vt   = (ushort*)(ws + 100663296);    // V in MFMA fragment layout
  ushort* Wthi = (ushort*)(ws + 117440512);
  ushort* Wtlo = (ushort*)(ws + 119013376);
  ushort* Wot  = (ushort*)(ws + 120061952);
  float*  fb   = (float*) (ws + 120586240);
  float*  comb = (float*) (ws + 120592384);
  float*  pvp  = (float*) (ws + 120854528);    // [64][8] partial logits
  float*  pe   = (float*) (ws + 120858624);    // 256 KB (perm layout, *log2e)
  ushort* ao   = xhi;   // alias: xhi dead after the projection GEMMs

  (void)hipFuncSetAttribute((const void*)attn_k,
      hipFuncAttributeMaxDynamicSharedMemorySize, 65536);
  (void)hipFuncSetAttribute((const void*)gemm_proj,
      hipFuncAttributeMaxDynamicSharedMemorySize, 65536);

  prep_k   <<<6464, 256, 0, stream>>>(x, Wq, Wk, Wv, Wo, bq, bk, bv, prior, fimp,
                                      xhi, xlo, Wthi, Wtlo, Wot, fb, pe, comb);
  pv_hid_k <<<512, 256, 0, stream>>>(comb, W1, b1, W2, pvp);
  gemm_proj<<<1536, 256, 65536, stream>>>(xhi, xlo, Wthi, Wtlo, fb,
                                          qhi, qlo, khi, klo, vt);
  attn_k   <<<1024, 512, 65536, stream>>>(qhi, qlo, khi, klo, vt, pe, pvp, b2, ao);
  gemm_out <<<512, 256, 0, stream>>>(ao, Wot, bo, (float*)d_out);

  (void)in_sizes; (void)n_in; (void)out_size; (void)ws_size;
}

// Round 12
// 202.467 us; speedup vs baseline: 2.8255x; 1.0088x over previous
//
#include <hip/hip_runtime.h>

// ---------------------------------------------------------------------------
// TabularDiffFlow sparse-attention pipeline, MI355X (gfx950)
// B=64, N=256, D=512, H=8, HD=64, top-k = 128 of 256 per score row.
//
// Precision: q,k projections and QK^T in split-bf16 (hi+lo, 3 MFMAs); v/P/
// out-proj plain bf16 (absmax 3.9e-3 vs 4.65e-3 threshold, R1-R11).
//
// R12: (1) gemm_proj qk branch reads Blo (Wtlo, 1 MB L2-resident weights)
// fragments directly from global -> LDS 64->48 KB dbuf -> 3 blocks/CU.
// (2) prep_k weight transposes via LDS 64x65 tiles (both sides coalesced;
// was stride-512 scalar reads with ~16x line overfetch). attn/pv/gemm_out
// frozen from R11.
// ---------------------------------------------------------------------------

typedef __attribute__((ext_vector_type(8))) short short8;
typedef __attribute__((ext_vector_type(4))) float float4v;

#define MFMA16(A,B,C) __builtin_amdgcn_mfma_f32_16x16x32_bf16((A),(B),(C),0,0,0)
#define LOG2E 1.4426950408889634f

__device__ __forceinline__ ushort f2bf(float f){
  unsigned u = __float_as_uint(f);
  unsigned r = u + 0x7FFFu + ((u >> 16) & 1u);   // round-to-nearest-even
  return (ushort)(r >> 16);
}
__device__ __forceinline__ float bf2f(ushort h){
  return __uint_as_float(((unsigned)h) << 16);
}
// async global -> LDS, 16 bytes per lane; LDS dest = wave-uniform base + lane*16
__device__ __forceinline__ void gl_lds16(const void* g, void* l){
  __builtin_amdgcn_global_load_lds(
      (const __attribute__((address_space(1))) unsigned int*)g,
      (__attribute__((address_space(3))) unsigned int*)l, 16, 0, 0);
}
// pack two f32 -> one u32 of two bf16 (RNE), low16 = a, high16 = b
__device__ __forceinline__ unsigned cvt_pk_bf16(float a, float b){
  unsigned r;
  asm("v_cvt_pk_bf16_f32 %0, %1, %2" : "=v"(r) : "v"(a), "v"(b));
  return r;
}

// ---------------------------------------------------------------- prep -----
// blocks [0,4096): x -> bf16 hi/lo.
// [4096,4352): weight transposes via LDS 64x64 tiles (coalesced both sides).
// [4352]: fused bias fill. [4353,4609): prior (permuted, *log2e).
// [4609,4673): pv means.
__global__ __launch_bounds__(256) void prep_k(
    const float* __restrict__ x,
    const float* __restrict__ Wq, const float* __restrict__ Wk,
    const float* __restrict__ Wv, const float* __restrict__ Wo,
    const float* __restrict__ bq, const float* __restrict__ bk,
    const float* __restrict__ bv,
    const float* __restrict__ prior, const float* __restrict__ fimp,
    ushort* __restrict__ xhi, ushort* __restrict__ xlo,
    ushort* __restrict__ Wthi, ushort* __restrict__ Wtlo,
    ushort* __restrict__ Wot, float* __restrict__ fb,
    float* __restrict__ pe, float* __restrict__ comb)
{
  __shared__ float tile[64][65];
  int bid = (int)blockIdx.x, t = threadIdx.x;
  if (bid < 4096){
    size_t i = ((size_t)bid * 256 + t) * 8;
    float4v a = *(const float4v*)(x + i);
    float4v b = *(const float4v*)(x + i + 4);
    float v0=a[0],v1=a[1],v2=a[2],v3=a[3],v4=b[0],v5=b[1],v6=b[2],v7=b[3];
    ushort h0=f2bf(v0),h1=f2bf(v1),h2=f2bf(v2),h3=f2bf(v3);
    ushort h4=f2bf(v4),h5=f2bf(v5),h6=f2bf(v6),h7=f2bf(v7);
    ushort l0=f2bf(v0-bf2f(h0)),l1=f2bf(v1-bf2f(h1)),l2=f2bf(v2-bf2f(h2)),l3=f2bf(v3-bf2f(h3));
    ushort l4=f2bf(v4-bf2f(h4)),l5=f2bf(v5-bf2f(h5)),l6=f2bf(v6-bf2f(h6)),l7=f2bf(v7-bf2f(h7));
    uint4 ph, pl;
    ph.x = h0 | ((unsigned)h1<<16); ph.y = h2 | ((unsigned)h3<<16);
    ph.z = h4 | ((unsigned)h5<<16); ph.w = h6 | ((unsigned)h7<<16);
    pl.x = l0 | ((unsigned)l1<<16); pl.y = l2 | ((unsigned)l3<<16);
    pl.z = l4 | ((unsigned)l5<<16); pl.w = l6 | ((unsigned)l7<<16);
    *(uint4*)(xhi + i) = ph;
    *(uint4*)(xlo + i) = pl;
  } else if (bid < 4352){
    int wt = bid - 4096;
    int mat = wt >> 6, tl = wt & 63;
    int I0 = (tl & 7) << 6, O0 = (tl >> 3) << 6;   // in-dim / out-dim origins
    const float* W = (mat == 0) ? Wq : ((mat == 1) ? Wk : ((mat == 2) ? Wv : Wo));
    int rbase = (t >> 6) << 4;                     // 0,16,32,48
    int c = t & 63;
    #pragma unroll 4
    for (int rr = 0; rr < 16; rr++)
      tile[rbase + rr][c] = W[(size_t)(I0 + rbase + rr)*512 + O0 + c];
    __syncthreads();
    bool dolo = (mat < 2);
    #pragma unroll 4
    for (int rr = 0; rr < 16; rr++){
      int ol = rbase + rr;                         // local out-row
      float f = tile[c][ol];
      ushort hi = f2bf(f);
      if (mat < 3){
        size_t idx = (size_t)(mat*512 + O0 + ol)*512 + I0 + c;
        Wthi[idx] = hi;
        if (dolo) Wtlo[idx] = f2bf(f - bf2f(hi));
      } else {
        Wot[(size_t)(O0 + ol)*512 + I0 + c] = hi;
      }
    }
  } else if (bid == 4352){
    for (int q = t; q < 1536; q += 256)
      fb[q] = (q < 512) ? bq[q] : ((q < 1024) ? bk[q-512] : bv[q-1024]);
  } else if (bid < 4609){
    int i = bid - 4353, j = t;
    int kt = ((j >> 5) << 1) | ((j >> 2) & 1);
    int g  = (j >> 3) & 3;
    int r  = j & 3;
    int slot = (kt << 4) | (g << 2) | r;
    pe[(size_t)i*256 + slot] = prior[(size_t)i*256 + j] * fimp[i] * fimp[j] * LOG2E;
  } else {
    int b = bid - 4609;
    const float* xb = x + (size_t)b * 131072;
    float p0=0.f,p1=0.f,q0=0.f,q1=0.f;
    for (int n = 0; n < 128; n++){ p0 += xb[n*512 + t]; p1 += xb[n*512 + t + 256]; }
    for (int n = 128; n < 256; n++){ q0 += xb[n*512 + t]; q1 += xb[n*512 + t + 256]; }
    const float s = 1.0f/128.0f;
    comb[(size_t)b*1024 + t]             = p0*s;
    comb[(size_t)b*1024 + t + 256]       = p1*s;
    comb[(size_t)b*1024 + 512 + t]       = q0*s;
    comb[(size_t)b*1024 + 512 + t + 256] = q1*s;
  }
}

// -------------------------------------------------------------- pv path ----
__global__ __launch_bounds__(256) void pv_hid_k(const float* __restrict__ comb,
    const float* __restrict__ W1, const float* __restrict__ b1,
    const float* __restrict__ W2, float* __restrict__ pvp){
  __shared__ float cs[1024];
  __shared__ float red[4][64];
  int ct = blockIdx.x & 7, b = blockIdx.x >> 3;
  int t = threadIdx.x, lane = t & 63, w = t >> 6;
  for (int i = t; i < 1024; i += 256) cs[i] = comb[(size_t)b*1024 + i];
  __syncthreads();
  int col = (ct << 6) + lane;
  const float* w1p = W1 + (size_t)(w << 8)*512 + col;
  const float* csp = cs + (w << 8);
  float acc = 0.f;
  #pragma unroll 8
  for (int i = 0; i < 256; i++)
    acc = fmaf(csp[i], w1p[(size_t)i*512], acc);
  red[w][lane] = acc;
  __syncthreads();
  if (w == 0){
    float a = red[0][lane] + red[1][lane] + red[2][lane] + red[3][lane] + b1[col];
    float p = (a / (1.0f + __expf(-a))) * W2[col];
    p += __shfl_xor(p, 32); p += __shfl_xor(p, 16); p += __shfl_xor(p, 8);
    p += __shfl_xor(p, 4);  p += __shfl_xor(p, 2);  p += __shfl_xor(p, 1);
    if (lane == 0) pvp[b*8 + ct] = p;
  }
}

// --------------------------------------- fused projection GEMMs (qk + v) ---
// blocks [0,1024): split-bf16 qk GEMM. LDS stages Ahi|Alo|Bhi (24KB/step,
// dbuf 48KB -> 3 blocks/CU); Blo (Wtlo, L2-resident 1MB weights) fragments
// read directly from global. [1024,1536): plain v GEMM (dbuf 2x16KB).
__global__ __launch_bounds__(256) void gemm_proj(
    const ushort* __restrict__ xhi_, const ushort* __restrict__ xlo_,
    const ushort* __restrict__ Wthi, const ushort* __restrict__ Wtlo,
    const float* __restrict__ fb,
    ushort* __restrict__ qhi, ushort* __restrict__ qlo,
    ushort* __restrict__ khi, ushort* __restrict__ klo,
    ushort* __restrict__ vt)
{
  extern __shared__ __align__(16) char smx[];   // 48KB (qk) / 32KB (v)
  int bid = (int)blockIdx.x;
  int tid = threadIdx.x, lane = tid & 63, w = tid >> 6, wm = w >> 1, wn = w & 1;
  int q15 = lane & 15, g = lane >> 4;
  int lrow = lane >> 2, lcol = (lane & 3) * 8;

  if (bid < 1024){
    int round = bid >> 7, rem = bid & 127;
    int sw = (round << 7) + ((rem & 7) << 4) + (rem >> 3);
    int n0 = (sw & 7) * 128, m0 = (sw >> 3) * 128;
    float4v acc[4][4] = {};

    auto STAGE = [&](int buf, int k0){
      #pragma unroll
      for (int t = 0; t < 6; t++){
        int id = w*6 + t;                    // 0..23 = Ahi(8)|Alo(8)|Bhi(8)
        int mat = id >> 3, sp = id & 7;
        int row = ((mat < 2) ? m0 : n0) + sp*16 + lrow;
        const ushort* src;
        if      (mat == 0) src = xhi_ + (size_t)row*512 + k0 + lcol;
        else if (mat == 1) src = xlo_ + (size_t)row*512 + k0 + lcol;
        else               src = Wthi + (size_t)row*512 + k0 + lcol;
        gl_lds16(src, smx + buf*24576 + (id << 10));
      }
    };

    STAGE(0, 0);
    __syncthreads();
    int buf = 0;
    for (int k0 = 0; k0 < 512; k0 += 32){
      if (k0 + 32 < 512) STAGE(buf ^ 1, k0 + 32);
      const char* sb = smx + buf*24576;
      short8 ah[4], al[4], bh[4], bl[4];
      #pragma unroll
      for (int i = 0; i < 4; i++){
        int ra = (wm*64 + i*16 + q15)*64 + g*16;
        int rb = (wn*64 + i*16 + q15)*64 + g*16;
        ah[i] = *(const short8*)(sb +         ra);
        al[i] = *(const short8*)(sb + 8192  + ra);
        bh[i] = *(const short8*)(sb + 16384 + rb);
        bl[i] = *(const short8*)(Wtlo + (size_t)(n0 + wn*64 + i*16 + q15)*512 + k0 + g*8);
      }
      #pragma unroll
      for (int mi = 0; mi < 4; mi++){
        #pragma unroll
        for (int ni = 0; ni < 4; ni++){
          acc[mi][ni] = MFMA16(ah[mi], bh[ni], acc[mi][ni]);
          acc[mi][ni] = MFMA16(ah[mi], bl[ni], acc[mi][ni]);
          acc[mi][ni] = MFMA16(al[mi], bh[ni], acc[mi][ni]);
        }
      }
      __syncthreads();           // drains prefetch (vmcnt0) + frees buf
      buf ^= 1;
    }
    #pragma unroll
    for (int mi = 0; mi < 4; mi++){
      #pragma unroll
      for (int ni = 0; ni < 4; ni++){
        #pragma unroll
        for (int r = 0; r < 4; r++){
          int rg = m0 + wm*64 + mi*16 + (g<<2) + r;
          int cg = n0 + wn*64 + ni*16 + q15;
          float val = acc[mi][ni][r] + fb[cg];
          int which = cg >> 9, within = cg & 511;
          int bb = rg >> 8, seq = rg & 255, hh = within >> 6, hd = within & 63;
          size_t idx = ((size_t)((bb*8 + hh)*256 + seq))*64 + hd;
          ushort hi_ = f2bf(val);
          ushort lo_ = f2bf(val - bf2f(hi_));
          if (which == 0) { qhi[idx] = hi_; qlo[idx] = lo_; }
          else            { khi[idx] = hi_; klo[idx] = lo_; }
        }
      }
    }
  } else {
    int flat = bid - 1024;
    int round = flat >> 7, rem = flat & 127;
    int sw = (round << 7) + ((rem & 7) << 4) + (rem >> 3);
    int n0 = (sw & 3) * 128, m0 = (sw >> 2) * 128;
    const ushort* Bt = Wthi + (size_t)1024*512;
    const float* bias = fb + 1024;
    float4v acc[4][4] = {};

    auto STAGE = [&](int buf, int k0){
      #pragma unroll
      for (int t = 0; t < 4; t++){
        int id = (w << 2) + t;
        int mat = id >> 3, sp = id & 7;
        int row = ((mat == 0) ? m0 : n0) + sp*16 + lrow;
        const ushort* src = ((mat == 0) ? xhi_ : Bt) + (size_t)row*512 + k0 + lcol;
        gl_lds16(src, smx + buf*16384 + (id << 10));
      }
    };

    STAGE(0, 0);
    __syncthreads();
    int buf = 0;
    for (int k0 = 0; k0 < 512; k0 += 32){
      if (k0 + 32 < 512) STAGE(buf ^ 1, k0 + 32);
      const char* sb = smx + buf*16384;
      short8 af[4], bg4[4];
      #pragma unroll
      for (int i = 0; i < 4; i++){
        int ra = (wm*64 + i*16 + q15)*64 + g*16;
        int rb = (wn*64 + i*16 + q15)*64 + g*16;
        af[i]  = *(const short8*)(sb +        ra);
        bg4[i] = *(const short8*)(sb + 8192 + rb);
      }
      #pragma unroll
      for (int mi = 0; mi < 4; mi++){
        #pragma unroll
        for (int ni = 0; ni < 4; ni++)
          acc[mi][ni] = MFMA16(af[mi], bg4[ni], acc[mi][ni]);
      }
      __syncthreads();
      buf ^= 1;
    }
    #pragma unroll
    for (int mi = 0; mi < 4; mi++){
      #pragma unroll
      for (int ni = 0; ni < 4; ni++){
        int rg0 = m0 + wm*64 + mi*16 + (g<<2);
        int cg  = n0 + wn*64 + ni*16 + q15;
        int bb = rg0 >> 8, seq0 = rg0 & 255;
        int hh = cg >> 6, hd = cg & 63;
        int kb = seq0 >> 5, wi = seq0 & 31;
        float b_ = bias[cg];
        uint2 pk;
        pk.x = (unsigned)f2bf(acc[mi][ni][0] + b_) | ((unsigned)f2bf(acc[mi][ni][1] + b_) << 16);
        pk.y = (unsigned)f2bf(acc[mi][ni][2] + b_) | ((unsigned)f2bf(acc[mi][ni][3] + b_) << 16);
        size_t off = ((size_t)(bb*8 + hh) << 14) + (size_t)(((kb<<6) + hd) << 5) + wi;
        *(uint2*)(vt + off) = pk;
      }
    }
  }
}

// -------------------------------------------------- out-projection GEMM ----
__global__ __launch_bounds__(256) void gemm_out(
    const ushort* __restrict__ A, const ushort* __restrict__ Bt,
    const float* __restrict__ bias, float* __restrict__ outp)
{
  __shared__ __align__(16) char sm[32768];   // 2 x 16KB double buffer
  int flat = (int)blockIdx.x;
  int round = flat >> 7, rem = flat & 127;
  int sw = (round << 7) + ((rem & 7) << 4) + (rem >> 3);
  int n0 = (sw & 3) * 128, m0 = (sw >> 2) * 128;
  int tid = threadIdx.x, lane = tid & 63, w = tid >> 6, wm = w >> 1, wn = w & 1;
  int q15 = lane & 15, g = lane >> 4;
  int lrow = lane >> 2, lcol = (lane & 3) * 8;
  float4v acc[4][4] = {};

  auto STAGE = [&](int buf, int k0){
    #pragma unroll
    for (int t = 0; t < 4; t++){
      int id = (w << 2) + t;
      int mat = id >> 3, sp = id & 7;
      int row = ((mat == 0) ? m0 : n0) + sp*16 + lrow;
      const ushort* src = ((mat == 0) ? A : Bt) + (size_t)row*512 + k0 + lcol;
      gl_lds16(src, sm + buf*16384 + (id << 10));
    }
  };

  STAGE(0, 0);
  __syncthreads();
  int buf = 0;
  for (int k0 = 0; k0 < 512; k0 += 32){
    if (k0 + 32 < 512) STAGE(buf ^ 1, k0 + 32);
    const char* sb = sm + buf*16384;
    short8 af[4], bg4[4];
    #pragma unroll
    for (int i = 0; i < 4; i++){
      int ra = (wm*64 + i*16 + q15)*64 + g*16;
      int rb = (wn*64 + i*16 + q15)*64 + g*16;
      af[i]  = *(const short8*)(sb +        ra);
      bg4[i] = *(const short8*)(sb + 8192 + rb);
    }
    #pragma unroll
    for (int mi = 0; mi < 4; mi++){
      #pragma unroll
      for (int ni = 0; ni < 4; ni++)
        acc[mi][ni] = MFMA16(af[mi], bg4[ni], acc[mi][ni]);
    }
    __syncthreads();
    buf ^= 1;
  }
  #pragma unroll
  for (int mi = 0; mi < 4; mi++){
    #pragma unroll
    for (int ni = 0; ni < 4; ni++){
      int rg0 = m0 + wm*64 + mi*16 + (g<<2);
      int cg  = n0 + wn*64 + ni*16 + q15;
      float b_ = bias[cg];
      #pragma unroll
      for (int r = 0; r < 4; r++)
        outp[(size_t)(rg0 + r)*512 + cg] = acc[mi][ni][r] + b_;
    }
  }
}

// ------------------------------------------------------ fused attention ----
// 1024 blocks = (half-major, bh XCD-swizzled), 8 waves x 16 q-rows.
// LDS 64 KB = K hi/lo (rho-permuted fragment-major); V overwrites K region
// after QK^T. exp2-domain scores. Top-k = float bisection on [rowmin,rowmax]
// (exact kept-set incl. tie semantics); softmax without max-subtraction.
__global__ __launch_bounds__(512, 4) void attn_k(
    const ushort* __restrict__ qhi_, const ushort* __restrict__ qlo_,
    const ushort* __restrict__ khi_, const ushort* __restrict__ klo_,
    const ushort* __restrict__ vt, const float* __restrict__ pe,
    const float* __restrict__ pvp, const float* __restrict__ b2,
    ushort* __restrict__ ao)
{
  extern __shared__ char sm[];   // 64KB: Khi 0..32K | Klo 32..64K; V -> 0..32K

  int bid = (int)blockIdx.x;
  int half = bid >> 9, s = bid & 511;
  int bh = ((s & 7) << 6) + (s >> 3);        // XCD swizzle (512 = 8*64)
  int b = bh >> 3, h = bh & 7;
  int tid = threadIdx.x, lane = tid & 63, w = tid >> 6;
  int g = lane >> 4, q15 = lane & 15;
  size_t base = (size_t)bh << 14;
  int qbase = (half << 7) + (w << 4);
  int qg = qbase + q15;

  // price/vol logit: sum of 8 partials + bias, sigmoid (uniform -> s_loads)
  float pvl = b2[0];
  #pragma unroll
  for (int i = 0; i < 8; i++) pvl += pvp[b*8 + i];
  float pvb2 = (1.0f / (1.0f + __expf(-pvl))) * (0.5f * LOG2E);
  const float scale2 = 0.125f * LOG2E;

  const ushort* qp1 = qhi_ + base + (size_t)qg*64 + (g<<3);
  const ushort* qp2 = qlo_ + base + (size_t)qg*64 + (g<<3);
  short8 qh0 = *(const short8*)(qp1);
  short8 qh1 = *(const short8*)(qp1 + 32);
  short8 ql0 = *(const short8*)(qp2);
  short8 ql1 = *(const short8*)(qp2 + 32);

  // ---- stage K hi/lo: 64 spans of 1KB, 8 per wave, rho-permuted rows
  #pragma unroll
  for (int t = 0; t < 8; t++){
    int sp = (w<<3) + t;
    int mat = sp >> 5, s5 = sp & 31, kt = s5 >> 1, hf = s5 & 1;
    int R = ((kt>>1)<<5) + ((q15>>2)<<3) + ((kt&1)<<2) + (q15&3);
    const ushort* gp = (mat ? klo_ : khi_) + base + (size_t)R*64 + hf*32 + g*8;
    gl_lds16(gp, sm + sp*1024);
  }
  __syncthreads();

  // ---- QK^T (split 3-mfma x 2 halves)
  float4v acc[16];
  #pragma unroll
  for (int kt = 0; kt < 16; kt++){
    short8 kh0 = *(const short8*)(sm +         kt*2048 +        lane*16);
    short8 kh1 = *(const short8*)(sm +         kt*2048 + 1024 + lane*16);
    short8 kl0 = *(const short8*)(sm + 32768 + kt*2048 +        lane*16);
    short8 kl1 = *(const short8*)(sm + 32768 + kt*2048 + 1024 + lane*16);
    float4v a = {0.f,0.f,0.f,0.f};
    a = MFMA16(kh0, qh0, a);
    a = MFMA16(kh1, qh1, a);
    a = MFMA16(kh0, ql0, a);
    a = MFMA16(kh1, ql1, a);
    a = MFMA16(kl0, qh0, a);
    a = MFMA16(kl1, qh1, a);
    acc[kt] = a;
  }
  __syncthreads();                           // all K LDS reads complete

  // ---- stage V into the K region (latency hides under topk VALU phase)
  #pragma unroll
  for (int t = 0; t < 4; t++){
    int vsp = (w<<2) + t;
    int mM = vsp >> 2, ht = vsp & 3;
    gl_lds16(vt + base + mM*2048 + (ht*16 + q15)*32 + g*8, sm + vsp*1024);
  }

  // ---- scaled-domain bias: s2 = raw*scale2 + pe2 + cb2
  bool qlow = (qg < 128);
  #pragma unroll
  for (int kt = 0; kt < 16; kt++){
    float4v p4 = *(const float4v*)(pe + qg*256 + (kt<<4) + (g<<2));
    float cb = (qlow != (kt < 8)) ? pvb2 : 0.0f;
    #pragma unroll
    for (int r = 0; r < 4; r++)
      acc[kt][r] = fmaf(acc[kt][r], scale2, p4[r] + cb);
  }

  // ---- row min/max across the 4-lane group
  float rmin = acc[0][0], rmax = acc[0][0];
  #pragma unroll
  for (int kt = 0; kt < 16; kt++){
    #pragma unroll
    for (int r = 0; r < 4; r++){
      rmin = fminf(rmin, acc[kt][r]);
      rmax = fmaxf(rmax, acc[kt][r]);
    }
  }
  rmin = fminf(rmin, __shfl_xor(rmin, 16));
  rmin = fminf(rmin, __shfl_xor(rmin, 32));
  rmax = fmaxf(rmax, __shfl_xor(rmax, 16));
  rmax = fmaxf(rmax, __shfl_xor(rmax, 32));

  // ---- exact 128th-largest: bisection on value space.
  float lo = rmin, hi = rmax;
  #pragma unroll 1
  for (int it = 0; it < 40; ++it){
    float mid = 0.5f*(lo + hi);
    if (!(mid > lo && mid < hi)) break;
    int cnt = 0;
    #pragma unroll
    for (int kt = 0; kt < 16; kt++){
      #pragma unroll
      for (int r = 0; r < 4; r++)
        cnt += (acc[kt][r] >= mid) ? 1 : 0;
    }
    cnt += __shfl_xor(cnt, 16);
    cnt += __shfl_xor(cnt, 32);
    if (cnt >= 128){
      lo = mid;
      if (cnt == 128) break;
    } else hi = mid;
  }
  float thrf = lo;

  // ---- softmax over kept (exp2 domain, no max subtraction: |s2| bounded)
  float sum = 0.0f;
  #pragma unroll
  for (int kt = 0; kt < 16; kt++){
    #pragma unroll
    for (int r = 0; r < 4; r++){
      float e = (acc[kt][r] >= thrf) ? exp2f(acc[kt][r]) : 0.0f;
      acc[kt][r] = e;
      sum += e;
    }
  }
  sum += __shfl_xor(sum, 16);
  sum += __shfl_xor(sum, 32);
  float inv = 1.0f / sum;

  __syncthreads();                           // V staged (vmcnt drained)

  // ---- PV fully in-register; V fragments from LDS
  float4v oa[4] = {};
  #pragma unroll
  for (int mM = 0; mM < 8; mM++){
    uint4 pk;
    pk.x = cvt_pk_bf16(acc[2*mM][0]*inv,   acc[2*mM][1]*inv);
    pk.y = cvt_pk_bf16(acc[2*mM][2]*inv,   acc[2*mM][3]*inv);
    pk.z = cvt_pk_bf16(acc[2*mM+1][0]*inv, acc[2*mM+1][1]*inv);
    pk.w = cvt_pk_bf16(acc[2*mM+1][2]*inv, acc[2*mM+1][3]*inv);
    short8 pf = *(short8*)&pk;
    #pragma unroll
    for (int ht = 0; ht < 4; ht++){
      short8 vf = *(const short8*)(sm + (mM*4 + ht)*1024 + lane*16);
      oa[ht] = MFMA16(pf, vf, oa[ht]);
    }
  }
  #pragma unroll
  for (int ht = 0; ht < 4; ht++){
    #pragma unroll
    for (int r = 0; r < 4; r++){
      int qo = qbase + (g<<2) + r;
      ao[((size_t)(b*256 + qo) << 9) + (h<<6) + (ht<<4) + q15] = f2bf(oa[ht][r]);
    }
  }
}

// ---------------------------------------------------------------------------
extern "C" void kernel_launch(void* const* d_in, const int* in_sizes, int n_in,
                              void* d_out, int out_size, void* d_ws, size_t ws_size,
                              hipStream_t stream)
{
  const float* x     = (const float*)d_in[0];
  const float* Wq    = (const float*)d_in[1];
  const float* bq    = (const float*)d_in[2];
  const float* Wk    = (const float*)d_in[3];
  const float* bk    = (const float*)d_in[4];
  const float* Wv    = (const float*)d_in[5];
  const float* bv    = (const float*)d_in[6];
  const float* Wo    = (const float*)d_in[7];
  const float* bo    = (const float*)d_in[8];
  const float* prior = (const float*)d_in[9];
  const float* fimp  = (const float*)d_in[10];
  const float* W1    = (const float*)d_in[11];
  const float* b1    = (const float*)d_in[12];
  const float* W2    = (const float*)d_in[13];
  const float* b2    = (const float*)d_in[14];

  char* ws = (char*)d_ws;
  ushort* xhi  = (ushort*)(ws + 0);
  ushort* xlo  = (ushort*)(ws + 16777216);
  ushort* qhi  = (ushort*)(ws + 33554432);
  ushort* qlo  = (ushort*)(ws + 50331648);
  ushort* khi  = (ushort*)(ws + 67108864);
  ushort* klo  = (ushort*)(ws + 83886080);
  ushort* vt   = (ushort*)(ws + 100663296);    // V in MFMA fragment layout
  ushort* Wthi = (ushort*)(ws + 117440512);
  ushort* Wtlo = (ushort*)(ws + 119013376);
  ushort* Wot  = (ushort*)(ws + 120061952);
  float*  fb   = (float*) (ws + 120586240);
  float*  comb = (float*) (ws + 120592384);
  float*  pvp  = (float*) (ws + 120854528);    // [64][8] partial logits
  float*  pe   = (float*) (ws + 120858624);    // 256 KB (perm layout, *log2e)
  ushort* ao   = xhi;   // alias: xhi dead after the projection GEMMs

  (void)hipFuncSetAttribute((const void*)attn_k,
      hipFuncAttributeMaxDynamicSharedMemorySize, 65536);
  (void)hipFuncSetAttribute((const void*)gemm_proj,
      hipFuncAttributeMaxDynamicSharedMemorySize, 65536);

  prep_k   <<<4673, 256, 0, stream>>>(x, Wq, Wk, Wv, Wo, bq, bk, bv, prior, fimp,
                                      xhi, xlo, Wthi, Wtlo, Wot, fb, pe, comb);
  pv_hid_k <<<512, 256, 0, stream>>>(comb, W1, b1, W2, pvp);
  gemm_proj<<<1536, 256, 49152, stream>>>(xhi, xlo, Wthi, Wtlo, fb,
                                          qhi, qlo, khi, klo, vt);
  attn_k   <<<1024, 512, 65536, stream>>>(qhi, qlo, khi, klo, vt, pe, pvp, b2, ao);
  gemm_out <<<512, 256, 0, stream>>>(ao, Wot, bo, (float*)d_out);

  (void)in_sizes; (void)n_in; (void)out_size; (void)ws_size;
}